// Round 1
// baseline (728.544 us; speedup 1.0000x reference)
//
#include <hip/hip_runtime.h>

typedef unsigned short u16;
typedef unsigned int u32;

#define B_ 4
#define S_ 4
#define NTOK 1029
#define CDIM 2048
#define PSI 5
#define NPB 4096
#define MROWS 16384
#define N1 1024
#define N2 256
#define MD 64
#define MA 65

using bf16x8 = __attribute__((ext_vector_type(8))) short;
using f32x4  = __attribute__((ext_vector_type(4))) float;
using u16x8  = __attribute__((ext_vector_type(8))) unsigned short;

typedef __attribute__((address_space(1))) const void global_cvoid;
typedef __attribute__((address_space(3))) void lds_void;

__device__ __forceinline__ u16 f2b(float f) {
  u32 u = __builtin_bit_cast(u32, f);
  u32 r = (u + 0x7fffu + ((u >> 16) & 1u)) >> 16;
  return (u16)r;
}

// ---------------- prep: gather patch tokens, convert fp32 -> bf16 ----------------
__global__ void k_convert_patch(const float* __restrict__ tokens, u16* __restrict__ Abf) {
  size_t idx = (size_t)blockIdx.x * 256 + threadIdx.x;   // over MROWS*256 vec8 units
  size_t r = idx >> 8;
  int cv = (int)(idx & 255) << 3;
  int b = (int)(r >> 12), s = (int)((r >> 10) & 3), j = (int)(r & 1023);
  const float* src = tokens + ((size_t)((b * S_ + s) * NTOK + PSI + j)) * CDIM + cv;
  float4 v0 = *(const float4*)src;
  float4 v1 = *(const float4*)(src + 4);
  u16x8 o;
  o[0] = f2b(v0.x); o[1] = f2b(v0.y); o[2] = f2b(v0.z); o[3] = f2b(v0.w);
  o[4] = f2b(v1.x); o[5] = f2b(v1.y); o[6] = f2b(v1.z); o[7] = f2b(v1.w);
  *(u16x8*)(Abf + r * CDIM + cv) = o;
}

// ---------------- prep: transpose+convert combined W1 [2048,1024] -> W1t [1024][2048] bf16
__global__ void k_pack_w1t(const float* __restrict__ pfw1, const float* __restrict__ psw1,
                           u16* __restrict__ W1t) {
  __shared__ float tile[32][33];
  int kb = blockIdx.x * 32, nb = blockIdx.y * 32;
  int tx = threadIdx.x, ty = threadIdx.y;  // (32, 8)
  #pragma unroll
  for (int i = 0; i < 4; ++i) {
    int k = kb + ty + i * 8, n = nb + tx;
    float v = (n < 512) ? pfw1[(size_t)k * 512 + n] : psw1[(size_t)k * 512 + (n - 512)];
    tile[ty + i * 8][tx] = v;
  }
  __syncthreads();
  #pragma unroll
  for (int i = 0; i < 4; ++i) {
    int n = nb + ty + i * 8, k = kb + tx;
    W1t[(size_t)n * CDIM + k] = f2b(tile[tx][ty + i * 8]);
  }
}

// ---------------- prep: block-diagonal W2 [1024,256pad] -> W2t [256][1024] bf16
__global__ void k_pack_w2t(const float* __restrict__ pfw2, const float* __restrict__ psw2,
                           u16* __restrict__ W2t) {
  __shared__ float tile[32][33];
  int kb = blockIdx.x * 32, jb = blockIdx.y * 32;
  int tx = threadIdx.x, ty = threadIdx.y;  // (32, 8)
  #pragma unroll
  for (int i = 0; i < 4; ++i) {
    int k = kb + ty + i * 8, j = jb + tx;
    float v = 0.f;
    if (j < 128) { if (k < 512) v = pfw2[(size_t)k * 128 + j]; }
    else if (j < 192) { if (k >= 512) v = psw2[(size_t)(k - 512) * 64 + (j - 128)]; }
    tile[ty + i * 8][tx] = v;
  }
  __syncthreads();
  #pragma unroll
  for (int i = 0; i < 4; ++i) {
    int j = jb + ty + i * 8, k = kb + tx;
    W2t[(size_t)j * N1 + k] = f2b(tile[tx][ty + i * 8]);
  }
}

__global__ void k_pack_bias(const float* __restrict__ pfb1, const float* __restrict__ psb1,
                            const float* __restrict__ pfb2, const float* __restrict__ psb2,
                            float* __restrict__ b1c, float* __restrict__ b2c) {
  int t = blockIdx.x * 256 + threadIdx.x;
  if (t < 1024) b1c[t] = (t < 512) ? pfb1[t] : psb1[t - 512];
  if (t < 256)  b2c[t] = (t < 128) ? pfb2[t] : ((t < 192) ? psb2[t - 128] : 0.f);
}

// ---------------- bf16 MFMA GEMM:  C[M,N] = A[M,K] @ Bt[N,K]^T  (+bias, opt ReLU) ---
// 128x128 tile, BK=64, 4 waves (2x2), m97 2-barrier structure with global_load_lds w16.
template <int RELU, int OUTBF>
__global__ __launch_bounds__(256, 2)
void k_gemm(const u16* __restrict__ A, const u16* __restrict__ Bt,
            const float* __restrict__ bias, void* __restrict__ Cout,
            int M, int N, int K) {
  __shared__ u16 As[128 * 64];
  __shared__ u16 Bs[128 * 64];
  const int tid = threadIdx.x;
  const int lane = tid & 63;
  const int wave = tid >> 6;
  const int tM = blockIdx.x << 7;
  const int tN = blockIdx.y << 7;
  const int wr = wave >> 1, wc = wave & 1;

  const int srow = (wave << 3) + (lane >> 3);     // staging row within 32-row band
  const int scol = (lane & 7) << 3;               // staging col (k)
  const size_t abase = (size_t)(tM + srow) * K + scol;
  const size_t bbase = (size_t)(tN + srow) * K + scol;
  u16* asw = &As[(wave << 9) + (lane << 3)];
  u16* bsw = &Bs[(wave << 9) + (lane << 3)];

  f32x4 acc[4][4];
  #pragma unroll
  for (int i = 0; i < 4; ++i)
    #pragma unroll
    for (int j = 0; j < 4; ++j)
      acc[i][j] = (f32x4){0.f, 0.f, 0.f, 0.f};

  for (int k0 = 0; k0 < K; k0 += 64) {
    #pragma unroll
    for (int r = 0; r < 4; ++r) {
      __builtin_amdgcn_global_load_lds(
          (global_cvoid*)(A + abase + (size_t)(r * 32) * K + k0),
          (lds_void*)(asw + r * 2048), 16, 0, 0);
      __builtin_amdgcn_global_load_lds(
          (global_cvoid*)(Bt + bbase + (size_t)(r * 32) * K + k0),
          (lds_void*)(bsw + r * 2048), 16, 0, 0);
    }
    __syncthreads();   // drains vmcnt before barrier
    #pragma unroll
    for (int kk = 0; kk < 64; kk += 32) {
      bf16x8 af[4], bfr[4];
      #pragma unroll
      for (int i = 0; i < 4; ++i) {
        af[i]  = *(const bf16x8*)&As[((wr << 6) + (i << 4) + (lane & 15)) * 64 + kk + ((lane >> 4) << 3)];
        bfr[i] = *(const bf16x8*)&Bs[((wc << 6) + (i << 4) + (lane & 15)) * 64 + kk + ((lane >> 4) << 3)];
      }
      #pragma unroll
      for (int mi = 0; mi < 4; ++mi)
        #pragma unroll
        for (int ni = 0; ni < 4; ++ni)
          acc[mi][ni] = __builtin_amdgcn_mfma_f32_16x16x32_bf16(af[mi], bfr[ni], acc[mi][ni], 0, 0, 0);
    }
    __syncthreads();
  }

  #pragma unroll
  for (int ni = 0; ni < 4; ++ni) {
    const int col = tN + (wc << 6) + (ni << 4) + (lane & 15);
    const float bv = bias[col];
    #pragma unroll
    for (int mi = 0; mi < 4; ++mi) {
      #pragma unroll
      for (int j = 0; j < 4; ++j) {
        const int row = tM + (wr << 6) + (mi << 4) + ((lane >> 4) << 2) + j;
        float vv = acc[mi][ni][j] + bv;
        if (RELU) vv = fmaxf(vv, 0.f);
        if (OUTBF) ((u16*)Cout)[(size_t)row * N + col] = f2b(vv);
        else       ((float*)Cout)[(size_t)row * N + col] = vv;
      }
    }
  }
}

// ---------------- scores transpose: FS[:,128:192] -> Sc[B][65][4096] (+dust row) ----
__global__ void k_tr_scores(const float* __restrict__ FS, const float* __restrict__ dust,
                            float* __restrict__ Sc) {
  __shared__ float t[64][65];
  int b = blockIdx.x >> 6, n0 = (blockIdx.x & 63) * 64;
  int tx = threadIdx.x & 63, ty = threadIdx.x >> 6;   // 64 x 4
  for (int r = ty; r < 64; r += 4)
    t[r][tx] = FS[((size_t)(b * NPB + n0 + r)) * N2 + 128 + tx];
  __syncthreads();
  for (int k = ty; k < 64; k += 4)
    Sc[((size_t)(b * MA) + k) * NPB + n0 + tx] = t[tx][k];
  if (threadIdx.x < 64)
    Sc[((size_t)(b * MA) + 64) * NPB + n0 + threadIdx.x] = dust[0];
}

// ---------------- sinkhorn: u update (row LSE over n=4096) ----------------
__global__ void k_sink_u(const float* __restrict__ Sc, const float* __restrict__ v,
                         float* __restrict__ u) {
  __shared__ float red[4];
  int b = blockIdx.x / MA, k = blockIdx.x % MA;
  const float* row = Sc + ((size_t)(b * MA) + k) * NPB;
  const float* vb = v + (size_t)b * NPB;
  int tid = threadIdx.x;
  float mx = -1e30f;
  for (int n = tid; n < NPB; n += 256) mx = fmaxf(mx, row[n] + vb[n]);
  #pragma unroll
  for (int o = 32; o; o >>= 1) mx = fmaxf(mx, __shfl_down(mx, o));
  if ((tid & 63) == 0) red[tid >> 6] = mx;
  __syncthreads();
  mx = fmaxf(fmaxf(red[0], red[1]), fmaxf(red[2], red[3]));
  float s = 0.f;
  for (int n = tid; n < NPB; n += 256) s += expf(row[n] + vb[n] - mx);
  #pragma unroll
  for (int o = 32; o; o >>= 1) s += __shfl_down(s, o);
  __syncthreads();
  if ((tid & 63) == 0) red[tid >> 6] = s;
  __syncthreads();
  if (tid == 0) {
    float ssum = red[0] + red[1] + red[2] + red[3];
    const float nrm = -logf((float)(NPB + MD));
    float la = (k == MD) ? (nrm + logf((float)(NPB - MD))) : nrm;
    u[b * MA + k] = la - (mx + logf(ssum));
  }
}

// ---------------- sinkhorn: v update (col LSE over m+1=65) ----------------
__global__ void k_sink_v(const float* __restrict__ Sc, const float* __restrict__ u,
                         float* __restrict__ v) {
  __shared__ float us[MA];
  int b = blockIdx.x >> 4;
  int n = ((blockIdx.x & 15) << 8) + threadIdx.x;
  if (threadIdx.x < MA) us[threadIdx.x] = u[b * MA + threadIdx.x];
  __syncthreads();
  const float* Sb = Sc + (size_t)b * MA * NPB + n;
  float mx = -1e30f;
  for (int k = 0; k < MA; ++k) mx = fmaxf(mx, Sb[(size_t)k * NPB] + us[k]);
  float s = 0.f;
  for (int k = 0; k < MA; ++k) s += expf(Sb[(size_t)k * NPB] + us[k] - mx);
  const float nrm = -logf((float)(NPB + MD));
  v[(size_t)b * NPB + n] = nrm - (mx + logf(s));
}

// ---------------- P = exp(M + u + v - norm), rows 0..63 ----------------
__global__ void k_compute_p(const float* __restrict__ Sc, const float* __restrict__ u,
                            const float* __restrict__ v, float* __restrict__ P) {
  size_t idx = (size_t)blockIdx.x * 256 + threadIdx.x;  // B*64*4096
  int b = (int)(idx >> 18), k = (int)((idx >> 12) & 63), n = (int)(idx & 4095);
  const float nrm = -logf((float)(NPB + MD));
  float lp = Sc[((size_t)(b * MA) + k) * NPB + n] + u[b * MA + k] + v[(size_t)b * NPB + n] - nrm;
  P[idx] = expf(lp);
}

// ---------------- pooled[b][c][k] = sum_n feats[b][n][c] * P[b][k][n] ----------------
__global__ void k_pooled(const float* __restrict__ FS, const float* __restrict__ P,
                         float* __restrict__ pooled) {
  int b = blockIdx.x >> 5;
  int k = ((blockIdx.x & 31) << 1) + (threadIdx.x >> 7);
  int c = threadIdx.x & 127;
  const float* f = FS + (size_t)b * NPB * N2 + c;
  const float* p = P + ((size_t)(b * MD) + k) * NPB;
  float acc = 0.f;
  #pragma unroll 4
  for (int n = 0; n < NPB; ++n) acc += f[(size_t)n * N2] * p[n];
  pooled[((size_t)(b * 128) + c) * MD + k] = acc;
}

// ---------------- patch output: l2norm over c (128), write [b][c*64+k] --------------
__global__ void k_patch_out(const float* __restrict__ pooled, float* __restrict__ out) {
  int b = blockIdx.x >> 6, k = blockIdx.x & 63;
  int tid = threadIdx.x;  // 64 threads
  float v0 = pooled[((size_t)(b * 128) + tid) * MD + k];
  float v1 = pooled[((size_t)(b * 128) + 64 + tid) * MD + k];
  float ss = v0 * v0 + v1 * v1;
  #pragma unroll
  for (int o = 32; o; o >>= 1) ss += __shfl_down(ss, o);
  ss = __shfl(ss, 0);
  float inv = 1.f / fmaxf(sqrtf(ss), 1e-12f);
  out[(size_t)b * 8704 + tid * 64 + k] = v0 * inv;
  out[(size_t)b * 8704 + (64 + tid) * 64 + k] = v1 * inv;
}

// ---------------- cam/reg layer 1: H1[80][1024] = ReLU(X @ W1 + b1) ----------------
__global__ __launch_bounds__(256)
void k_cr1(const float* __restrict__ tokens,
           const float* __restrict__ camw1, const float* __restrict__ camb1,
           const float* __restrict__ regw1, const float* __restrict__ regb1,
           float* __restrict__ H1) {
  __shared__ float xs[4][CDIM];
  int g = blockIdx.x;               // 0..19 : rows 4g..4g+3 (0..15 cam, 16..79 reg)
  bool cam = (g < 4);
  const float* W = cam ? camw1 : regw1;
  const float* bias = cam ? camb1 : regb1;
  for (int r = 0; r < 4; ++r) {
    int rr = g * 4 + r;
    const float* src;
    if (rr < 16) { int b = rr >> 2, s = rr & 3; src = tokens + ((size_t)(b * S_ + s) * NTOK) * CDIM; }
    else { int r2 = rr - 16; int b = r2 >> 4, q = r2 & 15, s = q >> 2, t = (q & 3) + 1;
           src = tokens + ((size_t)(b * S_ + s) * NTOK + t) * CDIM; }
    for (int c = threadIdx.x; c < CDIM; c += 256) xs[r][c] = src[c];
  }
  __syncthreads();
  int o = blockIdx.y * 256 + threadIdx.x;
  float a0 = 0.f, a1 = 0.f, a2 = 0.f, a3 = 0.f;
  #pragma unroll 8
  for (int k = 0; k < CDIM; ++k) {
    float w = W[(size_t)k * 1024 + o];
    a0 += xs[0][k] * w; a1 += xs[1][k] * w; a2 += xs[2][k] * w; a3 += xs[3][k] * w;
  }
  float bv = bias[o];
  H1[(size_t)(g * 4 + 0) * 1024 + o] = fmaxf(a0 + bv, 0.f);
  H1[(size_t)(g * 4 + 1) * 1024 + o] = fmaxf(a1 + bv, 0.f);
  H1[(size_t)(g * 4 + 2) * 1024 + o] = fmaxf(a2 + bv, 0.f);
  H1[(size_t)(g * 4 + 3) * 1024 + o] = fmaxf(a3 + bv, 0.f);
}

// ---------------- cam/reg layer 2 + l2norm + clip^p: hp[80][512] ----------------
__global__ __launch_bounds__(512)
void k_cr2(const float* __restrict__ H1,
           const float* __restrict__ camw2, const float* __restrict__ camb2,
           const float* __restrict__ regw2, const float* __restrict__ regb2,
           const float* __restrict__ camp, const float* __restrict__ regp,
           float* __restrict__ hp) {
  __shared__ float h1s[1024];
  __shared__ float red[8];
  int row = blockIdx.x;
  bool cam = (row < 16);
  const float* W = cam ? camw2 : regw2;
  const float* bias = cam ? camb2 : regb2;
  float p = cam ? camp[0] : regp[0];
  for (int k = threadIdx.x; k < 1024; k += 512) h1s[k] = H1[(size_t)row * 1024 + k];
  __syncthreads();
  int o = threadIdx.x;
  float acc = 0.f;
  #pragma unroll 8
  for (int k = 0; k < 1024; ++k) acc += h1s[k] * W[(size_t)k * 512 + o];
  acc += bias[o];
  float ss = acc * acc;
  #pragma unroll
  for (int of = 32; of; of >>= 1) ss += __shfl_down(ss, of);
  if ((threadIdx.x & 63) == 0) red[threadIdx.x >> 6] = ss;
  __syncthreads();
  float tot = 0.f;
  #pragma unroll
  for (int i = 0; i < 8; ++i) tot += red[i];
  float inv = 1.f / fmaxf(sqrtf(tot), 1e-12f);
  float t = fmaxf(acc * inv, 1e-6f);
  hp[(size_t)row * 512 + o] = powf(t, p);
}

// ---------------- cam/reg GeM finalize + layers 3/4 + l2norm ----------------
__global__ __launch_bounds__(256)
void k_cr3(const float* __restrict__ hp,
           const float* __restrict__ camp, const float* __restrict__ camw3,
           const float* __restrict__ camb3, const float* __restrict__ camw4,
           const float* __restrict__ camb4,
           const float* __restrict__ regp, const float* __restrict__ regw3,
           const float* __restrict__ regb3, const float* __restrict__ regw4,
           const float* __restrict__ regb4,
           float* __restrict__ out) {
  __shared__ float gs[512];
  __shared__ float o1s[512];
  __shared__ float red[4];
  int path = blockIdx.x >> 2, b = blockIdx.x & 3;
  bool cam = (path == 0);
  const float* W3 = cam ? camw3 : regw3;
  const float* B3 = cam ? camb3 : regb3;
  const float* W4 = cam ? camw4 : regw4;
  const float* B4 = cam ? camb4 : regb4;
  float p = cam ? camp[0] : regp[0];
  int L = cam ? 4 : 16;
  int row0 = cam ? b * 4 : 16 + b * 16;
  for (int o = threadIdx.x; o < 512; o += 256) {
    float s = 0.f;
    for (int r = 0; r < 16; ++r) if (r < L) s += hp[(size_t)(row0 + r) * 512 + o];
    gs[o] = powf(s / (float)L, 1.f / p);
  }
  __syncthreads();
  for (int o = threadIdx.x; o < 512; o += 256) {
    float acc = 0.f;
    #pragma unroll 8
    for (int k = 0; k < 512; ++k) acc += gs[k] * W3[(size_t)k * 512 + o];
    o1s[o] = fmaxf(acc + B3[o], 0.f);
  }
  __syncthreads();
  int o = threadIdx.x;
  float acc = 0.f;
  #pragma unroll 8
  for (int k = 0; k < 512; ++k) acc += o1s[k] * W4[(size_t)k * 256 + o];
  acc += B4[o];
  float ss = acc * acc;
  #pragma unroll
  for (int of = 32; of; of >>= 1) ss += __shfl_down(ss, of);
  if ((threadIdx.x & 63) == 0) red[threadIdx.x >> 6] = ss;
  __syncthreads();
  float tot = red[0] + red[1] + red[2] + red[3];
  float inv = 1.f / fmaxf(sqrtf(tot), 1e-12f);
  out[(size_t)b * 8704 + 8192 + path * 256 + o] = acc * inv;
}

// ---------------- workspace layout (bytes) ----------------
#define OFF_ABF 0u                        // 16384*2048*2 = 67,108,864 (reused region below after GEMM1)
#define OFF_SC 0u                         // B*65*4096*4 = 4,259,840
#define OFF_U 4259840u                    // pad to 4KB
#define OFF_V 4263936u                    // B*4096*4 = 65,536
#define OFF_P 4329472u                    // B*64*4096*4 = 4,194,304
#define OFF_POOL 8523776u                 // B*128*64*4 = 131,072
#define OFF_H1 8654848u                   // 80*1024*4 = 327,680
#define OFF_HP 8982528u                   // 80*512*4 = 163,840
#define OFF_H 67108864u                   // 16384*1024*2 = 33,554,432
#define OFF_FS 100663296u                 // 16384*256*4 = 16,777,216
#define OFF_W1T 117440512u                // 1024*2048*2 = 4,194,304
#define OFF_W2T 121634816u                // 256*1024*2 = 524,288
#define OFF_B1C 122159104u                // 4096
#define OFF_B2C 122163200u                // 1024

extern "C" void kernel_launch(void* const* d_in, const int* in_sizes, int n_in,
                              void* d_out, int out_size, void* d_ws, size_t ws_size,
                              hipStream_t stream) {
  (void)in_sizes; (void)n_in; (void)out_size; (void)ws_size;
  const float* tokens = (const float*)d_in[0];
  const float* cam_w1 = (const float*)d_in[2];
  const float* cam_b1 = (const float*)d_in[3];
  const float* cam_w2 = (const float*)d_in[4];
  const float* cam_b2 = (const float*)d_in[5];
  const float* cam_p  = (const float*)d_in[6];
  const float* cam_w3 = (const float*)d_in[7];
  const float* cam_b3 = (const float*)d_in[8];
  const float* cam_w4 = (const float*)d_in[9];
  const float* cam_b4 = (const float*)d_in[10];
  const float* reg_w1 = (const float*)d_in[11];
  const float* reg_b1 = (const float*)d_in[12];
  const float* reg_w2 = (const float*)d_in[13];
  const float* reg_b2 = (const float*)d_in[14];
  const float* reg_p  = (const float*)d_in[15];
  const float* reg_w3 = (const float*)d_in[16];
  const float* reg_b3 = (const float*)d_in[17];
  const float* reg_w4 = (const float*)d_in[18];
  const float* reg_b4 = (const float*)d_in[19];
  const float* pf_w1  = (const float*)d_in[20];
  const float* pf_b1  = (const float*)d_in[21];
  const float* pf_w2  = (const float*)d_in[22];
  const float* pf_b2  = (const float*)d_in[23];
  const float* ps_w1  = (const float*)d_in[24];
  const float* ps_b1  = (const float*)d_in[25];
  const float* ps_w2  = (const float*)d_in[26];
  const float* ps_b2  = (const float*)d_in[27];
  const float* dust   = (const float*)d_in[28];
  float* out = (float*)d_out;
  char* ws = (char*)d_ws;

  u16* Abf = (u16*)(ws + OFF_ABF);
  float* Sc = (float*)(ws + OFF_SC);
  float* ub = (float*)(ws + OFF_U);
  float* vb = (float*)(ws + OFF_V);
  float* P  = (float*)(ws + OFF_P);
  float* pooled = (float*)(ws + OFF_POOL);
  float* H1 = (float*)(ws + OFF_H1);
  float* hp = (float*)(ws + OFF_HP);
  u16* H   = (u16*)(ws + OFF_H);
  float* FS = (float*)(ws + OFF_FS);
  u16* W1t = (u16*)(ws + OFF_W1T);
  u16* W2t = (u16*)(ws + OFF_W2T);
  float* b1c = (float*)(ws + OFF_B1C);
  float* b2c = (float*)(ws + OFF_B2C);

  hipMemsetAsync(vb, 0, (size_t)B_ * NPB * sizeof(float), stream);
  k_convert_patch<<<16384, 256, 0, stream>>>(tokens, Abf);
  k_pack_w1t<<<dim3(64, 32), dim3(32, 8), 0, stream>>>(pf_w1, ps_w1, W1t);
  k_pack_w2t<<<dim3(32, 8), dim3(32, 8), 0, stream>>>(pf_w2, ps_w2, W2t);
  k_pack_bias<<<4, 256, 0, stream>>>(pf_b1, ps_b1, pf_b2, ps_b2, b1c, b2c);

  k_gemm<1, 1><<<dim3(128, 8), 256, 0, stream>>>(Abf, W1t, b1c, (void*)H, MROWS, N1, CDIM);
  k_gemm<0, 0><<<dim3(128, 2), 256, 0, stream>>>(H, W2t, b2c, (void*)FS, MROWS, N2, N1);

  k_cr1<<<dim3(20, 4), 256, 0, stream>>>(tokens, cam_w1, cam_b1, reg_w1, reg_b1, H1);
  k_cr2<<<80, 512, 0, stream>>>(H1, cam_w2, cam_b2, reg_w2, reg_b2, cam_p, reg_p, hp);

  k_tr_scores<<<256, 256, 0, stream>>>(FS, dust, Sc);
  for (int it = 0; it < 3; ++it) {
    k_sink_u<<<B_ * MA, 256, 0, stream>>>(Sc, vb, ub);
    k_sink_v<<<B_ * 16, 256, 0, stream>>>(Sc, ub, vb);
  }
  k_compute_p<<<4096, 256, 0, stream>>>(Sc, ub, vb, P);
  k_pooled<<<B_ * 32, 256, 0, stream>>>(FS, P, pooled);
  k_patch_out<<<B_ * MD, 64, 0, stream>>>(pooled, out);
  k_cr3<<<8, 256, 0, stream>>>(hp, cam_p, cam_w3, cam_b3, cam_w4, cam_b4,
                               reg_p, reg_w3, reg_b3, reg_w4, reg_b4, out);
}

// Round 3
// 482.533 us; speedup vs baseline: 1.5098x; 1.5098x over previous
//
#include <hip/hip_runtime.h>

typedef unsigned short u16;
typedef unsigned int u32;

#define B_ 4
#define S_ 4
#define NTOK 1029
#define CDIM 2048
#define PSI 5
#define NPB 4096
#define MROWS 16384
#define N1 1024
#define N2 256
#define MD 64
#define MA 65

using bf16x8 = __attribute__((ext_vector_type(8))) short;
using f32x4  = __attribute__((ext_vector_type(4))) float;
using u16x8  = __attribute__((ext_vector_type(8))) unsigned short;

typedef __attribute__((address_space(1))) const void global_cvoid;
typedef __attribute__((address_space(3))) void lds_void;

__device__ __forceinline__ u16 f2b(float f) {
  u32 u = __builtin_bit_cast(u32, f);
  u32 r = (u + 0x7fffu + ((u >> 16) & 1u)) >> 16;
  return (u16)r;
}

// ---------------- prep: gather patch tokens, convert fp32 -> bf16 ----------------
__global__ void k_convert_patch(const float* __restrict__ tokens, u16* __restrict__ Abf) {
  size_t idx = (size_t)blockIdx.x * 256 + threadIdx.x;   // over MROWS*256 vec8 units
  size_t r = idx >> 8;
  int cv = (int)(idx & 255) << 3;
  int b = (int)(r >> 12), s = (int)((r >> 10) & 3), j = (int)(r & 1023);
  const float* src = tokens + ((size_t)((b * S_ + s) * NTOK + PSI + j)) * CDIM + cv;
  float4 v0 = *(const float4*)src;
  float4 v1 = *(const float4*)(src + 4);
  u16x8 o;
  o[0] = f2b(v0.x); o[1] = f2b(v0.y); o[2] = f2b(v0.z); o[3] = f2b(v0.w);
  o[4] = f2b(v1.x); o[5] = f2b(v1.y); o[6] = f2b(v1.z); o[7] = f2b(v1.w);
  *(u16x8*)(Abf + r * CDIM + cv) = o;
}

// ---------------- prep: transpose+convert combined W1 [2048,1024] -> W1t [1024][2048] bf16
__global__ void k_pack_w1t(const float* __restrict__ pfw1, const float* __restrict__ psw1,
                           u16* __restrict__ W1t) {
  __shared__ float tile[32][33];
  int kb = blockIdx.x * 32, nb = blockIdx.y * 32;
  int tx = threadIdx.x, ty = threadIdx.y;  // (32, 8)
  #pragma unroll
  for (int i = 0; i < 4; ++i) {
    int k = kb + ty + i * 8, n = nb + tx;
    float v = (n < 512) ? pfw1[(size_t)k * 512 + n] : psw1[(size_t)k * 512 + (n - 512)];
    tile[ty + i * 8][tx] = v;
  }
  __syncthreads();
  #pragma unroll
  for (int i = 0; i < 4; ++i) {
    int n = nb + ty + i * 8, k = kb + tx;
    W1t[(size_t)n * CDIM + k] = f2b(tile[tx][ty + i * 8]);
  }
}

// ---------------- prep: block-diagonal W2 [1024,256pad] -> W2t [256][1024] bf16
__global__ void k_pack_w2t(const float* __restrict__ pfw2, const float* __restrict__ psw2,
                           u16* __restrict__ W2t) {
  __shared__ float tile[32][33];
  int kb = blockIdx.x * 32, jb = blockIdx.y * 32;
  int tx = threadIdx.x, ty = threadIdx.y;  // (32, 8)
  #pragma unroll
  for (int i = 0; i < 4; ++i) {
    int k = kb + ty + i * 8, j = jb + tx;
    float v = 0.f;
    if (j < 128) { if (k < 512) v = pfw2[(size_t)k * 128 + j]; }
    else if (j < 192) { if (k >= 512) v = psw2[(size_t)(k - 512) * 64 + (j - 128)]; }
    tile[ty + i * 8][tx] = v;
  }
  __syncthreads();
  #pragma unroll
  for (int i = 0; i < 4; ++i) {
    int j = jb + ty + i * 8, k = kb + tx;
    W2t[(size_t)j * N1 + k] = f2b(tile[tx][ty + i * 8]);
  }
}

__global__ void k_pack_bias(const float* __restrict__ pfb1, const float* __restrict__ psb1,
                            const float* __restrict__ pfb2, const float* __restrict__ psb2,
                            float* __restrict__ b1c, float* __restrict__ b2c) {
  int t = blockIdx.x * 256 + threadIdx.x;
  if (t < 1024) b1c[t] = (t < 512) ? pfb1[t] : psb1[t - 512];
  if (t < 256)  b2c[t] = (t < 128) ? pfb2[t] : ((t < 192) ? psb2[t - 128] : 0.f);
}

// ---------------- bf16 MFMA GEMM:  C[M,N] = A[M,K] @ Bt[N,K]^T  (+bias, opt ReLU) ---
// 128x128 tile, BK=64, 4 waves (2x2), m97 2-barrier structure with global_load_lds w16.
template <int RELU, int OUTBF>
__global__ __launch_bounds__(256, 2)
void k_gemm(const u16* __restrict__ A, const u16* __restrict__ Bt,
            const float* __restrict__ bias, void* __restrict__ Cout,
            int M, int N, int K) {
  __shared__ u16 As[128 * 64];
  __shared__ u16 Bs[128 * 64];
  const int tid = threadIdx.x;
  const int lane = tid & 63;
  const int wave = tid >> 6;
  const int tM = blockIdx.x << 7;
  const int tN = blockIdx.y << 7;
  const int wr = wave >> 1, wc = wave & 1;

  const int srow = (wave << 3) + (lane >> 3);     // staging row within 32-row band
  const int scol = (lane & 7) << 3;               // staging col (k)
  const size_t abase = (size_t)(tM + srow) * K + scol;
  const size_t bbase = (size_t)(tN + srow) * K + scol;
  u16* asw = &As[(wave << 9) + (lane << 3)];
  u16* bsw = &Bs[(wave << 9) + (lane << 3)];

  f32x4 acc[4][4];
  #pragma unroll
  for (int i = 0; i < 4; ++i)
    #pragma unroll
    for (int j = 0; j < 4; ++j)
      acc[i][j] = (f32x4){0.f, 0.f, 0.f, 0.f};

  for (int k0 = 0; k0 < K; k0 += 64) {
    #pragma unroll
    for (int r = 0; r < 4; ++r) {
      __builtin_amdgcn_global_load_lds(
          (global_cvoid*)(A + abase + (size_t)(r * 32) * K + k0),
          (lds_void*)(asw + r * 2048), 16, 0, 0);
      __builtin_amdgcn_global_load_lds(
          (global_cvoid*)(Bt + bbase + (size_t)(r * 32) * K + k0),
          (lds_void*)(bsw + r * 2048), 16, 0, 0);
    }
    __syncthreads();   // drains vmcnt before barrier
    #pragma unroll
    for (int kk = 0; kk < 64; kk += 32) {
      bf16x8 af[4], bfr[4];
      #pragma unroll
      for (int i = 0; i < 4; ++i) {
        af[i]  = *(const bf16x8*)&As[((wr << 6) + (i << 4) + (lane & 15)) * 64 + kk + ((lane >> 4) << 3)];
        bfr[i] = *(const bf16x8*)&Bs[((wc << 6) + (i << 4) + (lane & 15)) * 64 + kk + ((lane >> 4) << 3)];
      }
      #pragma unroll
      for (int mi = 0; mi < 4; ++mi)
        #pragma unroll
        for (int ni = 0; ni < 4; ++ni)
          acc[mi][ni] = __builtin_amdgcn_mfma_f32_16x16x32_bf16(af[mi], bfr[ni], acc[mi][ni], 0, 0, 0);
    }
    __syncthreads();
  }

  #pragma unroll
  for (int ni = 0; ni < 4; ++ni) {
    const int col = tN + (wc << 6) + (ni << 4) + (lane & 15);
    const float bv = bias[col];
    #pragma unroll
    for (int mi = 0; mi < 4; ++mi) {
      #pragma unroll
      for (int j = 0; j < 4; ++j) {
        const int row = tM + (wr << 6) + (mi << 4) + ((lane >> 4) << 2) + j;
        float vv = acc[mi][ni][j] + bv;
        if (RELU) vv = fmaxf(vv, 0.f);
        if (OUTBF) ((u16*)Cout)[(size_t)row * N + col] = f2b(vv);
        else       ((float*)Cout)[(size_t)row * N + col] = vv;
      }
    }
  }
}

// ---------------- scores transpose: FS[:,128:192] -> Sc[B][65][4096] (+dust row) ----
__global__ void k_tr_scores(const float* __restrict__ FS, const float* __restrict__ dust,
                            float* __restrict__ Sc) {
  __shared__ float t[64][65];
  int b = blockIdx.x >> 6, n0 = (blockIdx.x & 63) * 64;
  int tx = threadIdx.x & 63, ty = threadIdx.x >> 6;   // 64 x 4
  for (int r = ty; r < 64; r += 4)
    t[r][tx] = FS[((size_t)(b * NPB + n0 + r)) * N2 + 128 + tx];
  __syncthreads();
  for (int k = ty; k < 64; k += 4)
    Sc[((size_t)(b * MA) + k) * NPB + n0 + tx] = t[tx][k];
  if (threadIdx.x < 64)
    Sc[((size_t)(b * MA) + 64) * NPB + n0 + threadIdx.x] = dust[0];
}

// ---------------- sinkhorn: u update (row LSE over n=4096) ----------------
__global__ void k_sink_u(const float* __restrict__ Sc, const float* __restrict__ v,
                         float* __restrict__ u) {
  __shared__ float red[4];
  int b = blockIdx.x / MA, k = blockIdx.x % MA;
  const float* row = Sc + ((size_t)(b * MA) + k) * NPB;
  const float* vb = v + (size_t)b * NPB;
  int tid = threadIdx.x;
  float mx = -1e30f;
  for (int n = tid; n < NPB; n += 256) mx = fmaxf(mx, row[n] + vb[n]);
  #pragma unroll
  for (int o = 32; o; o >>= 1) mx = fmaxf(mx, __shfl_down(mx, o));
  if ((tid & 63) == 0) red[tid >> 6] = mx;
  __syncthreads();
  mx = fmaxf(fmaxf(red[0], red[1]), fmaxf(red[2], red[3]));
  float s = 0.f;
  for (int n = tid; n < NPB; n += 256) s += expf(row[n] + vb[n] - mx);
  #pragma unroll
  for (int o = 32; o; o >>= 1) s += __shfl_down(s, o);
  __syncthreads();
  if ((tid & 63) == 0) red[tid >> 6] = s;
  __syncthreads();
  if (tid == 0) {
    float ssum = red[0] + red[1] + red[2] + red[3];
    const float nrm = -logf((float)(NPB + MD));
    float la = (k == MD) ? (nrm + logf((float)(NPB - MD))) : nrm;
    u[b * MA + k] = la - (mx + logf(ssum));
  }
}

// ---------------- sinkhorn: v update (col LSE over m+1=65) ----------------
__global__ void k_sink_v(const float* __restrict__ Sc, const float* __restrict__ u,
                         float* __restrict__ v) {
  __shared__ float us[MA];
  int b = blockIdx.x >> 4;
  int n = ((blockIdx.x & 15) << 8) + threadIdx.x;
  if (threadIdx.x < MA) us[threadIdx.x] = u[b * MA + threadIdx.x];
  __syncthreads();
  const float* Sb = Sc + (size_t)b * MA * NPB + n;
  float mx = -1e30f;
  for (int k = 0; k < MA; ++k) mx = fmaxf(mx, Sb[(size_t)k * NPB] + us[k]);
  float s = 0.f;
  for (int k = 0; k < MA; ++k) s += expf(Sb[(size_t)k * NPB] + us[k] - mx);
  const float nrm = -logf((float)(NPB + MD));
  v[(size_t)b * NPB + n] = nrm - (mx + logf(s));
}

// ---------------- P = exp(M + u + v - norm), rows 0..63 ----------------
__global__ void k_compute_p(const float* __restrict__ Sc, const float* __restrict__ u,
                            const float* __restrict__ v, float* __restrict__ P) {
  size_t idx = (size_t)blockIdx.x * 256 + threadIdx.x;  // B*64*4096
  int b = (int)(idx >> 18), k = (int)((idx >> 12) & 63), n = (int)(idx & 4095);
  const float nrm = -logf((float)(NPB + MD));
  float lp = Sc[((size_t)(b * MA) + k) * NPB + n] + u[b * MA + k] + v[(size_t)b * NPB + n] - nrm;
  P[idx] = expf(lp);
}

// ---------------- pooled stage 1: partial[b][j][c][k] over 64-n chunks ----------------
// out[c][k] = sum_n F[n][c] * P[k][n] ; F = FS[b][n][0:128], per-batch 128x64x4096 GEMM
__global__ __launch_bounds__(256)
void k_pooled1(const float* __restrict__ FS, const float* __restrict__ P,
               float* __restrict__ partial) {
  __shared__ float Fs[64][132];   // [n][c], pad keeps float4 align, breaks stride
  __shared__ float Ps[64][68];    // [k][n]
  int b = blockIdx.x >> 6, j = blockIdx.x & 63;
  int n0 = j << 6;
  int tid = threadIdx.x;
  // load Fs: 64 rows(n) x 128 cols(c)
  {
    int r = tid >> 5;            // 0..7
    int c4 = (tid & 31) << 2;    // 0..124
    #pragma unroll
    for (int i = 0; i < 8; ++i) {
      int n = r + (i << 3);
      float4 v = *(const float4*)&FS[((size_t)(b * NPB + n0 + n)) * N2 + c4];
      *(float4*)&Fs[n][c4] = v;
    }
  }
  // load Ps: 64 rows(k) x 64 cols(n)
  {
    int r = tid >> 4;            // 0..15
    int c4 = (tid & 15) << 2;    // 0..60
    #pragma unroll
    for (int i = 0; i < 4; ++i) {
      int k = r + (i << 4);
      float4 v = *(const float4*)&P[((size_t)(b * MD + k)) * NPB + n0 + c4];
      *(float4*)&Ps[k][c4] = v;
    }
  }
  __syncthreads();
  int tc = tid & 31, tk = tid >> 5;   // c-tile 0..31 (x4), k-tile 0..7 (x8)
  int c0 = tc << 2, k0 = tk << 3;
  float acc[4][8];
  #pragma unroll
  for (int i = 0; i < 4; ++i)
    #pragma unroll
    for (int kk = 0; kk < 8; ++kk) acc[i][kk] = 0.f;
  for (int n = 0; n < 64; ++n) {
    float4 f = *(const float4*)&Fs[n][c0];
    float pv[8];
    #pragma unroll
    for (int kk = 0; kk < 8; ++kk) pv[kk] = Ps[k0 + kk][n];  // same-addr broadcast
    #pragma unroll
    for (int i = 0; i < 4; ++i) {
      float fv = ((const float*)&f)[i];
      #pragma unroll
      for (int kk = 0; kk < 8; ++kk) acc[i][kk] += fv * pv[kk];
    }
  }
  float* dst = partial + ((size_t)(b * 64 + j) << 13);   // [128c][64k]
  #pragma unroll
  for (int i = 0; i < 4; ++i) {
    float4 lo = {acc[i][0], acc[i][1], acc[i][2], acc[i][3]};
    float4 hi = {acc[i][4], acc[i][5], acc[i][6], acc[i][7]};
    *(float4*)&dst[((c0 + i) << 6) + k0] = lo;
    *(float4*)&dst[((c0 + i) << 6) + k0 + 4] = hi;
  }
}

// ---------------- pooled stage 2: reduce 64 partials, coalesced ----------------
__global__ void k_pooled2(const float* __restrict__ partial, float* __restrict__ pooled) {
  int o = blockIdx.x * 256 + threadIdx.x;    // 4*128*64 = 32768
  int b = o >> 13, rem = o & 8191;
  const float* src = partial + ((size_t)b << 19) + rem;
  float s = 0.f;
  #pragma unroll 8
  for (int j = 0; j < 64; ++j) s += src[(size_t)j << 13];
  pooled[o] = s;
}

// ---------------- patch output: l2norm over c (128), write [b][c*64+k] --------------
__global__ void k_patch_out(const float* __restrict__ pooled, float* __restrict__ out) {
  int b = blockIdx.x >> 6, k = blockIdx.x & 63;
  int tid = threadIdx.x;  // 64 threads
  float v0 = pooled[((size_t)(b * 128) + tid) * MD + k];
  float v1 = pooled[((size_t)(b * 128) + 64 + tid) * MD + k];
  float ss = v0 * v0 + v1 * v1;
  #pragma unroll
  for (int o = 32; o; o >>= 1) ss += __shfl_down(ss, o);
  ss = __shfl(ss, 0);
  float inv = 1.f / fmaxf(sqrtf(ss), 1e-12f);
  out[(size_t)b * 8704 + tid * 64 + k] = v0 * inv;
  out[(size_t)b * 8704 + (64 + tid) * 64 + k] = v1 * inv;
}

// ---------------- cam/reg layer 1: H1[80][1024] = ReLU(X @ W1 + b1) ----------------
__global__ __launch_bounds__(256)
void k_cr1(const float* __restrict__ tokens,
           const float* __restrict__ camw1, const float* __restrict__ camb1,
           const float* __restrict__ regw1, const float* __restrict__ regb1,
           float* __restrict__ H1) {
  __shared__ float xs[4][CDIM];
  int g = blockIdx.x;               // 0..19 : rows 4g..4g+3 (0..15 cam, 16..79 reg)
  bool cam = (g < 4);
  const float* W = cam ? camw1 : regw1;
  const float* bias = cam ? camb1 : regb1;
  for (int r = 0; r < 4; ++r) {
    int rr = g * 4 + r;
    const float* src;
    if (rr < 16) { int b = rr >> 2, s = rr & 3; src = tokens + ((size_t)(b * S_ + s) * NTOK) * CDIM; }
    else { int r2 = rr - 16; int b = r2 >> 4, q = r2 & 15, s = q >> 2, t = (q & 3) + 1;
           src = tokens + ((size_t)(b * S_ + s) * NTOK + t) * CDIM; }
    for (int c = threadIdx.x; c < CDIM; c += 256) xs[r][c] = src[c];
  }
  __syncthreads();
  int o = blockIdx.y * 256 + threadIdx.x;
  float a0 = 0.f, a1 = 0.f, a2 = 0.f, a3 = 0.f;
  #pragma unroll 8
  for (int k = 0; k < CDIM; ++k) {
    float w = W[(size_t)k * 1024 + o];
    a0 += xs[0][k] * w; a1 += xs[1][k] * w; a2 += xs[2][k] * w; a3 += xs[3][k] * w;
  }
  float bv = bias[o];
  H1[(size_t)(g * 4 + 0) * 1024 + o] = fmaxf(a0 + bv, 0.f);
  H1[(size_t)(g * 4 + 1) * 1024 + o] = fmaxf(a1 + bv, 0.f);
  H1[(size_t)(g * 4 + 2) * 1024 + o] = fmaxf(a2 + bv, 0.f);
  H1[(size_t)(g * 4 + 3) * 1024 + o] = fmaxf(a3 + bv, 0.f);
}

// ---------------- cam/reg layer 2 + l2norm + clip^p: hp[80][512] ----------------
__global__ __launch_bounds__(512)
void k_cr2(const float* __restrict__ H1,
           const float* __restrict__ camw2, const float* __restrict__ camb2,
           const float* __restrict__ regw2, const float* __restrict__ regb2,
           const float* __restrict__ camp, const float* __restrict__ regp,
           float* __restrict__ hp) {
  __shared__ float h1s[1024];
  __shared__ float red[8];
  int row = blockIdx.x;
  bool cam = (row < 16);
  const float* W = cam ? camw2 : regw2;
  const float* bias = cam ? camb2 : regb2;
  float p = cam ? camp[0] : regp[0];
  for (int k = threadIdx.x; k < 1024; k += 512) h1s[k] = H1[(size_t)row * 1024 + k];
  __syncthreads();
  int o = threadIdx.x;
  float acc = 0.f;
  #pragma unroll 8
  for (int k = 0; k < 1024; ++k) acc += h1s[k] * W[(size_t)k * 512 + o];
  acc += bias[o];
  float ss = acc * acc;
  #pragma unroll
  for (int of = 32; of; of >>= 1) ss += __shfl_down(ss, of);
  if ((threadIdx.x & 63) == 0) red[threadIdx.x >> 6] = ss;
  __syncthreads();
  float tot = 0.f;
  #pragma unroll
  for (int i = 0; i < 8; ++i) tot += red[i];
  float inv = 1.f / fmaxf(sqrtf(tot), 1e-12f);
  float t = fmaxf(acc * inv, 1e-6f);
  hp[(size_t)row * 512 + o] = powf(t, p);
}

// ---------------- cam/reg GeM finalize + layers 3/4 + l2norm ----------------
__global__ __launch_bounds__(256)
void k_cr3(const float* __restrict__ hp,
           const float* __restrict__ camp, const float* __restrict__ camw3,
           const float* __restrict__ camb3, const float* __restrict__ camw4,
           const float* __restrict__ camb4,
           const float* __restrict__ regp, const float* __restrict__ regw3,
           const float* __restrict__ regb3, const float* __restrict__ regw4,
           const float* __restrict__ regb4,
           float* __restrict__ out) {
  __shared__ float gs[512];
  __shared__ float o1s[512];
  __shared__ float red[4];
  int path = blockIdx.x >> 2, b = blockIdx.x & 3;
  bool cam = (path == 0);
  const float* W3 = cam ? camw3 : regw3;
  const float* B3 = cam ? camb3 : regb3;
  const float* W4 = cam ? camw4 : regw4;
  const float* B4 = cam ? camb4 : regb4;
  float p = cam ? camp[0] : regp[0];
  int L = cam ? 4 : 16;
  int row0 = cam ? b * 4 : 16 + b * 16;
  for (int o = threadIdx.x; o < 512; o += 256) {
    float s = 0.f;
    for (int r = 0; r < 16; ++r) if (r < L) s += hp[(size_t)(row0 + r) * 512 + o];
    gs[o] = powf(s / (float)L, 1.f / p);
  }
  __syncthreads();
  for (int o = threadIdx.x; o < 512; o += 256) {
    float acc = 0.f;
    #pragma unroll 8
    for (int k = 0; k < 512; ++k) acc += gs[k] * W3[(size_t)k * 512 + o];
    o1s[o] = fmaxf(acc + B3[o], 0.f);
  }
  __syncthreads();
  int o = threadIdx.x;
  float acc = 0.f;
  #pragma unroll 8
  for (int k = 0; k < 512; ++k) acc += o1s[k] * W4[(size_t)k * 256 + o];
  acc += B4[o];
  float ss = acc * acc;
  #pragma unroll
  for (int of = 32; of; of >>= 1) ss += __shfl_down(ss, of);
  if ((threadIdx.x & 63) == 0) red[threadIdx.x >> 6] = ss;
  __syncthreads();
  float tot = red[0] + red[1] + red[2] + red[3];
  float inv = 1.f / fmaxf(sqrtf(tot), 1e-12f);
  out[(size_t)b * 8704 + 8192 + path * 256 + o] = acc * inv;
}

// ---------------- workspace layout (bytes) ----------------
#define OFF_ABF 0u                        // 16384*2048*2 = 67,108,864 (reused after GEMM1)
#define OFF_SC 0u                         // B*65*4096*4 = 4,259,840
#define OFF_U 4259840u
#define OFF_V 4263936u                    // B*4096*4 = 65,536
#define OFF_P 4329472u                    // B*64*4096*4 = 4,194,304
#define OFF_POOL 8523776u                 // B*128*64*4 = 131,072
#define OFF_H1 8654848u                   // 80*1024*4 = 327,680
#define OFF_HP 8982528u                   // 80*512*4 = 163,840
#define OFF_H 67108864u                   // 16384*1024*2 = 33,554,432 (dead after GEMM2)
#define OFF_PART OFF_H                    // B*64*128*64*4 = 8,388,608 (reuses H region)
#define OFF_FS 100663296u                 // 16384*256*4 = 16,777,216
#define OFF_W1T 117440512u                // 1024*2048*2 = 4,194,304
#define OFF_W2T 121634816u                // 256*1024*2 = 524,288
#define OFF_B1C 122159104u                // 4096
#define OFF_B2C 122163200u                // 1024

extern "C" void kernel_launch(void* const* d_in, const int* in_sizes, int n_in,
                              void* d_out, int out_size, void* d_ws, size_t ws_size,
                              hipStream_t stream) {
  (void)in_sizes; (void)n_in; (void)out_size; (void)ws_size;
  const float* tokens = (const float*)d_in[0];
  const float* cam_w1 = (const float*)d_in[2];
  const float* cam_b1 = (const float*)d_in[3];
  const float* cam_w2 = (const float*)d_in[4];
  const float* cam_b2 = (const float*)d_in[5];
  const float* cam_p  = (const float*)d_in[6];
  const float* cam_w3 = (const float*)d_in[7];
  const float* cam_b3 = (const float*)d_in[8];
  const float* cam_w4 = (const float*)d_in[9];
  const float* cam_b4 = (const float*)d_in[10];
  const float* reg_w1 = (const float*)d_in[11];
  const float* reg_b1 = (const float*)d_in[12];
  const float* reg_w2 = (const float*)d_in[13];
  const float* reg_b2 = (const float*)d_in[14];
  const float* reg_p  = (const float*)d_in[15];
  const float* reg_w3 = (const float*)d_in[16];
  const float* reg_b3 = (const float*)d_in[17];
  const float* reg_w4 = (const float*)d_in[18];
  const float* reg_b4 = (const float*)d_in[19];
  const float* pf_w1  = (const float*)d_in[20];
  const float* pf_b1  = (const float*)d_in[21];
  const float* pf_w2  = (const float*)d_in[22];
  const float* pf_b2  = (const float*)d_in[23];
  const float* ps_w1  = (const float*)d_in[24];
  const float* ps_b1  = (const float*)d_in[25];
  const float* ps_w2  = (const float*)d_in[26];
  const float* ps_b2  = (const float*)d_in[27];
  const float* dust   = (const float*)d_in[28];
  float* out = (float*)d_out;
  char* ws = (char*)d_ws;

  u16* Abf = (u16*)(ws + OFF_ABF);
  float* Sc = (float*)(ws + OFF_SC);
  float* ub = (float*)(ws + OFF_U);
  float* vb = (float*)(ws + OFF_V);
  float* P  = (float*)(ws + OFF_P);
  float* pooled = (float*)(ws + OFF_POOL);
  float* H1 = (float*)(ws + OFF_H1);
  float* hp = (float*)(ws + OFF_HP);
  u16* H   = (u16*)(ws + OFF_H);
  float* partial = (float*)(ws + OFF_PART);
  float* FS = (float*)(ws + OFF_FS);
  u16* W1t = (u16*)(ws + OFF_W1T);
  u16* W2t = (u16*)(ws + OFF_W2T);
  float* b1c = (float*)(ws + OFF_B1C);
  float* b2c = (float*)(ws + OFF_B2C);

  hipMemsetAsync(vb, 0, (size_t)B_ * NPB * sizeof(float), stream);
  k_convert_patch<<<16384, 256, 0, stream>>>(tokens, Abf);
  k_pack_w1t<<<dim3(64, 32), dim3(32, 8), 0, stream>>>(pf_w1, ps_w1, W1t);
  k_pack_w2t<<<dim3(32, 8), dim3(32, 8), 0, stream>>>(pf_w2, ps_w2, W2t);
  k_pack_bias<<<4, 256, 0, stream>>>(pf_b1, ps_b1, pf_b2, ps_b2, b1c, b2c);

  k_gemm<1, 1><<<dim3(128, 8), 256, 0, stream>>>(Abf, W1t, b1c, (void*)H, MROWS, N1, CDIM);
  k_gemm<0, 0><<<dim3(128, 2), 256, 0, stream>>>(H, W2t, b2c, (void*)FS, MROWS, N2, N1);

  k_cr1<<<dim3(20, 4), 256, 0, stream>>>(tokens, cam_w1, cam_b1, reg_w1, reg_b1, H1);
  k_cr2<<<80, 512, 0, stream>>>(H1, cam_w2, cam_b2, reg_w2, reg_b2, cam_p, reg_p, hp);

  k_tr_scores<<<256, 256, 0, stream>>>(FS, dust, Sc);
  for (int it = 0; it < 3; ++it) {
    k_sink_u<<<B_ * MA, 256, 0, stream>>>(Sc, vb, ub);
    k_sink_v<<<B_ * 16, 256, 0, stream>>>(Sc, ub, vb);
  }
  k_compute_p<<<4096, 256, 0, stream>>>(Sc, ub, vb, P);
  k_pooled1<<<B_ * 64, 256, 0, stream>>>(FS, P, partial);
  k_pooled2<<<128, 256, 0, stream>>>(partial, pooled);
  k_patch_out<<<B_ * MD, 64, 0, stream>>>(pooled, out);
  k_cr3<<<8, 256, 0, stream>>>(hp, cam_p, cam_w3, cam_b3, cam_w4, cam_b4,
                               reg_p, reg_w3, reg_b3, reg_w4, reg_b4, out);
}

// Round 5
// 354.633 us; speedup vs baseline: 2.0544x; 1.3607x over previous
//
#include <hip/hip_runtime.h>

typedef unsigned short u16;
typedef unsigned int u32;

#define B_ 4
#define S_ 4
#define NTOK 1029
#define CDIM 2048
#define PSI 5
#define NPB 4096
#define MROWS 16384
#define N1 1024
#define N2 256
#define MD 64
#define MA 65

using bf16x8 = __attribute__((ext_vector_type(8))) short;
using f32x4  = __attribute__((ext_vector_type(4))) float;
using u16x8  = __attribute__((ext_vector_type(8))) unsigned short;

typedef __attribute__((address_space(1))) const void global_cvoid;
typedef __attribute__((address_space(3))) void lds_void;

__device__ __forceinline__ u16 f2b(float f) {
  u32 u = __builtin_bit_cast(u32, f);
  u32 r = (u + 0x7fffu + ((u >> 16) & 1u)) >> 16;
  return (u16)r;
}

// ---------------- prep: gather patch tokens, convert fp32 -> bf16 ----------------
__global__ void k_convert_patch(const float* __restrict__ tokens, u16* __restrict__ Abf) {
  size_t idx = (size_t)blockIdx.x * 256 + threadIdx.x;   // over MROWS*256 vec8 units
  size_t r = idx >> 8;
  int cv = (int)(idx & 255) << 3;
  int b = (int)(r >> 12), s = (int)((r >> 10) & 3), j = (int)(r & 1023);
  const float* src = tokens + ((size_t)((b * S_ + s) * NTOK + PSI + j)) * CDIM + cv;
  float4 v0 = *(const float4*)src;
  float4 v1 = *(const float4*)(src + 4);
  u16x8 o;
  o[0] = f2b(v0.x); o[1] = f2b(v0.y); o[2] = f2b(v0.z); o[3] = f2b(v0.w);
  o[4] = f2b(v1.x); o[5] = f2b(v1.y); o[6] = f2b(v1.z); o[7] = f2b(v1.w);
  *(u16x8*)(Abf + r * CDIM + cv) = o;
}

// ---------------- prep: transpose+convert combined W1 [2048,1024] -> W1t [1024][2048] bf16
__global__ void k_pack_w1t(const float* __restrict__ pfw1, const float* __restrict__ psw1,
                           u16* __restrict__ W1t) {
  __shared__ float tile[32][33];
  int kb = blockIdx.x * 32, nb = blockIdx.y * 32;
  int tx = threadIdx.x, ty = threadIdx.y;  // (32, 8)
  #pragma unroll
  for (int i = 0; i < 4; ++i) {
    int k = kb + ty + i * 8, n = nb + tx;
    float v = (n < 512) ? pfw1[(size_t)k * 512 + n] : psw1[(size_t)k * 512 + (n - 512)];
    tile[ty + i * 8][tx] = v;
  }
  __syncthreads();
  #pragma unroll
  for (int i = 0; i < 4; ++i) {
    int n = nb + ty + i * 8, k = kb + tx;
    W1t[(size_t)n * CDIM + k] = f2b(tile[tx][ty + i * 8]);
  }
}

// ---------------- prep: block-diagonal W2 [1024,256pad] -> W2t [256][1024] bf16
__global__ void k_pack_w2t(const float* __restrict__ pfw2, const float* __restrict__ psw2,
                           u16* __restrict__ W2t) {
  __shared__ float tile[32][33];
  int kb = blockIdx.x * 32, jb = blockIdx.y * 32;
  int tx = threadIdx.x, ty = threadIdx.y;  // (32, 8)
  #pragma unroll
  for (int i = 0; i < 4; ++i) {
    int k = kb + ty + i * 8, j = jb + tx;
    float v = 0.f;
    if (j < 128) { if (k < 512) v = pfw2[(size_t)k * 128 + j]; }
    else if (j < 192) { if (k >= 512) v = psw2[(size_t)(k - 512) * 64 + (j - 128)]; }
    tile[ty + i * 8][tx] = v;
  }
  __syncthreads();
  #pragma unroll
  for (int i = 0; i < 4; ++i) {
    int j = jb + ty + i * 8, k = kb + tx;
    W2t[(size_t)j * N1 + k] = f2b(tile[tx][ty + i * 8]);
  }
}

// ---------------- generic transpose-pack: dst[n][k] (bf16) = src[k][n] (f32) ----------
__global__ void k_pack_wt(const float* __restrict__ src, u16* __restrict__ dst,
                          int N, int dstride) {
  __shared__ float tile[32][33];
  int kb = blockIdx.x * 32, nb = blockIdx.y * 32;
  int tx = threadIdx.x, ty = threadIdx.y;  // (32, 8)
  #pragma unroll
  for (int i = 0; i < 4; ++i)
    tile[ty + i * 8][tx] = src[(size_t)(kb + ty + i * 8) * N + nb + tx];
  __syncthreads();
  #pragma unroll
  for (int i = 0; i < 4; ++i)
    dst[(size_t)(nb + ty + i * 8) * dstride + kb + tx] = f2b(tile[tx][ty + i * 8]);
}

__global__ void k_pack_bias(const float* __restrict__ pfb1, const float* __restrict__ psb1,
                            const float* __restrict__ pfb2, const float* __restrict__ psb2,
                            float* __restrict__ b1c, float* __restrict__ b2c) {
  int t = blockIdx.x * 256 + threadIdx.x;
  if (t < 1024) b1c[t] = (t < 512) ? pfb1[t] : psb1[t - 512];
  if (t < 256)  b2c[t] = (t < 128) ? pfb2[t] : ((t < 192) ? psb2[t - 128] : 0.f);
}

// ---------------- pack cam/reg token rows -> Acr bf16 [128][2048] (zero pad 80+) ------
__global__ void k_pack_across(const float* __restrict__ tokens, u16* __restrict__ Acr) {
  int r = blockIdx.x;               // 0..127
  int c0 = threadIdx.x << 3;        // 256 thr x 8
  u16x8 o;
  if (r >= 80) {
    #pragma unroll
    for (int i = 0; i < 8; ++i) o[i] = 0;
  } else {
    const float* src;
    if (r < 16) { int b = r >> 2, s = r & 3; src = tokens + ((size_t)(b * S_ + s) * NTOK) * CDIM; }
    else { int r2 = r - 16; int b = r2 >> 4, q = r2 & 15, s = q >> 2, t = (q & 3) + 1;
           src = tokens + ((size_t)(b * S_ + s) * NTOK + t) * CDIM; }
    float4 v0 = *(const float4*)(src + c0);
    float4 v1 = *(const float4*)(src + c0 + 4);
    o[0] = f2b(v0.x); o[1] = f2b(v0.y); o[2] = f2b(v0.z); o[3] = f2b(v0.w);
    o[4] = f2b(v1.x); o[5] = f2b(v1.y); o[6] = f2b(v1.z); o[7] = f2b(v1.w);
  }
  *(u16x8*)(Acr + (size_t)r * CDIM + c0) = o;
}

// ---------------- bf16 MFMA GEMM:  C[M,N] = A[M,K] @ Bt[N,K]^T  (+bias, opt ReLU) ---
// 128x128 tile, BK=64, 4 waves (2x2), m97 2-barrier structure with global_load_lds w16.
template <int RELU, int OUTBF>
__global__ __launch_bounds__(256, 2)
void k_gemm(const u16* __restrict__ A, const u16* __restrict__ Bt,
            const float* __restrict__ bias, void* __restrict__ Cout,
            int M, int N, int K) {
  __shared__ u16 As[128 * 64];
  __shared__ u16 Bs[128 * 64];
  const int tid = threadIdx.x;
  const int lane = tid & 63;
  const int wave = tid >> 6;
  const int tM = blockIdx.x << 7;
  const int tN = blockIdx.y << 7;
  const int wr = wave >> 1, wc = wave & 1;

  const int srow = (wave << 3) + (lane >> 3);     // staging row within 32-row band
  const int scol = (lane & 7) << 3;               // staging col (k)
  const size_t abase = (size_t)(tM + srow) * K + scol;
  const size_t bbase = (size_t)(tN + srow) * K + scol;
  u16* asw = &As[(wave << 9) + (lane << 3)];
  u16* bsw = &Bs[(wave << 9) + (lane << 3)];

  f32x4 acc[4][4];
  #pragma unroll
  for (int i = 0; i < 4; ++i)
    #pragma unroll
    for (int j = 0; j < 4; ++j)
      acc[i][j] = (f32x4){0.f, 0.f, 0.f, 0.f};

  for (int k0 = 0; k0 < K; k0 += 64) {
    #pragma unroll
    for (int r = 0; r < 4; ++r) {
      __builtin_amdgcn_global_load_lds(
          (global_cvoid*)(A + abase + (size_t)(r * 32) * K + k0),
          (lds_void*)(asw + r * 2048), 16, 0, 0);
      __builtin_amdgcn_global_load_lds(
          (global_cvoid*)(Bt + bbase + (size_t)(r * 32) * K + k0),
          (lds_void*)(bsw + r * 2048), 16, 0, 0);
    }
    __syncthreads();   // drains vmcnt before barrier
    #pragma unroll
    for (int kk = 0; kk < 64; kk += 32) {
      bf16x8 af[4], bfr[4];
      #pragma unroll
      for (int i = 0; i < 4; ++i) {
        af[i]  = *(const bf16x8*)&As[((wr << 6) + (i << 4) + (lane & 15)) * 64 + kk + ((lane >> 4) << 3)];
        bfr[i] = *(const bf16x8*)&Bs[((wc << 6) + (i << 4) + (lane & 15)) * 64 + kk + ((lane >> 4) << 3)];
      }
      #pragma unroll
      for (int mi = 0; mi < 4; ++mi)
        #pragma unroll
        for (int ni = 0; ni < 4; ++ni)
          acc[mi][ni] = __builtin_amdgcn_mfma_f32_16x16x32_bf16(af[mi], bfr[ni], acc[mi][ni], 0, 0, 0);
    }
    __syncthreads();
  }

  #pragma unroll
  for (int ni = 0; ni < 4; ++ni) {
    const int col = tN + (wc << 6) + (ni << 4) + (lane & 15);
    const float bv = bias[col];
    #pragma unroll
    for (int mi = 0; mi < 4; ++mi) {
      #pragma unroll
      for (int j = 0; j < 4; ++j) {
        const int row = tM + (wr << 6) + (mi << 4) + ((lane >> 4) << 2) + j;
        float vv = acc[mi][ni][j] + bv;
        if (RELU) vv = fmaxf(vv, 0.f);
        if (OUTBF) ((u16*)Cout)[(size_t)row * N + col] = f2b(vv);
        else       ((float*)Cout)[(size_t)row * N + col] = vv;
      }
    }
  }
}

// ---------------- split-K MFMA GEMM, M=128 fixed: part[kc][128][N] (f32, no bias) ----
__global__ __launch_bounds__(256, 2)
void k_gemm_splitk(const u16* __restrict__ A, const u16* __restrict__ Bt,
                   float* __restrict__ part, int N, int K, int KC) {
  __shared__ u16 As[128 * 64];
  __shared__ u16 Bs[128 * 64];
  const int tid = threadIdx.x;
  const int lane = tid & 63;
  const int wave = tid >> 6;
  const int tN = blockIdx.y << 7;
  const int kb = blockIdx.z * KC;
  const int wr = wave >> 1, wc = wave & 1;

  const int srow = (wave << 3) + (lane >> 3);
  const int scol = (lane & 7) << 3;
  const size_t abase = (size_t)srow * K + scol;
  const size_t bbase = (size_t)(tN + srow) * K + scol;
  u16* asw = &As[(wave << 9) + (lane << 3)];
  u16* bsw = &Bs[(wave << 9) + (lane << 3)];

  f32x4 acc[4][4];
  #pragma unroll
  for (int i = 0; i < 4; ++i)
    #pragma unroll
    for (int j = 0; j < 4; ++j)
      acc[i][j] = (f32x4){0.f, 0.f, 0.f, 0.f};

  for (int k0 = kb; k0 < kb + KC; k0 += 64) {
    #pragma unroll
    for (int r = 0; r < 4; ++r) {
      __builtin_amdgcn_global_load_lds(
          (global_cvoid*)(A + abase + (size_t)(r * 32) * K + k0),
          (lds_void*)(asw + r * 2048), 16, 0, 0);
      __builtin_amdgcn_global_load_lds(
          (global_cvoid*)(Bt + bbase + (size_t)(r * 32) * K + k0),
          (lds_void*)(bsw + r * 2048), 16, 0, 0);
    }
    __syncthreads();
    #pragma unroll
    for (int kk = 0; kk < 64; kk += 32) {
      bf16x8 af[4], bfr[4];
      #pragma unroll
      for (int i = 0; i < 4; ++i) {
        af[i]  = *(const bf16x8*)&As[((wr << 6) + (i << 4) + (lane & 15)) * 64 + kk + ((lane >> 4) << 3)];
        bfr[i] = *(const bf16x8*)&Bs[((wc << 6) + (i << 4) + (lane & 15)) * 64 + kk + ((lane >> 4) << 3)];
      }
      #pragma unroll
      for (int mi = 0; mi < 4; ++mi)
        #pragma unroll
        for (int ni = 0; ni < 4; ++ni)
          acc[mi][ni] = __builtin_amdgcn_mfma_f32_16x16x32_bf16(af[mi], bfr[ni], acc[mi][ni], 0, 0, 0);
    }
    __syncthreads();
  }

  float* dst = part + (size_t)blockIdx.z * 128 * N;
  #pragma unroll
  for (int ni = 0; ni < 4; ++ni) {
    const int col = tN + (wc << 6) + (ni << 4) + (lane & 15);
    #pragma unroll
    for (int mi = 0; mi < 4; ++mi) {
      #pragma unroll
      for (int j = 0; j < 4; ++j) {
        const int row = (wr << 6) + (mi << 4) + ((lane >> 4) << 2) + j;
        dst[(size_t)row * N + col] = acc[mi][ni][j];
      }
    }
  }
}

// ---------------- cr fin1: reduce part1(kc=8) + bias + relu -> A2 bf16 [128][1024] ----
__global__ void k_cr_fin1(const float* __restrict__ part1,
                          const float* __restrict__ camb1, const float* __restrict__ regb1,
                          u16* __restrict__ A2) {
  int r = blockIdx.x;                       // 0..127
  int j = blockIdx.y * 256 + threadIdx.x;   // 0..1023
  if (r >= 80) { A2[(size_t)r * N1 + j] = 0; return; }
  bool cam = (r < 16);
  int cm = j + (cam ? 0 : 1024);
  float s = 0.f;
  #pragma unroll
  for (int kc = 0; kc < 8; ++kc) s += part1[((size_t)kc * 128 + r) * 2048 + cm];
  s += cam ? camb1[j] : regb1[j];
  A2[(size_t)r * N1 + j] = f2b(fmaxf(s, 0.f));
}

// ---------------- cr fin2: reduce part2(kc=8) + bias + l2norm + clip^p -> hp[80][512] -
__global__ __launch_bounds__(512)
void k_cr_fin2(const float* __restrict__ part2,
               const float* __restrict__ camb2, const float* __restrict__ regb2,
               const float* __restrict__ camp, const float* __restrict__ regp,
               float* __restrict__ hp) {
  __shared__ float red[8];
  int r = blockIdx.x;      // 0..79
  int j = threadIdx.x;     // 0..511
  bool cam = (r < 16);
  int cm = j + (cam ? 0 : 512);
  float s = 0.f;
  #pragma unroll
  for (int kc = 0; kc < 8; ++kc) s += part2[((size_t)kc * 128 + r) * 1024 + cm];
  s += cam ? camb2[j] : regb2[j];
  float ss = s * s;
  #pragma unroll
  for (int o = 32; o; o >>= 1) ss += __shfl_down(ss, o);
  if ((j & 63) == 0) red[j >> 6] = ss;
  __syncthreads();
  float tot = 0.f;
  #pragma unroll
  for (int i = 0; i < 8; ++i) tot += red[i];
  float inv = 1.f / fmaxf(sqrtf(tot), 1e-12f);
  float t = fmaxf(s * inv, 1e-6f);
  hp[(size_t)r * 512 + j] = powf(t, cam ? camp[0] : regp[0]);
}

// ---------------- scores transpose: FS[:,128:192] -> Sc[B][65][4096] (+dust row) ----
__global__ void k_tr_scores(const float* __restrict__ FS, const float* __restrict__ dust,
                            float* __restrict__ Sc) {
  __shared__ float t[64][65];
  int b = blockIdx.x >> 6, n0 = (blockIdx.x & 63) * 64;
  int tx = threadIdx.x & 63, ty = threadIdx.x >> 6;   // 64 x 4
  for (int r = ty; r < 64; r += 4)
    t[r][tx] = FS[((size_t)(b * NPB + n0 + r)) * N2 + 128 + tx];
  __syncthreads();
  for (int k = ty; k < 64; k += 4)
    Sc[((size_t)(b * MA) + k) * NPB + n0 + tx] = t[tx][k];
  if (threadIdx.x < 64)
    Sc[((size_t)(b * MA) + 64) * NPB + n0 + threadIdx.x] = dust[0];
}

// ---------------- sinkhorn: u update (row LSE over n=4096) ----------------
__global__ void k_sink_u(const float* __restrict__ Sc, const float* __restrict__ v,
                         float* __restrict__ u) {
  __shared__ float red[4];
  int b = blockIdx.x / MA, k = blockIdx.x % MA;
  const float* row = Sc + ((size_t)(b * MA) + k) * NPB;
  const float* vb = v + (size_t)b * NPB;
  int tid = threadIdx.x;
  float mx = -1e30f;
  for (int n = tid; n < NPB; n += 256) mx = fmaxf(mx, row[n] + vb[n]);
  #pragma unroll
  for (int o = 32; o; o >>= 1) mx = fmaxf(mx, __shfl_down(mx, o));
  if ((tid & 63) == 0) red[tid >> 6] = mx;
  __syncthreads();
  mx = fmaxf(fmaxf(red[0], red[1]), fmaxf(red[2], red[3]));
  float s = 0.f;
  for (int n = tid; n < NPB; n += 256) s += expf(row[n] + vb[n] - mx);
  #pragma unroll
  for (int o = 32; o; o >>= 1) s += __shfl_down(s, o);
  __syncthreads();
  if ((tid & 63) == 0) red[tid >> 6] = s;
  __syncthreads();
  if (tid == 0) {
    float ssum = red[0] + red[1] + red[2] + red[3];
    const float nrm = -logf((float)(NPB + MD));
    float la = (k == MD) ? (nrm + logf((float)(NPB - MD))) : nrm;
    u[b * MA + k] = la - (mx + logf(ssum));
  }
}

// ---------------- sinkhorn: v update (col LSE over m+1=65) ----------------
__global__ void k_sink_v(const float* __restrict__ Sc, const float* __restrict__ u,
                         float* __restrict__ v) {
  __shared__ float us[MA];
  int b = blockIdx.x >> 4;
  int n = ((blockIdx.x & 15) << 8) + threadIdx.x;
  if (threadIdx.x < MA) us[threadIdx.x] = u[b * MA + threadIdx.x];
  __syncthreads();
  const float* Sb = Sc + (size_t)b * MA * NPB + n;
  float mx = -1e30f;
  for (int k = 0; k < MA; ++k) mx = fmaxf(mx, Sb[(size_t)k * NPB] + us[k]);
  float s = 0.f;
  for (int k = 0; k < MA; ++k) s += expf(Sb[(size_t)k * NPB] + us[k] - mx);
  const float nrm = -logf((float)(NPB + MD));
  v[(size_t)b * NPB + n] = nrm - (mx + logf(s));
}

// ---------------- P = exp(M + u + v - norm), rows 0..63 ----------------
__global__ void k_compute_p(const float* __restrict__ Sc, const float* __restrict__ u,
                            const float* __restrict__ v, float* __restrict__ P) {
  size_t idx = (size_t)blockIdx.x * 256 + threadIdx.x;  // B*64*4096
  int b = (int)(idx >> 18), k = (int)((idx >> 12) & 63), n = (int)(idx & 4095);
  const float nrm = -logf((float)(NPB + MD));
  float lp = Sc[((size_t)(b * MA) + k) * NPB + n] + u[b * MA + k] + v[(size_t)b * NPB + n] - nrm;
  P[idx] = expf(lp);
}

// ---------------- pooled stage 1: partial[b][j][c][k] over 64-n chunks ----------------
__global__ __launch_bounds__(256)
void k_pooled1(const float* __restrict__ FS, const float* __restrict__ P,
               float* __restrict__ partial) {
  __shared__ float Fs[64][132];
  __shared__ float Ps[64][68];
  int b = blockIdx.x >> 6, j = blockIdx.x & 63;
  int n0 = j << 6;
  int tid = threadIdx.x;
  {
    int r = tid >> 5;
    int c4 = (tid & 31) << 2;
    #pragma unroll
    for (int i = 0; i < 8; ++i) {
      int n = r + (i << 3);
      float4 v = *(const float4*)&FS[((size_t)(b * NPB + n0 + n)) * N2 + c4];
      *(float4*)&Fs[n][c4] = v;
    }
  }
  {
    int r = tid >> 4;
    int c4 = (tid & 15) << 2;
    #pragma unroll
    for (int i = 0; i < 4; ++i) {
      int k = r + (i << 4);
      float4 v = *(const float4*)&P[((size_t)(b * MD + k)) * NPB + n0 + c4];
      *(float4*)&Ps[k][c4] = v;
    }
  }
  __syncthreads();
  int tc = tid & 31, tk = tid >> 5;
  int c0 = tc << 2, k0 = tk << 3;
  float acc[4][8];
  #pragma unroll
  for (int i = 0; i < 4; ++i)
    #pragma unroll
    for (int kk = 0; kk < 8; ++kk) acc[i][kk] = 0.f;
  for (int n = 0; n < 64; ++n) {
    float4 f = *(const float4*)&Fs[n][c0];
    float pv[8];
    #pragma unroll
    for (int kk = 0; kk < 8; ++kk) pv[kk] = Ps[k0 + kk][n];
    #pragma unroll
    for (int i = 0; i < 4; ++i) {
      float fv = ((const float*)&f)[i];
      #pragma unroll
      for (int kk = 0; kk < 8; ++kk) acc[i][kk] += fv * pv[kk];
    }
  }
  float* dst = partial + ((size_t)(b * 64 + j) << 13);
  #pragma unroll
  for (int i = 0; i < 4; ++i) {
    float4 lo = {acc[i][0], acc[i][1], acc[i][2], acc[i][3]};
    float4 hi = {acc[i][4], acc[i][5], acc[i][6], acc[i][7]};
    *(float4*)&dst[((c0 + i) << 6) + k0] = lo;
    *(float4*)&dst[((c0 + i) << 6) + k0 + 4] = hi;
  }
}

// ---------------- pooled stage 2: reduce 64 partials, coalesced ----------------
__global__ void k_pooled2(const float* __restrict__ partial, float* __restrict__ pooled) {
  int o = blockIdx.x * 256 + threadIdx.x;    // 4*128*64 = 32768
  int b = o >> 13, rem = o & 8191;
  const float* src = partial + ((size_t)b << 19) + rem;
  float s = 0.f;
  #pragma unroll 8
  for (int j = 0; j < 64; ++j) s += src[(size_t)j << 13];
  pooled[o] = s;
}

// ---------------- patch output: l2norm over c (128), write [b][c*64+k] --------------
__global__ void k_patch_out(const float* __restrict__ pooled, float* __restrict__ out) {
  int b = blockIdx.x >> 6, k = blockIdx.x & 63;
  int tid = threadIdx.x;  // 64 threads
  float v0 = pooled[((size_t)(b * 128) + tid) * MD + k];
  float v1 = pooled[((size_t)(b * 128) + 64 + tid) * MD + k];
  float ss = v0 * v0 + v1 * v1;
  #pragma unroll
  for (int o = 32; o; o >>= 1) ss += __shfl_down(ss, o);
  ss = __shfl(ss, 0);
  float inv = 1.f / fmaxf(sqrtf(ss), 1e-12f);
  out[(size_t)b * 8704 + tid * 64 + k] = v0 * inv;
  out[(size_t)b * 8704 + (64 + tid) * 64 + k] = v1 * inv;
}

// ---------------- cam/reg GeM finalize + layers 3/4 + l2norm ----------------
__global__ __launch_bounds__(256)
void k_cr3(const float* __restrict__ hp,
           const float* __restrict__ camp, const float* __restrict__ camw3,
           const float* __restrict__ camb3, const float* __restrict__ camw4,
           const float* __restrict__ camb4,
           const float* __restrict__ regp, const float* __restrict__ regw3,
           const float* __restrict__ regb3, const float* __restrict__ regw4,
           const float* __restrict__ regb4,
           float* __restrict__ out) {
  __shared__ float gs[512];
  __shared__ float o1s[512];
  __shared__ float red[4];
  int path = blockIdx.x >> 2, b = blockIdx.x & 3;
  bool cam = (path == 0);
  const float* W3 = cam ? camw3 : regw3;
  const float* B3 = cam ? camb3 : regb3;
  const float* W4 = cam ? camw4 : regw4;
  const float* B4 = cam ? camb4 : regb4;
  float p = cam ? camp[0] : regp[0];
  int L = cam ? 4 : 16;
  int row0 = cam ? b * 4 : 16 + b * 16;
  for (int o = threadIdx.x; o < 512; o += 256) {
    float s = 0.f;
    for (int r = 0; r < 16; ++r) if (r < L) s += hp[(size_t)(row0 + r) * 512 + o];
    gs[o] = powf(s / (float)L, 1.f / p);
  }
  __syncthreads();
  for (int o = threadIdx.x; o < 512; o += 256) {
    float acc = 0.f;
    #pragma unroll 8
    for (int k = 0; k < 512; ++k) acc += gs[k] * W3[(size_t)k * 512 + o];
    o1s[o] = fmaxf(acc + B3[o], 0.f);
  }
  __syncthreads();
  int o = threadIdx.x;
  float acc = 0.f;
  #pragma unroll 8
  for (int k = 0; k < 512; ++k) acc += o1s[k] * W4[(size_t)k * 256 + o];
  acc += B4[o];
  float ss = acc * acc;
  #pragma unroll
  for (int of = 32; of; of >>= 1) ss += __shfl_down(ss, of);
  if ((threadIdx.x & 63) == 0) red[threadIdx.x >> 6] = ss;
  __syncthreads();
  float tot = red[0] + red[1] + red[2] + red[3];
  float inv = 1.f / fmaxf(sqrtf(tot), 1e-12f);
  out[(size_t)b * 8704 + 8192 + path * 256 + o] = acc * inv;
}

// ---------------- workspace layout (bytes) ----------------
// NOTE lifetime rule: everything below 67,108,864 overlaps Abf (live until GEMM1 done);
// 67,108,864..100,663,296 overlaps H (live GEMM1->GEMM2). The cr path therefore runs
// AFTER k_gemm<0,0> (both Abf and H dead).  [R4 bug: hp written pre-GEMM1 corrupted Abf]
#define OFF_ABF 0u                        // 16384*2048*2 = 67,108,864
#define OFF_SC 0u                         // B*65*4096*4 = 4,259,840
#define OFF_U 4259840u
#define OFF_V 4263936u                    // B*4096*4 = 65,536
#define OFF_P 4329472u                    // B*64*4096*4 = 4,194,304
#define OFF_POOL 8523776u                 // B*128*64*4 = 131,072
#define OFF_HP 8982528u                   // 80*512*4 = 163,840 (written post-GEMM2 only!)
#define OFF_H 67108864u                   // 16384*1024*2 = 33,554,432
#define OFF_PART OFF_H                    // pooled partial: 8,388,608
#define OFF_CP1 75497472u                 // cr part1: 8*128*2048*4 = 8,388,608
#define OFF_CP2 83886080u                 // cr part2: 8*128*1024*4 = 4,194,304
#define OFF_BT1CR 88080384u               // 2048*2048*2 = 8,388,608
#define OFF_BT2CR 96468992u               // 1024*1024*2 = 2,097,152
#define OFF_ACR 98566144u                 // 128*2048*2 = 524,288
#define OFF_A2 99090432u                  // 128*1024*2 = 262,144 (ends 99,352,576)
#define OFF_FS 100663296u                 // 16384*256*4 = 16,777,216
#define OFF_W1T 117440512u                // 1024*2048*2 = 4,194,304
#define OFF_W2T 121634816u                // 256*1024*2 = 524,288
#define OFF_B1C 122159104u
#define OFF_B2C 122163200u

extern "C" void kernel_launch(void* const* d_in, const int* in_sizes, int n_in,
                              void* d_out, int out_size, void* d_ws, size_t ws_size,
                              hipStream_t stream) {
  (void)in_sizes; (void)n_in; (void)out_size; (void)ws_size;
  const float* tokens = (const float*)d_in[0];
  const float* cam_w1 = (const float*)d_in[2];
  const float* cam_b1 = (const float*)d_in[3];
  const float* cam_w2 = (const float*)d_in[4];
  const float* cam_b2 = (const float*)d_in[5];
  const float* cam_p  = (const float*)d_in[6];
  const float* cam_w3 = (const float*)d_in[7];
  const float* cam_b3 = (const float*)d_in[8];
  const float* cam_w4 = (const float*)d_in[9];
  const float* cam_b4 = (const float*)d_in[10];
  const float* reg_w1 = (const float*)d_in[11];
  const float* reg_b1 = (const float*)d_in[12];
  const float* reg_w2 = (const float*)d_in[13];
  const float* reg_b2 = (const float*)d_in[14];
  const float* reg_p  = (const float*)d_in[15];
  const float* reg_w3 = (const float*)d_in[16];
  const float* reg_b3 = (const float*)d_in[17];
  const float* reg_w4 = (const float*)d_in[18];
  const float* reg_b4 = (const float*)d_in[19];
  const float* pf_w1  = (const float*)d_in[20];
  const float* pf_b1  = (const float*)d_in[21];
  const float* pf_w2  = (const float*)d_in[22];
  const float* pf_b2  = (const float*)d_in[23];
  const float* ps_w1  = (const float*)d_in[24];
  const float* ps_b1  = (const float*)d_in[25];
  const float* ps_w2  = (const float*)d_in[26];
  const float* ps_b2  = (const float*)d_in[27];
  const float* dust   = (const float*)d_in[28];
  float* out = (float*)d_out;
  char* ws = (char*)d_ws;

  u16* Abf = (u16*)(ws + OFF_ABF);
  float* Sc = (float*)(ws + OFF_SC);
  float* ub = (float*)(ws + OFF_U);
  float* vb = (float*)(ws + OFF_V);
  float* P  = (float*)(ws + OFF_P);
  float* pooled = (float*)(ws + OFF_POOL);
  float* hp = (float*)(ws + OFF_HP);
  u16* H   = (u16*)(ws + OFF_H);
  float* partial = (float*)(ws + OFF_PART);
  float* cp1 = (float*)(ws + OFF_CP1);
  float* cp2 = (float*)(ws + OFF_CP2);
  u16* Bt1cr = (u16*)(ws + OFF_BT1CR);
  u16* Bt2cr = (u16*)(ws + OFF_BT2CR);
  u16* Acr = (u16*)(ws + OFF_ACR);
  u16* A2  = (u16*)(ws + OFF_A2);
  float* FS = (float*)(ws + OFF_FS);
  u16* W1t = (u16*)(ws + OFF_W1T);
  u16* W2t = (u16*)(ws + OFF_W2T);
  float* b1c = (float*)(ws + OFF_B1C);
  float* b2c = (float*)(ws + OFF_B2C);

  hipMemsetAsync(vb, 0, (size_t)B_ * NPB * sizeof(float), stream);

  // ---- patch packs + GEMMs ----
  k_convert_patch<<<16384, 256, 0, stream>>>(tokens, Abf);
  k_pack_w1t<<<dim3(64, 32), dim3(32, 8), 0, stream>>>(pf_w1, ps_w1, W1t);
  k_pack_w2t<<<dim3(32, 8), dim3(32, 8), 0, stream>>>(pf_w2, ps_w2, W2t);
  k_pack_bias<<<4, 256, 0, stream>>>(pf_b1, ps_b1, pf_b2, ps_b2, b1c, b2c);

  k_gemm<1, 1><<<dim3(128, 8), 256, 0, stream>>>(Abf, W1t, b1c, (void*)H, MROWS, N1, CDIM);
  k_gemm<0, 0><<<dim3(128, 2), 256, 0, stream>>>(H, W2t, b2c, (void*)FS, MROWS, N2, N1);

  // ---- cam/reg path (Abf and H regions now dead) ----
  k_pack_wt<<<dim3(64, 32), dim3(32, 8), 0, stream>>>(cam_w1, Bt1cr, 1024, CDIM);
  k_pack_wt<<<dim3(64, 32), dim3(32, 8), 0, stream>>>(reg_w1, Bt1cr + (size_t)1024 * CDIM, 1024, CDIM);
  k_pack_wt<<<dim3(32, 16), dim3(32, 8), 0, stream>>>(cam_w2, Bt2cr, 512, N1);
  k_pack_wt<<<dim3(32, 16), dim3(32, 8), 0, stream>>>(reg_w2, Bt2cr + (size_t)512 * N1, 512, N1);
  k_pack_across<<<128, 256, 0, stream>>>(tokens, Acr);
  k_gemm_splitk<<<dim3(1, 16, 8), 256, 0, stream>>>(Acr, Bt1cr, cp1, 2048, CDIM, 256);
  k_cr_fin1<<<dim3(128, 4), 256, 0, stream>>>(cp1, cam_b1, reg_b1, A2);
  k_gemm_splitk<<<dim3(1, 8, 8), 256, 0, stream>>>(A2, Bt2cr, cp2, 1024, N1, 128);
  k_cr_fin2<<<80, 512, 0, stream>>>(cp2, cam_b2, reg_b2, cam_p, reg_p, hp);

  // ---- sinkhorn + pooled + outputs ----
  k_tr_scores<<<256, 256, 0, stream>>>(FS, dust, Sc);
  for (int it = 0; it < 3; ++it) {
    k_sink_u<<<B_ * MA, 256, 0, stream>>>(Sc, vb, ub);
    k_sink_v<<<B_ * 16, 256, 0, stream>>>(Sc, ub, vb);
  }
  k_compute_p<<<4096, 256, 0, stream>>>(Sc, ub, vb, P);
  k_pooled1<<<B_ * 64, 256, 0, stream>>>(FS, P, partial);
  k_pooled2<<<128, 256, 0, stream>>>(partial, pooled);
  k_patch_out<<<B_ * MD, 64, 0, stream>>>(pooled, out);
  k_cr3<<<8, 256, 0, stream>>>(hp, cam_p, cam_w3, cam_b3, cam_w4, cam_b4,
                               reg_p, reg_w3, reg_b3, reg_w4, reg_b4, out);
}

// Round 6
// 318.685 us; speedup vs baseline: 2.2861x; 1.1128x over previous
//
#include <hip/hip_runtime.h>

typedef unsigned short u16;
typedef unsigned int u32;

#define B_ 4
#define S_ 4
#define NTOK 1029
#define CDIM 2048
#define PSI 5
#define NPB 4096
#define MROWS 16384
#define N1 1024
#define N2 256
#define MD 64
#define MA 65

using bf16x8 = __attribute__((ext_vector_type(8))) short;
using f32x4  = __attribute__((ext_vector_type(4))) float;
using u16x8  = __attribute__((ext_vector_type(8))) unsigned short;

typedef __attribute__((address_space(1))) const void global_cvoid;
typedef __attribute__((address_space(3))) void lds_void;

__device__ __forceinline__ u16 f2b(float f) {
  u32 u = __builtin_bit_cast(u32, f);
  u32 r = (u + 0x7fffu + ((u >> 16) & 1u)) >> 16;
  return (u16)r;
}

// ---------------- prep: gather patch tokens, convert fp32 -> bf16 ----------------
__global__ void k_convert_patch(const float* __restrict__ tokens, u16* __restrict__ Abf) {
  size_t idx = (size_t)blockIdx.x * 256 + threadIdx.x;
  size_t r = idx >> 8;
  int cv = (int)(idx & 255) << 3;
  int b = (int)(r >> 12), s = (int)((r >> 10) & 3), j = (int)(r & 1023);
  const float* src = tokens + ((size_t)((b * S_ + s) * NTOK + PSI + j)) * CDIM + cv;
  float4 v0 = *(const float4*)src;
  float4 v1 = *(const float4*)(src + 4);
  u16x8 o;
  o[0] = f2b(v0.x); o[1] = f2b(v0.y); o[2] = f2b(v0.z); o[3] = f2b(v0.w);
  o[4] = f2b(v1.x); o[5] = f2b(v1.y); o[6] = f2b(v1.z); o[7] = f2b(v1.w);
  *(u16x8*)(Abf + r * CDIM + cv) = o;
}

// ---------------- merged patch-side packs: W1t, W2t, biases ----------------
// blocks [0,2048): W1t tiles; [2048,2304): W2t tiles; [2304,2308): biases
__global__ void k_pack_patch(const float* __restrict__ pfw1, const float* __restrict__ psw1,
                             const float* __restrict__ pfw2, const float* __restrict__ psw2,
                             const float* __restrict__ pfb1, const float* __restrict__ psb1,
                             const float* __restrict__ pfb2, const float* __restrict__ psb2,
                             u16* __restrict__ W1t, u16* __restrict__ W2t,
                             float* __restrict__ b1c, float* __restrict__ b2c) {
  __shared__ float tile[32][33];
  int id = blockIdx.x, tid = threadIdx.x;
  int tx = tid & 31, ty = tid >> 5;
  if (id < 2048) {
    int kb = (id & 63) * 32, nb = (id >> 6) * 32;
    #pragma unroll
    for (int i = 0; i < 4; ++i) {
      int k = kb + ty + i * 8, n = nb + tx;
      tile[ty + i * 8][tx] = (n < 512) ? pfw1[(size_t)k * 512 + n] : psw1[(size_t)k * 512 + (n - 512)];
    }
    __syncthreads();
    #pragma unroll
    for (int i = 0; i < 4; ++i) {
      int n = nb + ty + i * 8, k = kb + tx;
      W1t[(size_t)n * CDIM + k] = f2b(tile[tx][ty + i * 8]);
    }
  } else if (id < 2304) {
    int i2 = id - 2048;
    int kb = (i2 & 31) * 32, jb = (i2 >> 5) * 32;
    #pragma unroll
    for (int i = 0; i < 4; ++i) {
      int k = kb + ty + i * 8, j = jb + tx;
      float v = 0.f;
      if (j < 128) { if (k < 512) v = pfw2[(size_t)k * 128 + j]; }
      else if (j < 192) { if (k >= 512) v = psw2[(size_t)(k - 512) * 64 + (j - 128)]; }
      tile[ty + i * 8][tx] = v;
    }
    __syncthreads();
    #pragma unroll
    for (int i = 0; i < 4; ++i) {
      int j = jb + ty + i * 8, k = kb + tx;
      W2t[(size_t)j * N1 + k] = f2b(tile[tx][ty + i * 8]);
    }
  } else {
    int t = (id - 2304) * 256 + tid;
    if (t < 1024) b1c[t] = (t < 512) ? pfb1[t] : psb1[t - 512];
    if (t < 256)  b2c[t] = (t < 128) ? pfb2[t] : ((t < 192) ? psb2[t - 128] : 0.f);
  }
}

// ---------------- merged cr-side packs: Bt1cr, Bt2cr, Acr ----------------
// [0,2048) camw1; [2048,4096) regw1; [4096,4608) camw2; [4608,5120) regw2; [5120,5248) Acr
__global__ void k_pack_cr(const float* __restrict__ camw1, const float* __restrict__ regw1,
                          const float* __restrict__ camw2, const float* __restrict__ regw2,
                          const float* __restrict__ tokens,
                          u16* __restrict__ Bt1cr, u16* __restrict__ Bt2cr,
                          u16* __restrict__ Acr) {
  __shared__ float tile[32][33];
  int id = blockIdx.x, tid = threadIdx.x;
  int tx = tid & 31, ty = tid >> 5;
  if (id < 4096) {
    const float* src = (id < 2048) ? camw1 : regw1;
    u16* dst = Bt1cr + ((id < 2048) ? 0 : (size_t)1024 * CDIM);
    int i2 = id & 2047;
    int kb = (i2 & 63) * 32, nb = (i2 >> 6) * 32;
    #pragma unroll
    for (int i = 0; i < 4; ++i)
      tile[ty + i * 8][tx] = src[(size_t)(kb + ty + i * 8) * 1024 + nb + tx];
    __syncthreads();
    #pragma unroll
    for (int i = 0; i < 4; ++i)
      dst[(size_t)(nb + ty + i * 8) * CDIM + kb + tx] = f2b(tile[tx][ty + i * 8]);
  } else if (id < 5120) {
    int i3 = id - 4096;
    const float* src = (i3 < 512) ? camw2 : regw2;
    u16* dst = Bt2cr + ((i3 < 512) ? 0 : (size_t)512 * N1);
    int i2 = i3 & 511;
    int kb = (i2 & 31) * 32, nb = (i2 >> 5) * 32;
    #pragma unroll
    for (int i = 0; i < 4; ++i)
      tile[ty + i * 8][tx] = src[(size_t)(kb + ty + i * 8) * 512 + nb + tx];
    __syncthreads();
    #pragma unroll
    for (int i = 0; i < 4; ++i)
      dst[(size_t)(nb + ty + i * 8) * N1 + kb + tx] = f2b(tile[tx][ty + i * 8]);
  } else {
    int r = id - 5120;               // 0..127
    int c0 = tid << 3;
    u16x8 o;
    if (r >= 80) {
      #pragma unroll
      for (int i = 0; i < 8; ++i) o[i] = 0;
    } else {
      const float* src;
      if (r < 16) { int b = r >> 2, s = r & 3; src = tokens + ((size_t)(b * S_ + s) * NTOK) * CDIM; }
      else { int r2 = r - 16; int b = r2 >> 4, q = r2 & 15, s = q >> 2, t = (q & 3) + 1;
             src = tokens + ((size_t)(b * S_ + s) * NTOK + t) * CDIM; }
      float4 v0 = *(const float4*)(src + c0);
      float4 v1 = *(const float4*)(src + c0 + 4);
      o[0] = f2b(v0.x); o[1] = f2b(v0.y); o[2] = f2b(v0.z); o[3] = f2b(v0.w);
      o[4] = f2b(v1.x); o[5] = f2b(v1.y); o[6] = f2b(v1.z); o[7] = f2b(v1.w);
    }
    *(u16x8*)(Acr + (size_t)r * CDIM + c0) = o;
  }
}

// ---------------- bf16 MFMA GEMM, 2-phase explicit double-buffer ----------------
// 128x128 tile, BK=64, 4 waves. Stage t+1 issued BEFORE compute of t; one barrier/K-step.
#define STAGE_TILE(buf, k0)                                                    \
  {                                                                            \
    _Pragma("unroll")                                                          \
    for (int r = 0; r < 4; ++r) {                                              \
      __builtin_amdgcn_global_load_lds(                                        \
          (global_cvoid*)(A + abase + (size_t)(r * 32) * K + (k0)),            \
          (lds_void*)(&As[buf][lofs + r * 2048]), 16, 0, 0);                   \
      __builtin_amdgcn_global_load_lds(                                        \
          (global_cvoid*)(Bt + bbase + (size_t)(r * 32) * K + (k0)),           \
          (lds_void*)(&Bs[buf][lofs + r * 2048]), 16, 0, 0);                   \
    }                                                                          \
  }

#define COMPUTE_TILE(buf)                                                      \
  {                                                                            \
    _Pragma("unroll")                                                          \
    for (int kk = 0; kk < 64; kk += 32) {                                      \
      bf16x8 af[4], bfr[4];                                                    \
      _Pragma("unroll")                                                        \
      for (int i = 0; i < 4; ++i) {                                            \
        af[i]  = *(const bf16x8*)&As[buf][((wr << 6) + (i << 4) + (lane & 15)) * 64 + kk + hi8]; \
        bfr[i] = *(const bf16x8*)&Bs[buf][((wc << 6) + (i << 4) + (lane & 15)) * 64 + kk + hi8]; \
      }                                                                        \
      _Pragma("unroll")                                                        \
      for (int mi = 0; mi < 4; ++mi)                                           \
        _Pragma("unroll")                                                      \
        for (int ni = 0; ni < 4; ++ni)                                         \
          acc[mi][ni] = __builtin_amdgcn_mfma_f32_16x16x32_bf16(af[mi], bfr[ni], acc[mi][ni], 0, 0, 0); \
    }                                                                          \
  }

template <int RELU, int OUTBF>
__global__ __launch_bounds__(256, 2)
void k_gemm(const u16* __restrict__ A, const u16* __restrict__ Bt,
            const float* __restrict__ bias, void* __restrict__ Cout,
            int M, int N, int K) {
  __shared__ u16 As[2][128 * 64];
  __shared__ u16 Bs[2][128 * 64];
  const int tid = threadIdx.x;
  const int lane = tid & 63;
  const int wave = tid >> 6;
  const int tM = blockIdx.x << 7;
  const int tN = blockIdx.y << 7;
  const int wr = wave >> 1, wc = wave & 1;
  const int hi8 = (lane >> 4) << 3;

  const int srow = (wave << 3) + (lane >> 3);
  const int scol = (lane & 7) << 3;
  const size_t abase = (size_t)(tM + srow) * K + scol;
  const size_t bbase = (size_t)(tN + srow) * K + scol;
  const int lofs = (wave << 9) + (lane << 3);

  f32x4 acc[4][4];
  #pragma unroll
  for (int i = 0; i < 4; ++i)
    #pragma unroll
    for (int j = 0; j < 4; ++j)
      acc[i][j] = (f32x4){0.f, 0.f, 0.f, 0.f};

  const int nt = K >> 6;            // even for all our K (2048, 1024)
  STAGE_TILE(0, 0)
  __syncthreads();
  for (int t = 0; t < nt; t += 2) {
    if (t + 1 < nt) STAGE_TILE(1, (t + 1) << 6)
    COMPUTE_TILE(0)
    __syncthreads();                 // drains vmcnt (t+1 landed) + barrier
    if (t + 1 < nt) {
      if (t + 2 < nt) STAGE_TILE(0, (t + 2) << 6)
      COMPUTE_TILE(1)
      __syncthreads();
    }
  }

  #pragma unroll
  for (int ni = 0; ni < 4; ++ni) {
    const int col = tN + (wc << 6) + (ni << 4) + (lane & 15);
    const float bv = bias[col];
    #pragma unroll
    for (int mi = 0; mi < 4; ++mi) {
      #pragma unroll
      for (int j = 0; j < 4; ++j) {
        const int row = tM + (wr << 6) + (mi << 4) + ((lane >> 4) << 2) + j;
        float vv = acc[mi][ni][j] + bv;
        if (RELU) vv = fmaxf(vv, 0.f);
        if (OUTBF) ((u16*)Cout)[(size_t)row * N + col] = f2b(vv);
        else       ((float*)Cout)[(size_t)row * N + col] = vv;
      }
    }
  }
}

// ---------------- split-K MFMA GEMM, M=128 fixed (single-buffer, known-good) ----
__global__ __launch_bounds__(256, 2)
void k_gemm_splitk(const u16* __restrict__ A, const u16* __restrict__ Bt,
                   float* __restrict__ part, int N, int K, int KC) {
  __shared__ u16 As1[128 * 64];
  __shared__ u16 Bs1[128 * 64];
  const int tid = threadIdx.x;
  const int lane = tid & 63;
  const int wave = tid >> 6;
  const int tN = blockIdx.y << 7;
  const int kb = blockIdx.z * KC;
  const int wr = wave >> 1, wc = wave & 1;
  const int srow = (wave << 3) + (lane >> 3);
  const int scol = (lane & 7) << 3;
  const size_t abase = (size_t)srow * K + scol;
  const size_t bbase = (size_t)(tN + srow) * K + scol;
  u16* asw = &As1[(wave << 9) + (lane << 3)];
  u16* bsw = &Bs1[(wave << 9) + (lane << 3)];

  f32x4 acc[4][4];
  #pragma unroll
  for (int i = 0; i < 4; ++i)
    #pragma unroll
    for (int j = 0; j < 4; ++j)
      acc[i][j] = (f32x4){0.f, 0.f, 0.f, 0.f};

  for (int k0 = kb; k0 < kb + KC; k0 += 64) {
    #pragma unroll
    for (int r = 0; r < 4; ++r) {
      __builtin_amdgcn_global_load_lds(
          (global_cvoid*)(A + abase + (size_t)(r * 32) * K + k0),
          (lds_void*)(asw + r * 2048), 16, 0, 0);
      __builtin_amdgcn_global_load_lds(
          (global_cvoid*)(Bt + bbase + (size_t)(r * 32) * K + k0),
          (lds_void*)(bsw + r * 2048), 16, 0, 0);
    }
    __syncthreads();
    #pragma unroll
    for (int kk = 0; kk < 64; kk += 32) {
      bf16x8 af[4], bfr[4];
      #pragma unroll
      for (int i = 0; i < 4; ++i) {
        af[i]  = *(const bf16x8*)&As1[((wr << 6) + (i << 4) + (lane & 15)) * 64 + kk + ((lane >> 4) << 3)];
        bfr[i] = *(const bf16x8*)&Bs1[((wc << 6) + (i << 4) + (lane & 15)) * 64 + kk + ((lane >> 4) << 3)];
      }
      #pragma unroll
      for (int mi = 0; mi < 4; ++mi)
        #pragma unroll
        for (int ni = 0; ni < 4; ++ni)
          acc[mi][ni] = __builtin_amdgcn_mfma_f32_16x16x32_bf16(af[mi], bfr[ni], acc[mi][ni], 0, 0, 0);
    }
    __syncthreads();
  }

  float* dst = part + (size_t)blockIdx.z * 128 * N;
  #pragma unroll
  for (int ni = 0; ni < 4; ++ni) {
    const int col = tN + (wc << 6) + (ni << 4) + (lane & 15);
    #pragma unroll
    for (int mi = 0; mi < 4; ++mi) {
      #pragma unroll
      for (int j = 0; j < 4; ++j) {
        const int row = (wr << 6) + (mi << 4) + ((lane >> 4) << 2) + j;
        dst[(size_t)row * N + col] = acc[mi][ni][j];
      }
    }
  }
}

// ---------------- cr fin1: reduce part1(kc=8) + bias + relu -> A2 bf16 [128][1024] ----
__global__ void k_cr_fin1(const float* __restrict__ part1,
                          const float* __restrict__ camb1, const float* __restrict__ regb1,
                          u16* __restrict__ A2) {
  int r = blockIdx.x;
  int j = blockIdx.y * 256 + threadIdx.x;
  if (r >= 80) { A2[(size_t)r * N1 + j] = 0; return; }
  bool cam = (r < 16);
  int cm = j + (cam ? 0 : 1024);
  float s = 0.f;
  #pragma unroll
  for (int kc = 0; kc < 8; ++kc) s += part1[((size_t)kc * 128 + r) * 2048 + cm];
  s += cam ? camb1[j] : regb1[j];
  A2[(size_t)r * N1 + j] = f2b(fmaxf(s, 0.f));
}

// ---------------- cr fin2: reduce part2(kc=8) + bias + l2norm + clip^p -> hp[80][512] -
__global__ __launch_bounds__(512)
void k_cr_fin2(const float* __restrict__ part2,
               const float* __restrict__ camb2, const float* __restrict__ regb2,
               const float* __restrict__ camp, const float* __restrict__ regp,
               float* __restrict__ hp) {
  __shared__ float red[8];
  int r = blockIdx.x;
  int j = threadIdx.x;
  bool cam = (r < 16);
  int cm = j + (cam ? 0 : 512);
  float s = 0.f;
  #pragma unroll
  for (int kc = 0; kc < 8; ++kc) s += part2[((size_t)kc * 128 + r) * 1024 + cm];
  s += cam ? camb2[j] : regb2[j];
  float ss = s * s;
  #pragma unroll
  for (int o = 32; o; o >>= 1) ss += __shfl_down(ss, o);
  if ((j & 63) == 0) red[j >> 6] = ss;
  __syncthreads();
  float tot = 0.f;
  #pragma unroll
  for (int i = 0; i < 8; ++i) tot += red[i];
  float inv = 1.f / fmaxf(sqrtf(tot), 1e-12f);
  float t = fmaxf(s * inv, 1e-6f);
  hp[(size_t)r * 512 + j] = powf(t, cam ? camp[0] : regp[0]);
}

// ---------------- scores transpose: FS[:,128:192] -> Sc[B][65][4096] (+dust row) ----
__global__ void k_tr_scores(const float* __restrict__ FS, const float* __restrict__ dust,
                            float* __restrict__ Sc) {
  __shared__ float t[64][65];
  int b = blockIdx.x >> 6, n0 = (blockIdx.x & 63) * 64;
  int tx = threadIdx.x & 63, ty = threadIdx.x >> 6;
  for (int r = ty; r < 64; r += 4)
    t[r][tx] = FS[((size_t)(b * NPB + n0 + r)) * N2 + 128 + tx];
  __syncthreads();
  for (int k = ty; k < 64; k += 4)
    Sc[((size_t)(b * MA) + k) * NPB + n0 + tx] = t[tx][k];
  if (threadIdx.x < 64)
    Sc[((size_t)(b * MA) + 64) * NPB + n0 + threadIdx.x] = dust[0];
}

// ---------------- sinkhorn: u update — one-pass online LSE over n=4096 ----------------
__global__ void k_sink_u(const float* __restrict__ Sc, const float* __restrict__ v,
                         float* __restrict__ u) {
  __shared__ float redm[4], reds[4];
  int b = blockIdx.x / MA, k = blockIdx.x % MA;
  const float* row = Sc + ((size_t)(b * MA) + k) * NPB;
  const float* vb = v + (size_t)b * NPB;
  int tid = threadIdx.x;
  float mx = -1e30f, s = 0.f;
  for (int n = tid; n < NPB; n += 256) {
    float x = row[n] + vb[n];
    float m2 = fmaxf(mx, x);
    s = s * __expf(mx - m2) + __expf(x - m2);
    mx = m2;
  }
  #pragma unroll
  for (int o = 32; o; o >>= 1) {
    float mo = __shfl_down(mx, o), so = __shfl_down(s, o);
    float m2 = fmaxf(mx, mo);
    s = s * __expf(mx - m2) + so * __expf(mo - m2);
    mx = m2;
  }
  if ((tid & 63) == 0) { redm[tid >> 6] = mx; reds[tid >> 6] = s; }
  __syncthreads();
  if (tid == 0) {
    float M = redm[0];
    #pragma unroll
    for (int i = 1; i < 4; ++i) M = fmaxf(M, redm[i]);
    float S = 0.f;
    #pragma unroll
    for (int i = 0; i < 4; ++i) S += reds[i] * __expf(redm[i] - M);
    const float nrm = -logf((float)(NPB + MD));
    float la = (k == MD) ? (nrm + logf((float)(NPB - MD))) : nrm;
    u[b * MA + k] = la - (M + __logf(S));
  }
}

// ---------------- sinkhorn: v update (col LSE over m+1=65) ----------------
__global__ void k_sink_v(const float* __restrict__ Sc, const float* __restrict__ u,
                         float* __restrict__ v) {
  __shared__ float us[MA];
  int b = blockIdx.x >> 4;
  int n = ((blockIdx.x & 15) << 8) + threadIdx.x;
  if (threadIdx.x < MA) us[threadIdx.x] = u[b * MA + threadIdx.x];
  __syncthreads();
  const float* Sb = Sc + (size_t)b * MA * NPB + n;
  float mx = -1e30f;
  for (int k = 0; k < MA; ++k) mx = fmaxf(mx, Sb[(size_t)k * NPB] + us[k]);
  float s = 0.f;
  for (int k = 0; k < MA; ++k) s += __expf(Sb[(size_t)k * NPB] + us[k] - mx);
  const float nrm = -logf((float)(NPB + MD));
  v[(size_t)b * NPB + n] = nrm - (mx + __logf(s));
}

// ---------------- pooled stage 1 (P fused): partial[b][j][c][k] over 64-n chunks ------
__global__ __launch_bounds__(256)
void k_pooled1(const float* __restrict__ FS, const float* __restrict__ Sc,
               const float* __restrict__ u, const float* __restrict__ v,
               float* __restrict__ partial) {
  __shared__ float Fs[64][132];
  __shared__ float Ps[64][68];
  int b = blockIdx.x >> 6, j = blockIdx.x & 63;
  int n0 = j << 6;
  int tid = threadIdx.x;
  {
    int r = tid >> 5;
    int c4 = (tid & 31) << 2;
    #pragma unroll
    for (int i = 0; i < 8; ++i) {
      int n = r + (i << 3);
      float4 vv = *(const float4*)&FS[((size_t)(b * NPB + n0 + n)) * N2 + c4];
      *(float4*)&Fs[n][c4] = vv;
    }
  }
  {
    const float nrm = -logf((float)(NPB + MD));
    int r = tid >> 4;
    int c4 = (tid & 15) << 2;
    #pragma unroll
    for (int i = 0; i < 4; ++i) {
      int k = r + (i << 4);
      float uk = u[b * MA + k];
      float4 sv = *(const float4*)&Sc[((size_t)(b * MA) + k) * NPB + n0 + c4];
      float4 vv = *(const float4*)&v[(size_t)b * NPB + n0 + c4];
      float4 o;
      o.x = __expf(sv.x + uk + vv.x - nrm);
      o.y = __expf(sv.y + uk + vv.y - nrm);
      o.z = __expf(sv.z + uk + vv.z - nrm);
      o.w = __expf(sv.w + uk + vv.w - nrm);
      *(float4*)&Ps[k][c4] = o;
    }
  }
  __syncthreads();
  int tc = tid & 31, tk = tid >> 5;
  int c0 = tc << 2, k0 = tk << 3;
  float acc[4][8];
  #pragma unroll
  for (int i = 0; i < 4; ++i)
    #pragma unroll
    for (int kk = 0; kk < 8; ++kk) acc[i][kk] = 0.f;
  for (int n = 0; n < 64; ++n) {
    float4 f = *(const float4*)&Fs[n][c0];
    float pv[8];
    #pragma unroll
    for (int kk = 0; kk < 8; ++kk) pv[kk] = Ps[k0 + kk][n];
    #pragma unroll
    for (int i = 0; i < 4; ++i) {
      float fv = ((const float*)&f)[i];
      #pragma unroll
      for (int kk = 0; kk < 8; ++kk) acc[i][kk] += fv * pv[kk];
    }
  }
  float* dst = partial + ((size_t)(b * 64 + j) << 13);
  #pragma unroll
  for (int i = 0; i < 4; ++i) {
    float4 lo = {acc[i][0], acc[i][1], acc[i][2], acc[i][3]};
    float4 hi = {acc[i][4], acc[i][5], acc[i][6], acc[i][7]};
    *(float4*)&dst[((c0 + i) << 6) + k0] = lo;
    *(float4*)&dst[((c0 + i) << 6) + k0 + 4] = hi;
  }
}

// ---------------- pooled stage 2: reduce 64 partials, coalesced ----------------
__global__ void k_pooled2(const float* __restrict__ partial, float* __restrict__ pooled) {
  int o = blockIdx.x * 256 + threadIdx.x;
  int b = o >> 13, rem = o & 8191;
  const float* src = partial + ((size_t)b << 19) + rem;
  float s = 0.f;
  #pragma unroll 8
  for (int j = 0; j < 64; ++j) s += src[(size_t)j << 13];
  pooled[o] = s;
}

// ---------------- patch output: l2norm over c (128), write [b][c*64+k] --------------
__global__ void k_patch_out(const float* __restrict__ pooled, float* __restrict__ out) {
  int b = blockIdx.x >> 6, k = blockIdx.x & 63;
  int tid = threadIdx.x;
  float v0 = pooled[((size_t)(b * 128) + tid) * MD + k];
  float v1 = pooled[((size_t)(b * 128) + 64 + tid) * MD + k];
  float ss = v0 * v0 + v1 * v1;
  #pragma unroll
  for (int o = 32; o; o >>= 1) ss += __shfl_down(ss, o);
  ss = __shfl(ss, 0);
  float inv = 1.f / fmaxf(sqrtf(ss), 1e-12f);
  out[(size_t)b * 8704 + tid * 64 + k] = v0 * inv;
  out[(size_t)b * 8704 + (64 + tid) * 64 + k] = v1 * inv;
}

// ---------------- cam/reg GeM finalize + layers 3/4 + l2norm ----------------
__global__ __launch_bounds__(256)
void k_cr3(const float* __restrict__ hp,
           const float* __restrict__ camp, const float* __restrict__ camw3,
           const float* __restrict__ camb3, const float* __restrict__ camw4,
           const float* __restrict__ camb4,
           const float* __restrict__ regp, const float* __restrict__ regw3,
           const float* __restrict__ regb3, const float* __restrict__ regw4,
           const float* __restrict__ regb4,
           float* __restrict__ out) {
  __shared__ float gs[512];
  __shared__ float o1s[512];
  __shared__ float red[4];
  int path = blockIdx.x >> 2, b = blockIdx.x & 3;
  bool cam = (path == 0);
  const float* W3 = cam ? camw3 : regw3;
  const float* B3 = cam ? camb3 : regb3;
  const float* W4 = cam ? camw4 : regw4;
  const float* B4 = cam ? camb4 : regb4;
  float p = cam ? camp[0] : regp[0];
  int L = cam ? 4 : 16;
  int row0 = cam ? b * 4 : 16 + b * 16;
  for (int o = threadIdx.x; o < 512; o += 256) {
    float s = 0.f;
    for (int r = 0; r < 16; ++r) if (r < L) s += hp[(size_t)(row0 + r) * 512 + o];
    gs[o] = powf(s / (float)L, 1.f / p);
  }
  __syncthreads();
  for (int o = threadIdx.x; o < 512; o += 256) {
    float acc = 0.f;
    #pragma unroll 8
    for (int k = 0; k < 512; ++k) acc += gs[k] * W3[(size_t)k * 512 + o];
    o1s[o] = fmaxf(acc + B3[o], 0.f);
  }
  __syncthreads();
  int o = threadIdx.x;
  float acc = 0.f;
  #pragma unroll 8
  for (int k = 0; k < 512; ++k) acc += o1s[k] * W4[(size_t)k * 256 + o];
  acc += B4[o];
  float ss = acc * acc;
  #pragma unroll
  for (int of = 32; of; of >>= 1) ss += __shfl_down(ss, of);
  if ((threadIdx.x & 63) == 0) red[threadIdx.x >> 6] = ss;
  __syncthreads();
  float tot = red[0] + red[1] + red[2] + red[3];
  float inv = 1.f / fmaxf(sqrtf(tot), 1e-12f);
  out[(size_t)b * 8704 + 8192 + path * 256 + o] = acc * inv;
}

// ---------------- workspace layout (bytes) ----------------
// lifetime rule: below 67,108,864 overlaps Abf (live until GEMM1 done);
// 67,108,864..100,663,296 overlaps H (live GEMM1->GEMM2). cr path runs AFTER GEMM2.
#define OFF_ABF 0u
#define OFF_SC 0u
#define OFF_U 4259840u
#define OFF_V 4263936u
#define OFF_POOL 8523776u
#define OFF_HP 8982528u                   // written post-GEMM2 only!
#define OFF_H 67108864u
#define OFF_PART OFF_H                    // 8,388,608 (disjoint from CP1)
#define OFF_CP1 75497472u
#define OFF_CP2 83886080u
#define OFF_BT1CR 88080384u
#define OFF_BT2CR 96468992u
#define OFF_ACR 98566144u
#define OFF_A2 99090432u
#define OFF_FS 100663296u
#define OFF_W1T 117440512u
#define OFF_W2T 121634816u
#define OFF_B1C 122159104u
#define OFF_B2C 122163200u

extern "C" void kernel_launch(void* const* d_in, const int* in_sizes, int n_in,
                              void* d_out, int out_size, void* d_ws, size_t ws_size,
                              hipStream_t stream) {
  (void)in_sizes; (void)n_in; (void)out_size; (void)ws_size;
  const float* tokens = (const float*)d_in[0];
  const float* cam_w1 = (const float*)d_in[2];
  const float* cam_b1 = (const float*)d_in[3];
  const float* cam_w2 = (const float*)d_in[4];
  const float* cam_b2 = (const float*)d_in[5];
  const float* cam_p  = (const float*)d_in[6];
  const float* cam_w3 = (const float*)d_in[7];
  const float* cam_b3 = (const float*)d_in[8];
  const float* cam_w4 = (const float*)d_in[9];
  const float* cam_b4 = (const float*)d_in[10];
  const float* reg_w1 = (const float*)d_in[11];
  const float* reg_b1 = (const float*)d_in[12];
  const float* reg_w2 = (const float*)d_in[13];
  const float* reg_b2 = (const float*)d_in[14];
  const float* reg_p  = (const float*)d_in[15];
  const float* reg_w3 = (const float*)d_in[16];
  const float* reg_b3 = (const float*)d_in[17];
  const float* reg_w4 = (const float*)d_in[18];
  const float* reg_b4 = (const float*)d_in[19];
  const float* pf_w1  = (const float*)d_in[20];
  const float* pf_b1  = (const float*)d_in[21];
  const float* pf_w2  = (const float*)d_in[22];
  const float* pf_b2  = (const float*)d_in[23];
  const float* ps_w1  = (const float*)d_in[24];
  const float* ps_b1  = (const float*)d_in[25];
  const float* ps_w2  = (const float*)d_in[26];
  const float* ps_b2  = (const float*)d_in[27];
  const float* dust   = (const float*)d_in[28];
  float* out = (float*)d_out;
  char* ws = (char*)d_ws;

  u16* Abf = (u16*)(ws + OFF_ABF);
  float* Sc = (float*)(ws + OFF_SC);
  float* ub = (float*)(ws + OFF_U);
  float* vb = (float*)(ws + OFF_V);
  float* pooled = (float*)(ws + OFF_POOL);
  float* hp = (float*)(ws + OFF_HP);
  u16* H   = (u16*)(ws + OFF_H);
  float* partial = (float*)(ws + OFF_PART);
  float* cp1 = (float*)(ws + OFF_CP1);
  float* cp2 = (float*)(ws + OFF_CP2);
  u16* Bt1cr = (u16*)(ws + OFF_BT1CR);
  u16* Bt2cr = (u16*)(ws + OFF_BT2CR);
  u16* Acr = (u16*)(ws + OFF_ACR);
  u16* A2  = (u16*)(ws + OFF_A2);
  float* FS = (float*)(ws + OFF_FS);
  u16* W1t = (u16*)(ws + OFF_W1T);
  u16* W2t = (u16*)(ws + OFF_W2T);
  float* b1c = (float*)(ws + OFF_B1C);
  float* b2c = (float*)(ws + OFF_B2C);

  hipMemsetAsync(vb, 0, (size_t)B_ * NPB * sizeof(float), stream);

  // ---- patch packs + GEMMs ----
  k_convert_patch<<<16384, 256, 0, stream>>>(tokens, Abf);
  k_pack_patch<<<2308, 256, 0, stream>>>(pf_w1, ps_w1, pf_w2, ps_w2,
                                         pf_b1, ps_b1, pf_b2, ps_b2,
                                         W1t, W2t, b1c, b2c);
  k_gemm<1, 1><<<dim3(128, 8), 256, 0, stream>>>(Abf, W1t, b1c, (void*)H, MROWS, N1, CDIM);
  k_gemm<0, 0><<<dim3(128, 2), 256, 0, stream>>>(H, W2t, b2c, (void*)FS, MROWS, N2, N1);

  // ---- cam/reg path (Abf and H regions now dead) ----
  k_pack_cr<<<5248, 256, 0, stream>>>(cam_w1, reg_w1, cam_w2, reg_w2, tokens,
                                      Bt1cr, Bt2cr, Acr);
  k_gemm_splitk<<<dim3(1, 16, 8), 256, 0, stream>>>(Acr, Bt1cr, cp1, 2048, CDIM, 256);
  k_cr_fin1<<<dim3(128, 4), 256, 0, stream>>>(cp1, cam_b1, reg_b1, A2);
  k_gemm_splitk<<<dim3(1, 8, 8), 256, 0, stream>>>(A2, Bt2cr, cp2, 1024, N1, 128);
  k_cr_fin2<<<80, 512, 0, stream>>>(cp2, cam_b2, reg_b2, cam_p, reg_p, hp);

  // ---- sinkhorn + pooled + outputs ----
  k_tr_scores<<<256, 256, 0, stream>>>(FS, dust, Sc);
  for (int it = 0; it < 3; ++it) {
    k_sink_u<<<B_ * MA, 256, 0, stream>>>(Sc, vb, ub);
    k_sink_v<<<B_ * 16, 256, 0, stream>>>(Sc, ub, vb);
  }
  k_pooled1<<<B_ * 64, 256, 0, stream>>>(FS, Sc, ub, vb, partial);
  k_pooled2<<<128, 256, 0, stream>>>(partial, pooled);
  k_patch_out<<<B_ * MD, 64, 0, stream>>>(pooled, out);
  k_cr3<<<8, 256, 0, stream>>>(hp, cam_p, cam_w3, cam_b3, cam_w4, cam_b4,
                               reg_p, reg_w3, reg_b3, reg_w4, reg_b4, out);
}

// Round 7
// 260.468 us; speedup vs baseline: 2.7971x; 1.2235x over previous
//
#include <hip/hip_runtime.h>

typedef unsigned short u16;
typedef unsigned int u32;

#define B_ 4
#define S_ 4
#define NTOK 1029
#define CDIM 2048
#define PSI 5
#define NPB 4096
#define MROWS 16384
#define N1 1024
#define N2 256
#define MD 64
#define MA 65

using bf16x8 = __attribute__((ext_vector_type(8))) short;
using f32x4  = __attribute__((ext_vector_type(4))) float;
using u16x8  = __attribute__((ext_vector_type(8))) unsigned short;

typedef __attribute__((address_space(1))) const void global_cvoid;
typedef __attribute__((address_space(3))) void lds_void;

__device__ __forceinline__ u16 f2b(float f) {
  u32 u = __builtin_bit_cast(u32, f);
  u32 r = (u + 0x7fffu + ((u >> 16) & 1u)) >> 16;
  return (u16)r;
}

// ---------------- prep: gather patch tokens, convert fp32 -> bf16 ----------------
__global__ void k_convert_patch(const float* __restrict__ tokens, u16* __restrict__ Abf) {
  size_t idx = (size_t)blockIdx.x * 256 + threadIdx.x;
  size_t r = idx >> 8;
  int cv = (int)(idx & 255) << 3;
  int b = (int)(r >> 12), s = (int)((r >> 10) & 3), j = (int)(r & 1023);
  const float* src = tokens + ((size_t)((b * S_ + s) * NTOK + PSI + j)) * CDIM + cv;
  float4 v0 = *(const float4*)src;
  float4 v1 = *(const float4*)(src + 4);
  u16x8 o;
  o[0] = f2b(v0.x); o[1] = f2b(v0.y); o[2] = f2b(v0.z); o[3] = f2b(v0.w);
  o[4] = f2b(v1.x); o[5] = f2b(v1.y); o[6] = f2b(v1.z); o[7] = f2b(v1.w);
  *(u16x8*)(Abf + r * CDIM + cv) = o;
}

// ---------------- merged patch-side packs: W1t, W2t, biases ----------------
__global__ void k_pack_patch(const float* __restrict__ pfw1, const float* __restrict__ psw1,
                             const float* __restrict__ pfw2, const float* __restrict__ psw2,
                             const float* __restrict__ pfb1, const float* __restrict__ psb1,
                             const float* __restrict__ pfb2, const float* __restrict__ psb2,
                             u16* __restrict__ W1t, u16* __restrict__ W2t,
                             float* __restrict__ b1c, float* __restrict__ b2c) {
  __shared__ float tile[32][33];
  int id = blockIdx.x, tid = threadIdx.x;
  int tx = tid & 31, ty = tid >> 5;
  if (id < 2048) {
    int kb = (id & 63) * 32, nb = (id >> 6) * 32;
    #pragma unroll
    for (int i = 0; i < 4; ++i) {
      int k = kb + ty + i * 8, n = nb + tx;
      tile[ty + i * 8][tx] = (n < 512) ? pfw1[(size_t)k * 512 + n] : psw1[(size_t)k * 512 + (n - 512)];
    }
    __syncthreads();
    #pragma unroll
    for (int i = 0; i < 4; ++i) {
      int n = nb + ty + i * 8, k = kb + tx;
      W1t[(size_t)n * CDIM + k] = f2b(tile[tx][ty + i * 8]);
    }
  } else if (id < 2304) {
    int i2 = id - 2048;
    int kb = (i2 & 31) * 32, jb = (i2 >> 5) * 32;
    #pragma unroll
    for (int i = 0; i < 4; ++i) {
      int k = kb + ty + i * 8, j = jb + tx;
      float v = 0.f;
      if (j < 128) { if (k < 512) v = pfw2[(size_t)k * 128 + j]; }
      else if (j < 192) { if (k >= 512) v = psw2[(size_t)(k - 512) * 64 + (j - 128)]; }
      tile[ty + i * 8][tx] = v;
    }
    __syncthreads();
    #pragma unroll
    for (int i = 0; i < 4; ++i) {
      int j = jb + ty + i * 8, k = kb + tx;
      W2t[(size_t)j * N1 + k] = f2b(tile[tx][ty + i * 8]);
    }
  } else {
    int t = (id - 2304) * 256 + tid;
    if (t < 1024) b1c[t] = (t < 512) ? pfb1[t] : psb1[t - 512];
    if (t < 256)  b2c[t] = (t < 128) ? pfb2[t] : ((t < 192) ? psb2[t - 128] : 0.f);
  }
}

// ---------------- merged cr-side packs: Bt1cr, Bt2cr, Acr ----------------
__global__ void k_pack_cr(const float* __restrict__ camw1, const float* __restrict__ regw1,
                          const float* __restrict__ camw2, const float* __restrict__ regw2,
                          const float* __restrict__ tokens,
                          u16* __restrict__ Bt1cr, u16* __restrict__ Bt2cr,
                          u16* __restrict__ Acr) {
  __shared__ float tile[32][33];
  int id = blockIdx.x, tid = threadIdx.x;
  int tx = tid & 31, ty = tid >> 5;
  if (id < 4096) {
    const float* src = (id < 2048) ? camw1 : regw1;
    u16* dst = Bt1cr + ((id < 2048) ? 0 : (size_t)1024 * CDIM);
    int i2 = id & 2047;
    int kb = (i2 & 63) * 32, nb = (i2 >> 6) * 32;
    #pragma unroll
    for (int i = 0; i < 4; ++i)
      tile[ty + i * 8][tx] = src[(size_t)(kb + ty + i * 8) * 1024 + nb + tx];
    __syncthreads();
    #pragma unroll
    for (int i = 0; i < 4; ++i)
      dst[(size_t)(nb + ty + i * 8) * CDIM + kb + tx] = f2b(tile[tx][ty + i * 8]);
  } else if (id < 5120) {
    int i3 = id - 4096;
    const float* src = (i3 < 512) ? camw2 : regw2;
    u16* dst = Bt2cr + ((i3 < 512) ? 0 : (size_t)512 * N1);
    int i2 = i3 & 511;
    int kb = (i2 & 31) * 32, nb = (i2 >> 5) * 32;
    #pragma unroll
    for (int i = 0; i < 4; ++i)
      tile[ty + i * 8][tx] = src[(size_t)(kb + ty + i * 8) * 512 + nb + tx];
    __syncthreads();
    #pragma unroll
    for (int i = 0; i < 4; ++i)
      dst[(size_t)(nb + ty + i * 8) * N1 + kb + tx] = f2b(tile[tx][ty + i * 8]);
  } else {
    int r = id - 5120;
    int c0 = tid << 3;
    u16x8 o;
    if (r >= 80) {
      #pragma unroll
      for (int i = 0; i < 8; ++i) o[i] = 0;
    } else {
      const float* src;
      if (r < 16) { int b = r >> 2, s = r & 3; src = tokens + ((size_t)(b * S_ + s) * NTOK) * CDIM; }
      else { int r2 = r - 16; int b = r2 >> 4, q = r2 & 15, s = q >> 2, t = (q & 3) + 1;
             src = tokens + ((size_t)(b * S_ + s) * NTOK + t) * CDIM; }
      float4 v0 = *(const float4*)(src + c0);
      float4 v1 = *(const float4*)(src + c0 + 4);
      o[0] = f2b(v0.x); o[1] = f2b(v0.y); o[2] = f2b(v0.z); o[3] = f2b(v0.w);
      o[4] = f2b(v1.x); o[5] = f2b(v1.y); o[6] = f2b(v1.z); o[7] = f2b(v1.w);
    }
    *(u16x8*)(Acr + (size_t)r * CDIM + c0) = o;
  }
}

// ---------------- bf16 MFMA GEMM, 2-phase explicit double-buffer ----------------
#define STAGE_TILE(buf, k0)                                                    \
  {                                                                            \
    _Pragma("unroll")                                                          \
    for (int r = 0; r < 4; ++r) {                                              \
      __builtin_amdgcn_global_load_lds(                                        \
          (global_cvoid*)(A + abase + (size_t)(r * 32) * K + (k0)),            \
          (lds_void*)(&As[buf][lofs + r * 2048]), 16, 0, 0);                   \
      __builtin_amdgcn_global_load_lds(                                        \
          (global_cvoid*)(Bt + bbase + (size_t)(r * 32) * K + (k0)),           \
          (lds_void*)(&Bs[buf][lofs + r * 2048]), 16, 0, 0);                   \
    }                                                                          \
  }

#define COMPUTE_TILE(buf)                                                      \
  {                                                                            \
    _Pragma("unroll")                                                          \
    for (int kk = 0; kk < 64; kk += 32) {                                      \
      bf16x8 af[4], bfr[4];                                                    \
      _Pragma("unroll")                                                        \
      for (int i = 0; i < 4; ++i) {                                            \
        af[i]  = *(const bf16x8*)&As[buf][((wr << 6) + (i << 4) + (lane & 15)) * 64 + kk + hi8]; \
        bfr[i] = *(const bf16x8*)&Bs[buf][((wc << 6) + (i << 4) + (lane & 15)) * 64 + kk + hi8]; \
      }                                                                        \
      _Pragma("unroll")                                                        \
      for (int mi = 0; mi < 4; ++mi)                                           \
        _Pragma("unroll")                                                      \
        for (int ni = 0; ni < 4; ++ni)                                         \
          acc[mi][ni] = __builtin_amdgcn_mfma_f32_16x16x32_bf16(af[mi], bfr[ni], acc[mi][ni], 0, 0, 0); \
    }                                                                          \
  }

template <int RELU, int OUTBF>
__global__ __launch_bounds__(256, 2)
void k_gemm(const u16* __restrict__ A, const u16* __restrict__ Bt,
            const float* __restrict__ bias, void* __restrict__ Cout,
            int M, int N, int K) {
  __shared__ u16 As[2][128 * 64];
  __shared__ u16 Bs[2][128 * 64];
  const int tid = threadIdx.x;
  const int lane = tid & 63;
  const int wave = tid >> 6;
  const int tM = blockIdx.x << 7;
  const int tN = blockIdx.y << 7;
  const int wr = wave >> 1, wc = wave & 1;
  const int hi8 = (lane >> 4) << 3;

  const int srow = (wave << 3) + (lane >> 3);
  const int scol = (lane & 7) << 3;
  const size_t abase = (size_t)(tM + srow) * K + scol;
  const size_t bbase = (size_t)(tN + srow) * K + scol;
  const int lofs = (wave << 9) + (lane << 3);

  f32x4 acc[4][4];
  #pragma unroll
  for (int i = 0; i < 4; ++i)
    #pragma unroll
    for (int j = 0; j < 4; ++j)
      acc[i][j] = (f32x4){0.f, 0.f, 0.f, 0.f};

  const int nt = K >> 6;
  STAGE_TILE(0, 0)
  __syncthreads();
  for (int t = 0; t < nt; t += 2) {
    if (t + 1 < nt) STAGE_TILE(1, (t + 1) << 6)
    COMPUTE_TILE(0)
    __syncthreads();
    if (t + 1 < nt) {
      if (t + 2 < nt) STAGE_TILE(0, (t + 2) << 6)
      COMPUTE_TILE(1)
      __syncthreads();
    }
  }

  #pragma unroll
  for (int ni = 0; ni < 4; ++ni) {
    const int col = tN + (wc << 6) + (ni << 4) + (lane & 15);
    const float bv = bias[col];
    #pragma unroll
    for (int mi = 0; mi < 4; ++mi) {
      #pragma unroll
      for (int j = 0; j < 4; ++j) {
        const int row = tM + (wr << 6) + (mi << 4) + ((lane >> 4) << 2) + j;
        float vv = acc[mi][ni][j] + bv;
        if (RELU) vv = fmaxf(vv, 0.f);
        if (OUTBF) ((u16*)Cout)[(size_t)row * N + col] = f2b(vv);
        else       ((float*)Cout)[(size_t)row * N + col] = vv;
      }
    }
  }
}

// ---------------- split-K MFMA GEMM, M=128 fixed (single-buffer, known-good) ----
__global__ __launch_bounds__(256, 2)
void k_gemm_splitk(const u16* __restrict__ A, const u16* __restrict__ Bt,
                   float* __restrict__ part, int N, int K, int KC) {
  __shared__ u16 As1[128 * 64];
  __shared__ u16 Bs1[128 * 64];
  const int tid = threadIdx.x;
  const int lane = tid & 63;
  const int wave = tid >> 6;
  const int tN = blockIdx.y << 7;
  const int kb = blockIdx.z * KC;
  const int wr = wave >> 1, wc = wave & 1;
  const int srow = (wave << 3) + (lane >> 3);
  const int scol = (lane & 7) << 3;
  const size_t abase = (size_t)srow * K + scol;
  const size_t bbase = (size_t)(tN + srow) * K + scol;
  u16* asw = &As1[(wave << 9) + (lane << 3)];
  u16* bsw = &Bs1[(wave << 9) + (lane << 3)];

  f32x4 acc[4][4];
  #pragma unroll
  for (int i = 0; i < 4; ++i)
    #pragma unroll
    for (int j = 0; j < 4; ++j)
      acc[i][j] = (f32x4){0.f, 0.f, 0.f, 0.f};

  for (int k0 = kb; k0 < kb + KC; k0 += 64) {
    #pragma unroll
    for (int r = 0; r < 4; ++r) {
      __builtin_amdgcn_global_load_lds(
          (global_cvoid*)(A + abase + (size_t)(r * 32) * K + k0),
          (lds_void*)(asw + r * 2048), 16, 0, 0);
      __builtin_amdgcn_global_load_lds(
          (global_cvoid*)(Bt + bbase + (size_t)(r * 32) * K + k0),
          (lds_void*)(bsw + r * 2048), 16, 0, 0);
    }
    __syncthreads();
    #pragma unroll
    for (int kk = 0; kk < 64; kk += 32) {
      bf16x8 af[4], bfr[4];
      #pragma unroll
      for (int i = 0; i < 4; ++i) {
        af[i]  = *(const bf16x8*)&As1[((wr << 6) + (i << 4) + (lane & 15)) * 64 + kk + ((lane >> 4) << 3)];
        bfr[i] = *(const bf16x8*)&Bs1[((wc << 6) + (i << 4) + (lane & 15)) * 64 + kk + ((lane >> 4) << 3)];
      }
      #pragma unroll
      for (int mi = 0; mi < 4; ++mi)
        #pragma unroll
        for (int ni = 0; ni < 4; ++ni)
          acc[mi][ni] = __builtin_amdgcn_mfma_f32_16x16x32_bf16(af[mi], bfr[ni], acc[mi][ni], 0, 0, 0);
    }
    __syncthreads();
  }

  float* dst = part + (size_t)blockIdx.z * 128 * N;
  #pragma unroll
  for (int ni = 0; ni < 4; ++ni) {
    const int col = tN + (wc << 6) + (ni << 4) + (lane & 15);
    #pragma unroll
    for (int mi = 0; mi < 4; ++mi) {
      #pragma unroll
      for (int j = 0; j < 4; ++j) {
        const int row = (wr << 6) + (mi << 4) + ((lane >> 4) << 2) + j;
        dst[(size_t)row * N + col] = acc[mi][ni][j];
      }
    }
  }
}

// ---------------- cr fin1: reduce part1(kc=8) + bias + relu -> A2 bf16 [128][1024] ----
__global__ void k_cr_fin1(const float* __restrict__ part1,
                          const float* __restrict__ camb1, const float* __restrict__ regb1,
                          u16* __restrict__ A2) {
  int r = blockIdx.x;
  int j = blockIdx.y * 256 + threadIdx.x;
  if (r >= 80) { A2[(size_t)r * N1 + j] = 0; return; }
  bool cam = (r < 16);
  int cm = j + (cam ? 0 : 1024);
  float s = 0.f;
  #pragma unroll
  for (int kc = 0; kc < 8; ++kc) s += part1[((size_t)kc * 128 + r) * 2048 + cm];
  s += cam ? camb1[j] : regb1[j];
  A2[(size_t)r * N1 + j] = f2b(fmaxf(s, 0.f));
}

// ---------------- cr fin2: reduce part2(kc=8) + bias + l2norm + clip^p -> hp[80][512] -
__global__ __launch_bounds__(512)
void k_cr_fin2(const float* __restrict__ part2,
               const float* __restrict__ camb2, const float* __restrict__ regb2,
               const float* __restrict__ camp, const float* __restrict__ regp,
               float* __restrict__ hp) {
  __shared__ float red[8];
  int r = blockIdx.x;
  int j = threadIdx.x;
  bool cam = (r < 16);
  int cm = j + (cam ? 0 : 512);
  float s = 0.f;
  #pragma unroll
  for (int kc = 0; kc < 8; ++kc) s += part2[((size_t)kc * 128 + r) * 1024 + cm];
  s += cam ? camb2[j] : regb2[j];
  float ss = s * s;
  #pragma unroll
  for (int o = 32; o; o >>= 1) ss += __shfl_down(ss, o);
  if ((j & 63) == 0) red[j >> 6] = ss;
  __syncthreads();
  float tot = 0.f;
  #pragma unroll
  for (int i = 0; i < 8; ++i) tot += red[i];
  float inv = 1.f / fmaxf(sqrtf(tot), 1e-12f);
  float t = fmaxf(s * inv, 1e-6f);
  hp[(size_t)r * 512 + j] = powf(t, cam ? camp[0] : regp[0]);
}

// ---------------- cr3a: GeM finalize -> gsb[8][512] ----------------
__global__ __launch_bounds__(512)
void k_cr3a(const float* __restrict__ hp, const float* __restrict__ camp,
            const float* __restrict__ regp, float* __restrict__ gsb) {
  int pb = blockIdx.x;               // 0..7 : path = pb>>2 (0 cam, 1 reg), b = pb&3
  bool cam = (pb < 4);
  int b = pb & 3;
  float p = cam ? camp[0] : regp[0];
  int L = cam ? 4 : 16;
  int row0 = cam ? b * 4 : 16 + b * 16;
  int o = threadIdx.x;
  float s = 0.f;
  for (int r = 0; r < L; ++r) s += hp[(size_t)(row0 + r) * 512 + o];
  gsb[pb * 512 + o] = powf(s / (float)L, 1.f / p);
}

// ---------------- cr3b: o1[8][512] = ReLU(gs @ W3 + b3), k-split x4 ----------------
__global__ __launch_bounds__(512)
void k_cr3b(const float* __restrict__ gsb,
            const float* __restrict__ camw3, const float* __restrict__ regw3,
            const float* __restrict__ camb3, const float* __restrict__ regb3,
            float* __restrict__ o1b) {
  __shared__ float gls[512];
  __shared__ float part[4][128];
  int pb = blockIdx.x, och = blockIdx.y;
  bool cam = (pb < 4);
  const float* W3 = cam ? camw3 : regw3;
  const float* B3 = cam ? camb3 : regb3;
  int tid = threadIdx.x;
  gls[tid] = gsb[pb * 512 + tid];
  __syncthreads();
  int col = tid & 127, kq = tid >> 7;           // 128 cols x 4 k-quarters
  int o = (och << 7) + col;
  float acc = 0.f;
  const float* w = W3 + (size_t)(kq << 7) * 512 + o;
  #pragma unroll 8
  for (int kk = 0; kk < 128; ++kk) acc += gls[(kq << 7) + kk] * w[(size_t)kk * 512];
  part[kq][col] = acc;
  __syncthreads();
  if (kq == 0) {
    float s = part[0][col] + part[1][col] + part[2][col] + part[3][col] + B3[o];
    o1b[pb * 512 + o] = fmaxf(s, 0.f);
  }
}

// ---------------- cr3c: out = l2norm(o1 @ W4 + b4), k-split x2 + block l2norm -------
__global__ __launch_bounds__(512)
void k_cr3c(const float* __restrict__ o1b,
            const float* __restrict__ camw4, const float* __restrict__ regw4,
            const float* __restrict__ camb4, const float* __restrict__ regb4,
            float* __restrict__ out) {
  __shared__ float o1s[512];
  __shared__ float part[2][256];
  __shared__ float vsq[256];
  __shared__ float red[4];
  int pb = blockIdx.x;
  bool cam = (pb < 4);
  int path = pb >> 2, b = pb & 3;
  const float* W4 = cam ? camw4 : regw4;
  const float* B4 = cam ? camb4 : regb4;
  int tid = threadIdx.x;
  o1s[tid] = o1b[pb * 512 + tid];
  __syncthreads();
  int col = tid & 255, kh = tid >> 8;           // 256 cols x 2 k-halves
  float acc = 0.f;
  const float* w = W4 + (size_t)(kh << 8) * 256 + col;
  #pragma unroll 8
  for (int kk = 0; kk < 256; ++kk) acc += o1s[(kh << 8) + kk] * w[(size_t)kk * 256];
  part[kh][col] = acc;
  __syncthreads();
  float val = 0.f;
  if (kh == 0) {
    val = part[0][col] + part[1][col] + B4[col];
    vsq[col] = val * val;
  }
  __syncthreads();
  float ss = (tid < 256) ? vsq[tid] : 0.f;
  #pragma unroll
  for (int o = 32; o; o >>= 1) ss += __shfl_down(ss, o);
  if (tid < 256 && (tid & 63) == 0) red[tid >> 6] = ss;
  __syncthreads();
  if (kh == 0) {
    float tot = red[0] + red[1] + red[2] + red[3];
    float inv = 1.f / fmaxf(sqrtf(tot), 1e-12f);
    out[(size_t)b * 8704 + 8192 + path * 256 + col] = val * inv;
  }
}

// ---------------- scores transpose: FS[:,128:192] -> Sc[B][65][4096] (+dust row) ----
__global__ void k_tr_scores(const float* __restrict__ FS, const float* __restrict__ dust,
                            float* __restrict__ Sc) {
  __shared__ float t[64][65];
  int b = blockIdx.x >> 6, n0 = (blockIdx.x & 63) * 64;
  int tx = threadIdx.x & 63, ty = threadIdx.x >> 6;
  for (int r = ty; r < 64; r += 4)
    t[r][tx] = FS[((size_t)(b * NPB + n0 + r)) * N2 + 128 + tx];
  __syncthreads();
  for (int k = ty; k < 64; k += 4)
    Sc[((size_t)(b * MA) + k) * NPB + n0 + tx] = t[tx][k];
  if (threadIdx.x < 64)
    Sc[((size_t)(b * MA) + 64) * NPB + n0 + threadIdx.x] = dust[0];
}

// ---------------- sinkhorn: u update — one-pass online LSE over n=4096 ----------------
__global__ void k_sink_u(const float* __restrict__ Sc, const float* __restrict__ v,
                         float* __restrict__ u) {
  __shared__ float redm[4], reds[4];
  int b = blockIdx.x / MA, k = blockIdx.x % MA;
  const float* row = Sc + ((size_t)(b * MA) + k) * NPB;
  const float* vb = v + (size_t)b * NPB;
  int tid = threadIdx.x;
  float mx = -1e30f, s = 0.f;
  for (int n = tid; n < NPB; n += 256) {
    float x = row[n] + vb[n];
    float m2 = fmaxf(mx, x);
    s = s * __expf(mx - m2) + __expf(x - m2);
    mx = m2;
  }
  #pragma unroll
  for (int o = 32; o; o >>= 1) {
    float mo = __shfl_down(mx, o), so = __shfl_down(s, o);
    float m2 = fmaxf(mx, mo);
    s = s * __expf(mx - m2) + so * __expf(mo - m2);
    mx = m2;
  }
  if ((tid & 63) == 0) { redm[tid >> 6] = mx; reds[tid >> 6] = s; }
  __syncthreads();
  if (tid == 0) {
    float M = redm[0];
    #pragma unroll
    for (int i = 1; i < 4; ++i) M = fmaxf(M, redm[i]);
    float S = 0.f;
    #pragma unroll
    for (int i = 0; i < 4; ++i) S += reds[i] * __expf(redm[i] - M);
    const float nrm = -logf((float)(NPB + MD));
    float la = (k == MD) ? (nrm + logf((float)(NPB - MD))) : nrm;
    u[b * MA + k] = la - (M + __logf(S));
  }
}

// ---------------- sinkhorn: v update (col LSE over m+1=65) ----------------
__global__ void k_sink_v(const float* __restrict__ Sc, const float* __restrict__ u,
                         float* __restrict__ v) {
  __shared__ float us[MA];
  int b = blockIdx.x >> 4;
  int n = ((blockIdx.x & 15) << 8) + threadIdx.x;
  if (threadIdx.x < MA) us[threadIdx.x] = u[b * MA + threadIdx.x];
  __syncthreads();
  const float* Sb = Sc + (size_t)b * MA * NPB + n;
  float mx = -1e30f;
  for (int k = 0; k < MA; ++k) mx = fmaxf(mx, Sb[(size_t)k * NPB] + us[k]);
  float s = 0.f;
  for (int k = 0; k < MA; ++k) s += __expf(Sb[(size_t)k * NPB] + us[k] - mx);
  const float nrm = -logf((float)(NPB + MD));
  v[(size_t)b * NPB + n] = nrm - (mx + __logf(s));
}

// ---------------- pooled stage 1 (P fused): partial[b][j][c][k] over 64-n chunks ------
__global__ __launch_bounds__(256)
void k_pooled1(const float* __restrict__ FS, const float* __restrict__ Sc,
               const float* __restrict__ u, const float* __restrict__ v,
               float* __restrict__ partial) {
  __shared__ float Fs[64][132];
  __shared__ float Ps[64][68];
  int b = blockIdx.x >> 6, j = blockIdx.x & 63;
  int n0 = j << 6;
  int tid = threadIdx.x;
  {
    int r = tid >> 5;
    int c4 = (tid & 31) << 2;
    #pragma unroll
    for (int i = 0; i < 8; ++i) {
      int n = r + (i << 3);
      float4 vv = *(const float4*)&FS[((size_t)(b * NPB + n0 + n)) * N2 + c4];
      *(float4*)&Fs[n][c4] = vv;
    }
  }
  {
    const float nrm = -logf((float)(NPB + MD));
    int r = tid >> 4;
    int c4 = (tid & 15) << 2;
    #pragma unroll
    for (int i = 0; i < 4; ++i) {
      int k = r + (i << 4);
      float uk = u[b * MA + k];
      float4 sv = *(const float4*)&Sc[((size_t)(b * MA) + k) * NPB + n0 + c4];
      float4 vv = *(const float4*)&v[(size_t)b * NPB + n0 + c4];
      float4 o;
      o.x = __expf(sv.x + uk + vv.x - nrm);
      o.y = __expf(sv.y + uk + vv.y - nrm);
      o.z = __expf(sv.z + uk + vv.z - nrm);
      o.w = __expf(sv.w + uk + vv.w - nrm);
      *(float4*)&Ps[k][c4] = o;
    }
  }
  __syncthreads();
  int tc = tid & 31, tk = tid >> 5;
  int c0 = tc << 2, k0 = tk << 3;
  float acc[4][8];
  #pragma unroll
  for (int i = 0; i < 4; ++i)
    #pragma unroll
    for (int kk = 0; kk < 8; ++kk) acc[i][kk] = 0.f;
  for (int n = 0; n < 64; ++n) {
    float4 f = *(const float4*)&Fs[n][c0];
    float pv[8];
    #pragma unroll
    for (int kk = 0; kk < 8; ++kk) pv[kk] = Ps[k0 + kk][n];
    #pragma unroll
    for (int i = 0; i < 4; ++i) {
      float fv = ((const float*)&f)[i];
      #pragma unroll
      for (int kk = 0; kk < 8; ++kk) acc[i][kk] += fv * pv[kk];
    }
  }
  float* dst = partial + ((size_t)(b * 64 + j) << 13);
  #pragma unroll
  for (int i = 0; i < 4; ++i) {
    float4 lo = {acc[i][0], acc[i][1], acc[i][2], acc[i][3]};
    float4 hi = {acc[i][4], acc[i][5], acc[i][6], acc[i][7]};
    *(float4*)&dst[((c0 + i) << 6) + k0] = lo;
    *(float4*)&dst[((c0 + i) << 6) + k0 + 4] = hi;
  }
}

// ---------------- pooled stage 2: reduce 64 partials, coalesced ----------------
__global__ void k_pooled2(const float* __restrict__ partial, float* __restrict__ pooled) {
  int o = blockIdx.x * 256 + threadIdx.x;
  int b = o >> 13, rem = o & 8191;
  const float* src = partial + ((size_t)b << 19) + rem;
  float s = 0.f;
  #pragma unroll 8
  for (int j = 0; j < 64; ++j) s += src[(size_t)j << 13];
  pooled[o] = s;
}

// ---------------- patch output: l2norm over c (128), write [b][c*64+k] --------------
__global__ void k_patch_out(const float* __restrict__ pooled, float* __restrict__ out) {
  int b = blockIdx.x >> 6, k = blockIdx.x & 63;
  int tid = threadIdx.x;
  float v0 = pooled[((size_t)(b * 128) + tid) * MD + k];
  float v1 = pooled[((size_t)(b * 128) + 64 + tid) * MD + k];
  float ss = v0 * v0 + v1 * v1;
  #pragma unroll
  for (int o = 32; o; o >>= 1) ss += __shfl_down(ss, o);
  ss = __shfl(ss, 0);
  float inv = 1.f / fmaxf(sqrtf(ss), 1e-12f);
  out[(size_t)b * 8704 + tid * 64 + k] = v0 * inv;
  out[(size_t)b * 8704 + (64 + tid) * 64 + k] = v1 * inv;
}

// ---------------- workspace layout (bytes) ----------------
// lifetime rule: below 67,108,864 overlaps Abf (live until GEMM1 done);
// 67,108,864..100,663,296 overlaps H (live GEMM1->GEMM2). cr path runs AFTER GEMM2.
// GSB/O1B reuse CP1 region (cp1 last read by k_cr_fin1; cr3a runs after k_cr_fin2).
#define OFF_ABF 0u
#define OFF_SC 0u
#define OFF_U 4259840u
#define OFF_V 4263936u
#define OFF_POOL 8523776u
#define OFF_HP 8982528u                   // written post-GEMM2 only!
#define OFF_H 67108864u
#define OFF_PART OFF_H                    // 8,388,608 (disjoint from CP1)
#define OFF_CP1 75497472u
#define OFF_GSB OFF_CP1                   // 8*512*4 = 16,384
#define OFF_O1B 75513856u                 // 8*512*4 = 16,384
#define OFF_CP2 83886080u
#define OFF_BT1CR 88080384u
#define OFF_BT2CR 96468992u
#define OFF_ACR 98566144u
#define OFF_A2 99090432u
#define OFF_FS 100663296u
#define OFF_W1T 117440512u
#define OFF_W2T 121634816u
#define OFF_B1C 122159104u
#define OFF_B2C 122163200u

extern "C" void kernel_launch(void* const* d_in, const int* in_sizes, int n_in,
                              void* d_out, int out_size, void* d_ws, size_t ws_size,
                              hipStream_t stream) {
  (void)in_sizes; (void)n_in; (void)out_size; (void)ws_size;
  const float* tokens = (const float*)d_in[0];
  const float* cam_w1 = (const float*)d_in[2];
  const float* cam_b1 = (const float*)d_in[3];
  const float* cam_w2 = (const float*)d_in[4];
  const float* cam_b2 = (const float*)d_in[5];
  const float* cam_p  = (const float*)d_in[6];
  const float* cam_w3 = (const float*)d_in[7];
  const float* cam_b3 = (const float*)d_in[8];
  const float* cam_w4 = (const float*)d_in[9];
  const float* cam_b4 = (const float*)d_in[10];
  const float* reg_w1 = (const float*)d_in[11];
  const float* reg_b1 = (const float*)d_in[12];
  const float* reg_w2 = (const float*)d_in[13];
  const float* reg_b2 = (const float*)d_in[14];
  const float* reg_p  = (const float*)d_in[15];
  const float* reg_w3 = (const float*)d_in[16];
  const float* reg_b3 = (const float*)d_in[17];
  const float* reg_w4 = (const float*)d_in[18];
  const float* reg_b4 = (const float*)d_in[19];
  const float* pf_w1  = (const float*)d_in[20];
  const float* pf_b1  = (const float*)d_in[21];
  const float* pf_w2  = (const float*)d_in[22];
  const float* pf_b2  = (const float*)d_in[23];
  const float* ps_w1  = (const float*)d_in[24];
  const float* ps_b1  = (const float*)d_in[25];
  const float* ps_w2  = (const float*)d_in[26];
  const float* ps_b2  = (const float*)d_in[27];
  const float* dust   = (const float*)d_in[28];
  float* out = (float*)d_out;
  char* ws = (char*)d_ws;

  u16* Abf = (u16*)(ws + OFF_ABF);
  float* Sc = (float*)(ws + OFF_SC);
  float* ub = (float*)(ws + OFF_U);
  float* vb = (float*)(ws + OFF_V);
  float* pooled = (float*)(ws + OFF_POOL);
  float* hp = (float*)(ws + OFF_HP);
  u16* H   = (u16*)(ws + OFF_H);
  float* partial = (float*)(ws + OFF_PART);
  float* cp1 = (float*)(ws + OFF_CP1);
  float* gsb = (float*)(ws + OFF_GSB);
  float* o1b = (float*)(ws + OFF_O1B);
  float* cp2 = (float*)(ws + OFF_CP2);
  u16* Bt1cr = (u16*)(ws + OFF_BT1CR);
  u16* Bt2cr = (u16*)(ws + OFF_BT2CR);
  u16* Acr = (u16*)(ws + OFF_ACR);
  u16* A2  = (u16*)(ws + OFF_A2);
  float* FS = (float*)(ws + OFF_FS);
  u16* W1t = (u16*)(ws + OFF_W1T);
  u16* W2t = (u16*)(ws + OFF_W2T);
  float* b1c = (float*)(ws + OFF_B1C);
  float* b2c = (float*)(ws + OFF_B2C);

  hipMemsetAsync(vb, 0, (size_t)B_ * NPB * sizeof(float), stream);

  // ---- patch packs + GEMMs ----
  k_convert_patch<<<16384, 256, 0, stream>>>(tokens, Abf);
  k_pack_patch<<<2308, 256, 0, stream>>>(pf_w1, ps_w1, pf_w2, ps_w2,
                                         pf_b1, ps_b1, pf_b2, ps_b2,
                                         W1t, W2t, b1c, b2c);
  k_gemm<1, 1><<<dim3(128, 8), 256, 0, stream>>>(Abf, W1t, b1c, (void*)H, MROWS, N1, CDIM);
  k_gemm<0, 0><<<dim3(128, 2), 256, 0, stream>>>(H, W2t, b2c, (void*)FS, MROWS, N2, N1);

  // ---- cam/reg path (Abf and H regions now dead) ----
  k_pack_cr<<<5248, 256, 0, stream>>>(cam_w1, reg_w1, cam_w2, reg_w2, tokens,
                                      Bt1cr, Bt2cr, Acr);
  k_gemm_splitk<<<dim3(1, 16, 8), 256, 0, stream>>>(Acr, Bt1cr, cp1, 2048, CDIM, 256);
  k_cr_fin1<<<dim3(128, 4), 256, 0, stream>>>(cp1, cam_b1, reg_b1, A2);
  k_gemm_splitk<<<dim3(1, 8, 8), 256, 0, stream>>>(A2, Bt2cr, cp2, 1024, N1, 128);
  k_cr_fin2<<<80, 512, 0, stream>>>(cp2, cam_b2, reg_b2, cam_p, reg_p, hp);
  k_cr3a<<<8, 512, 0, stream>>>(hp, cam_p, reg_p, gsb);
  k_cr3b<<<dim3(8, 4), 512, 0, stream>>>(gsb, cam_w3, reg_w3, cam_b3, reg_b3, o1b);
  k_cr3c<<<8, 512, 0, stream>>>(o1b, cam_w4, reg_w4, cam_b4, reg_b4, out);

  // ---- sinkhorn + pooled + outputs ----
  k_tr_scores<<<256, 256, 0, stream>>>(FS, dust, Sc);
  for (int it = 0; it < 3; ++it) {
    k_sink_u<<<B_ * MA, 256, 0, stream>>>(Sc, vb, ub);
    k_sink_v<<<B_ * 16, 256, 0, stream>>>(Sc, ub, vb);
  }
  k_pooled1<<<B_ * 64, 256, 0, stream>>>(FS, Sc, ub, vb, partial);
  k_pooled2<<<128, 256, 0, stream>>>(partial, pooled);
  k_patch_out<<<B_ * MD, 64, 0, stream>>>(pooled, out);
}

// Round 8
// 245.596 us; speedup vs baseline: 2.9664x; 1.0606x over previous
//
#include <hip/hip_runtime.h>

typedef unsigned short u16;
typedef unsigned int u32;

#define B_ 4
#define S_ 4
#define NTOK 1029
#define CDIM 2048
#define PSI 5
#define NPB 4096
#define MROWS 16384
#define N1 1024
#define N2 256
#define MD 64
#define MA 65

using bf16x8 = __attribute__((ext_vector_type(8))) short;
using f32x4  = __attribute__((ext_vector_type(4))) float;
using u16x8  = __attribute__((ext_vector_type(8))) unsigned short;

typedef __attribute__((address_space(1))) const void global_cvoid;
typedef __attribute__((address_space(3))) void lds_void;

__device__ __forceinline__ u16 f2b(float f) {
  u32 u = __builtin_bit_cast(u32, f);
  u32 r = (u + 0x7fffu + ((u >> 16) & 1u)) >> 16;
  return (u16)r;
}

// ---------------- prep: gather patch tokens, convert fp32 -> bf16 ----------------
__global__ void k_convert_patch(const float* __restrict__ tokens, u16* __restrict__ Abf) {
  size_t idx = (size_t)blockIdx.x * 256 + threadIdx.x;
  size_t r = idx >> 8;
  int cv = (int)(idx & 255) << 3;
  int b = (int)(r >> 12), s = (int)((r >> 10) & 3), j = (int)(r & 1023);
  const float* src = tokens + ((size_t)((b * S_ + s) * NTOK + PSI + j)) * CDIM + cv;
  float4 v0 = *(const float4*)src;
  float4 v1 = *(const float4*)(src + 4);
  u16x8 o;
  o[0] = f2b(v0.x); o[1] = f2b(v0.y); o[2] = f2b(v0.z); o[3] = f2b(v0.w);
  o[4] = f2b(v1.x); o[5] = f2b(v1.y); o[6] = f2b(v1.z); o[7] = f2b(v1.w);
  *(u16x8*)(Abf + r * CDIM + cv) = o;
}

// ---------------- merged patch-side packs: W1t, W2t, biases ----------------
__global__ void k_pack_patch(const float* __restrict__ pfw1, const float* __restrict__ psw1,
                             const float* __restrict__ pfw2, const float* __restrict__ psw2,
                             const float* __restrict__ pfb1, const float* __restrict__ psb1,
                             const float* __restrict__ pfb2, const float* __restrict__ psb2,
                             u16* __restrict__ W1t, u16* __restrict__ W2t,
                             float* __restrict__ b1c, float* __restrict__ b2c) {
  __shared__ float tile[32][33];
  int id = blockIdx.x, tid = threadIdx.x;
  int tx = tid & 31, ty = tid >> 5;
  if (id < 2048) {
    int kb = (id & 63) * 32, nb = (id >> 6) * 32;
    #pragma unroll
    for (int i = 0; i < 4; ++i) {
      int k = kb + ty + i * 8, n = nb + tx;
      tile[ty + i * 8][tx] = (n < 512) ? pfw1[(size_t)k * 512 + n] : psw1[(size_t)k * 512 + (n - 512)];
    }
    __syncthreads();
    #pragma unroll
    for (int i = 0; i < 4; ++i) {
      int n = nb + ty + i * 8, k = kb + tx;
      W1t[(size_t)n * CDIM + k] = f2b(tile[tx][ty + i * 8]);
    }
  } else if (id < 2304) {
    int i2 = id - 2048;
    int kb = (i2 & 31) * 32, jb = (i2 >> 5) * 32;
    #pragma unroll
    for (int i = 0; i < 4; ++i) {
      int k = kb + ty + i * 8, j = jb + tx;
      float v = 0.f;
      if (j < 128) { if (k < 512) v = pfw2[(size_t)k * 128 + j]; }
      else if (j < 192) { if (k >= 512) v = psw2[(size_t)(k - 512) * 64 + (j - 128)]; }
      tile[ty + i * 8][tx] = v;
    }
    __syncthreads();
    #pragma unroll
    for (int i = 0; i < 4; ++i) {
      int j = jb + ty + i * 8, k = kb + tx;
      W2t[(size_t)j * N1 + k] = f2b(tile[tx][ty + i * 8]);
    }
  } else {
    int t = (id - 2304) * 256 + tid;
    if (t < 1024) b1c[t] = (t < 512) ? pfb1[t] : psb1[t - 512];
    if (t < 256)  b2c[t] = (t < 128) ? pfb2[t] : ((t < 192) ? psb2[t - 128] : 0.f);
  }
}

// ---------------- merged cr-side packs: Bt1cr, Bt2cr, Acr ----------------
__global__ void k_pack_cr(const float* __restrict__ camw1, const float* __restrict__ regw1,
                          const float* __restrict__ camw2, const float* __restrict__ regw2,
                          const float* __restrict__ tokens,
                          u16* __restrict__ Bt1cr, u16* __restrict__ Bt2cr,
                          u16* __restrict__ Acr) {
  __shared__ float tile[32][33];
  int id = blockIdx.x, tid = threadIdx.x;
  int tx = tid & 31, ty = tid >> 5;
  if (id < 4096) {
    const float* src = (id < 2048) ? camw1 : regw1;
    u16* dst = Bt1cr + ((id < 2048) ? 0 : (size_t)1024 * CDIM);
    int i2 = id & 2047;
    int kb = (i2 & 63) * 32, nb = (i2 >> 6) * 32;
    #pragma unroll
    for (int i = 0; i < 4; ++i)
      tile[ty + i * 8][tx] = src[(size_t)(kb + ty + i * 8) * 1024 + nb + tx];
    __syncthreads();
    #pragma unroll
    for (int i = 0; i < 4; ++i)
      dst[(size_t)(nb + ty + i * 8) * CDIM + kb + tx] = f2b(tile[tx][ty + i * 8]);
  } else if (id < 5120) {
    int i3 = id - 4096;
    const float* src = (i3 < 512) ? camw2 : regw2;
    u16* dst = Bt2cr + ((i3 < 512) ? 0 : (size_t)512 * N1);
    int i2 = i3 & 511;
    int kb = (i2 & 31) * 32, nb = (i2 >> 5) * 32;
    #pragma unroll
    for (int i = 0; i < 4; ++i)
      tile[ty + i * 8][tx] = src[(size_t)(kb + ty + i * 8) * 512 + nb + tx];
    __syncthreads();
    #pragma unroll
    for (int i = 0; i < 4; ++i)
      dst[(size_t)(nb + ty + i * 8) * N1 + kb + tx] = f2b(tile[tx][ty + i * 8]);
  } else {
    int r = id - 5120;
    int c0 = tid << 3;
    u16x8 o;
    if (r >= 80) {
      #pragma unroll
      for (int i = 0; i < 8; ++i) o[i] = 0;
    } else {
      const float* src;
      if (r < 16) { int b = r >> 2, s = r & 3; src = tokens + ((size_t)(b * S_ + s) * NTOK) * CDIM; }
      else { int r2 = r - 16; int b = r2 >> 4, q = r2 & 15, s = q >> 2, t = (q & 3) + 1;
             src = tokens + ((size_t)(b * S_ + s) * NTOK + t) * CDIM; }
      float4 v0 = *(const float4*)(src + c0);
      float4 v1 = *(const float4*)(src + c0 + 4);
      o[0] = f2b(v0.x); o[1] = f2b(v0.y); o[2] = f2b(v0.z); o[3] = f2b(v0.w);
      o[4] = f2b(v1.x); o[5] = f2b(v1.y); o[6] = f2b(v1.z); o[7] = f2b(v1.w);
    }
    *(u16x8*)(Acr + (size_t)r * CDIM + c0) = o;
  }
}

// ---------------- bf16 MFMA GEMM: 2-buf, counted vmcnt(8), raw barriers, T2 swizzle --
// LDS content is col-permuted: LDS[row][c] holds global col c ^ ((row&7)<<3).
// Staging keeps linear LDS dest (gload_lds constraint) and pre-swizzles the GLOBAL
// source column (same 128B segment -> coalescing preserved). Reads XOR the same term.
#define STAGE_TILE(buf, k0)                                                    \
  {                                                                            \
    _Pragma("unroll")                                                          \
    for (int r = 0; r < 4; ++r) {                                              \
      __builtin_amdgcn_global_load_lds(                                        \
          (global_cvoid*)(A + abase + (size_t)(r * 32) * K + (k0)),            \
          (lds_void*)(&As[buf][lofs + r * 2048]), 16, 0, 0);                   \
      __builtin_amdgcn_global_load_lds(                                        \
          (global_cvoid*)(Bt + bbase + (size_t)(r * 32) * K + (k0)),           \
          (lds_void*)(&Bs[buf][lofs + r * 2048]), 16, 0, 0);                   \
    }                                                                          \
  }

#define COMPUTE_TILE(buf)                                                      \
  {                                                                            \
    _Pragma("unroll")                                                          \
    for (int kk = 0; kk < 64; kk += 32) {                                      \
      const int csw = (kk + hi8) ^ ((lane & 7) << 3);                          \
      bf16x8 af[4], bfr[4];                                                    \
      _Pragma("unroll")                                                        \
      for (int i = 0; i < 4; ++i) {                                            \
        af[i]  = *(const bf16x8*)&As[buf][((wr << 6) + (i << 4) + (lane & 15)) * 64 + csw]; \
        bfr[i] = *(const bf16x8*)&Bs[buf][((wc << 6) + (i << 4) + (lane & 15)) * 64 + csw]; \
      }                                                                        \
      _Pragma("unroll")                                                        \
      for (int mi = 0; mi < 4; ++mi)                                           \
        _Pragma("unroll")                                                      \
        for (int ni = 0; ni < 4; ++ni)                                         \
          acc[mi][ni] = __builtin_amdgcn_mfma_f32_16x16x32_bf16(af[mi], bfr[ni], acc[mi][ni], 0, 0, 0); \
    }                                                                          \
  }

template <int RELU, int OUTBF>
__global__ __launch_bounds__(256, 2)
void k_gemm(const u16* __restrict__ A, const u16* __restrict__ Bt,
            const float* __restrict__ bias, void* __restrict__ Cout,
            int M, int N, int K) {
  __shared__ u16 As[2][128 * 64];
  __shared__ u16 Bs[2][128 * 64];
  const int tid = threadIdx.x;
  const int lane = tid & 63;
  const int wave = tid >> 6;
  const int tM = blockIdx.x << 7;
  const int tN = blockIdx.y << 7;
  const int wr = wave >> 1, wc = wave & 1;
  const int hi8 = (lane >> 4) << 3;

  const int srow = (wave << 3) + (lane >> 3);
  // swizzled source column: ((lane&7) ^ (lane>>3)) * 8 elements  (srow&7 == lane>>3)
  const int scolsw = ((lane & 7) ^ (lane >> 3)) << 3;
  const size_t abase = (size_t)(tM + srow) * K + scolsw;
  const size_t bbase = (size_t)(tN + srow) * K + scolsw;
  const int lofs = (wave << 9) + (lane << 3);   // linear LDS dest (elements)

  f32x4 acc[4][4];
  #pragma unroll
  for (int i = 0; i < 4; ++i)
    #pragma unroll
    for (int j = 0; j < 4; ++j)
      acc[i][j] = (f32x4){0.f, 0.f, 0.f, 0.f};

  const int nt = K >> 6;            // 32 (GEMM1) / 16 (GEMM2): even, >= 4
  STAGE_TILE(0, 0)
  STAGE_TILE(1, 64)
  for (int t = 0; t < nt; t += 2) {
    // even tile (buf 0): outstanding = tile t (8) + tile t+1 (8); vmcnt(8) lands tile t
    asm volatile("s_waitcnt vmcnt(8)" ::: "memory");
    __builtin_amdgcn_s_barrier();
    COMPUTE_TILE(0)
    __builtin_amdgcn_s_barrier();   // all waves done reading buf0
    if (t + 2 < nt) STAGE_TILE(0, (t + 2) << 6)
    // odd tile (buf 1)
    if (t + 1 == nt - 1) {
      asm volatile("s_waitcnt vmcnt(0)" ::: "memory");
    } else {
      asm volatile("s_waitcnt vmcnt(8)" ::: "memory");
    }
    __builtin_amdgcn_s_barrier();
    COMPUTE_TILE(1)
    __builtin_amdgcn_s_barrier();
    if (t + 3 < nt) STAGE_TILE(1, (t + 3) << 6)
  }

  #pragma unroll
  for (int ni = 0; ni < 4; ++ni) {
    const int col = tN + (wc << 6) + (ni << 4) + (lane & 15);
    const float bv = bias[col];
    #pragma unroll
    for (int mi = 0; mi < 4; ++mi) {
      #pragma unroll
      for (int j = 0; j < 4; ++j) {
        const int row = tM + (wr << 6) + (mi << 4) + ((lane >> 4) << 2) + j;
        float vv = acc[mi][ni][j] + bv;
        if (RELU) vv = fmaxf(vv, 0.f);
        if (OUTBF) ((u16*)Cout)[(size_t)row * N + col] = f2b(vv);
        else       ((float*)Cout)[(size_t)row * N + col] = vv;
      }
    }
  }
}

// ---------------- split-K MFMA GEMM, M=128 fixed (single-buffer, known-good) ----
__global__ __launch_bounds__(256, 2)
void k_gemm_splitk(const u16* __restrict__ A, const u16* __restrict__ Bt,
                   float* __restrict__ part, int N, int K, int KC) {
  __shared__ u16 As1[128 * 64];
  __shared__ u16 Bs1[128 * 64];
  const int tid = threadIdx.x;
  const int lane = tid & 63;
  const int wave = tid >> 6;
  const int tN = blockIdx.y << 7;
  const int kb = blockIdx.z * KC;
  const int wr = wave >> 1, wc = wave & 1;
  const int srow = (wave << 3) + (lane >> 3);
  const int scol = (lane & 7) << 3;
  const size_t abase = (size_t)srow * K + scol;
  const size_t bbase = (size_t)(tN + srow) * K + scol;
  u16* asw = &As1[(wave << 9) + (lane << 3)];
  u16* bsw = &Bs1[(wave << 9) + (lane << 3)];

  f32x4 acc[4][4];
  #pragma unroll
  for (int i = 0; i < 4; ++i)
    #pragma unroll
    for (int j = 0; j < 4; ++j)
      acc[i][j] = (f32x4){0.f, 0.f, 0.f, 0.f};

  for (int k0 = kb; k0 < kb + KC; k0 += 64) {
    #pragma unroll
    for (int r = 0; r < 4; ++r) {
      __builtin_amdgcn_global_load_lds(
          (global_cvoid*)(A + abase + (size_t)(r * 32) * K + k0),
          (lds_void*)(asw + r * 2048), 16, 0, 0);
      __builtin_amdgcn_global_load_lds(
          (global_cvoid*)(Bt + bbase + (size_t)(r * 32) * K + k0),
          (lds_void*)(bsw + r * 2048), 16, 0, 0);
    }
    __syncthreads();
    #pragma unroll
    for (int kk = 0; kk < 64; kk += 32) {
      bf16x8 af[4], bfr[4];
      #pragma unroll
      for (int i = 0; i < 4; ++i) {
        af[i]  = *(const bf16x8*)&As1[((wr << 6) + (i << 4) + (lane & 15)) * 64 + kk + ((lane >> 4) << 3)];
        bfr[i] = *(const bf16x8*)&Bs1[((wc << 6) + (i << 4) + (lane & 15)) * 64 + kk + ((lane >> 4) << 3)];
      }
      #pragma unroll
      for (int mi = 0; mi < 4; ++mi)
        #pragma unroll
        for (int ni = 0; ni < 4; ++ni)
          acc[mi][ni] = __builtin_amdgcn_mfma_f32_16x16x32_bf16(af[mi], bfr[ni], acc[mi][ni], 0, 0, 0);
    }
    __syncthreads();
  }

  float* dst = part + (size_t)blockIdx.z * 128 * N;
  #pragma unroll
  for (int ni = 0; ni < 4; ++ni) {
    const int col = tN + (wc << 6) + (ni << 4) + (lane & 15);
    #pragma unroll
    for (int mi = 0; mi < 4; ++mi) {
      #pragma unroll
      for (int j = 0; j < 4; ++j) {
        const int row = (wr << 6) + (mi << 4) + ((lane >> 4) << 2) + j;
        dst[(size_t)row * N + col] = acc[mi][ni][j];
      }
    }
  }
}

// ---------------- cr fin1: reduce part1(kc=8) + bias + relu -> A2 bf16 [128][1024] ----
__global__ void k_cr_fin1(const float* __restrict__ part1,
                          const float* __restrict__ camb1, const float* __restrict__ regb1,
                          u16* __restrict__ A2) {
  int r = blockIdx.x;
  int j = blockIdx.y * 256 + threadIdx.x;
  if (r >= 80) { A2[(size_t)r * N1 + j] = 0; return; }
  bool cam = (r < 16);
  int cm = j + (cam ? 0 : 1024);
  float s = 0.f;
  #pragma unroll
  for (int kc = 0; kc < 8; ++kc) s += part1[((size_t)kc * 128 + r) * 2048 + cm];
  s += cam ? camb1[j] : regb1[j];
  A2[(size_t)r * N1 + j] = f2b(fmaxf(s, 0.f));
}

// ---------------- cr fin2: reduce part2(kc=8) + bias + l2norm + clip^p -> hp[80][512] -
__global__ __launch_bounds__(512)
void k_cr_fin2(const float* __restrict__ part2,
               const float* __restrict__ camb2, const float* __restrict__ regb2,
               const float* __restrict__ camp, const float* __restrict__ regp,
               float* __restrict__ hp) {
  __shared__ float red[8];
  int r = blockIdx.x;
  int j = threadIdx.x;
  bool cam = (r < 16);
  int cm = j + (cam ? 0 : 512);
  float s = 0.f;
  #pragma unroll
  for (int kc = 0; kc < 8; ++kc) s += part2[((size_t)kc * 128 + r) * 1024 + cm];
  s += cam ? camb2[j] : regb2[j];
  float ss = s * s;
  #pragma unroll
  for (int o = 32; o; o >>= 1) ss += __shfl_down(ss, o);
  if ((j & 63) == 0) red[j >> 6] = ss;
  __syncthreads();
  float tot = 0.f;
  #pragma unroll
  for (int i = 0; i < 8; ++i) tot += red[i];
  float inv = 1.f / fmaxf(sqrtf(tot), 1e-12f);
  float t = fmaxf(s * inv, 1e-6f);
  hp[(size_t)r * 512 + j] = powf(t, cam ? camp[0] : regp[0]);
}

// ---------------- cr3a: GeM finalize -> gsb[8][512] ----------------
__global__ __launch_bounds__(512)
void k_cr3a(const float* __restrict__ hp, const float* __restrict__ camp,
            const float* __restrict__ regp, float* __restrict__ gsb) {
  int pb = blockIdx.x;
  bool cam = (pb < 4);
  int b = pb & 3;
  float p = cam ? camp[0] : regp[0];
  int L = cam ? 4 : 16;
  int row0 = cam ? b * 4 : 16 + b * 16;
  int o = threadIdx.x;
  float s = 0.f;
  for (int r = 0; r < L; ++r) s += hp[(size_t)(row0 + r) * 512 + o];
  gsb[pb * 512 + o] = powf(s / (float)L, 1.f / p);
}

// ---------------- cr3b: o1[8][512] = ReLU(gs @ W3 + b3), k-split x4 ----------------
__global__ __launch_bounds__(512)
void k_cr3b(const float* __restrict__ gsb,
            const float* __restrict__ camw3, const float* __restrict__ regw3,
            const float* __restrict__ camb3, const float* __restrict__ regb3,
            float* __restrict__ o1b) {
  __shared__ float gls[512];
  __shared__ float part[4][128];
  int pb = blockIdx.x, och = blockIdx.y;
  bool cam = (pb < 4);
  const float* W3 = cam ? camw3 : regw3;
  const float* B3 = cam ? camb3 : regb3;
  int tid = threadIdx.x;
  gls[tid] = gsb[pb * 512 + tid];
  __syncthreads();
  int col = tid & 127, kq = tid >> 7;
  int o = (och << 7) + col;
  float acc = 0.f;
  const float* w = W3 + (size_t)(kq << 7) * 512 + o;
  #pragma unroll 8
  for (int kk = 0; kk < 128; ++kk) acc += gls[(kq << 7) + kk] * w[(size_t)kk * 512];
  part[kq][col] = acc;
  __syncthreads();
  if (kq == 0) {
    float s = part[0][col] + part[1][col] + part[2][col] + part[3][col] + B3[o];
    o1b[pb * 512 + o] = fmaxf(s, 0.f);
  }
}

// ---------------- cr3c: out = l2norm(o1 @ W4 + b4), k-split x2 + block l2norm -------
__global__ __launch_bounds__(512)
void k_cr3c(const float* __restrict__ o1b,
            const float* __restrict__ camw4, const float* __restrict__ regw4,
            const float* __restrict__ camb4, const float* __restrict__ regb4,
            float* __restrict__ out) {
  __shared__ float o1s[512];
  __shared__ float part[2][256];
  __shared__ float vsq[256];
  __shared__ float red[4];
  int pb = blockIdx.x;
  bool cam = (pb < 4);
  int path = pb >> 2, b = pb & 3;
  const float* W4 = cam ? camw4 : regw4;
  const float* B4 = cam ? camb4 : regb4;
  int tid = threadIdx.x;
  o1s[tid] = o1b[pb * 512 + tid];
  __syncthreads();
  int col = tid & 255, kh = tid >> 8;
  float acc = 0.f;
  const float* w = W4 + (size_t)(kh << 8) * 256 + col;
  #pragma unroll 8
  for (int kk = 0; kk < 256; ++kk) acc += o1s[(kh << 8) + kk] * w[(size_t)kk * 256];
  part[kh][col] = acc;
  __syncthreads();
  float val = 0.f;
  if (kh == 0) {
    val = part[0][col] + part[1][col] + B4[col];
    vsq[col] = val * val;
  }
  __syncthreads();
  float ss = (tid < 256) ? vsq[tid] : 0.f;
  #pragma unroll
  for (int o = 32; o; o >>= 1) ss += __shfl_down(ss, o);
  if (tid < 256 && (tid & 63) == 0) red[tid >> 6] = ss;
  __syncthreads();
  if (kh == 0) {
    float tot = red[0] + red[1] + red[2] + red[3];
    float inv = 1.f / fmaxf(sqrtf(tot), 1e-12f);
    out[(size_t)b * 8704 + 8192 + path * 256 + col] = val * inv;
  }
}

// ---------------- scores transpose: FS[:,128:192] -> Sc[B][65][4096] (+dust row) ----
__global__ void k_tr_scores(const float* __restrict__ FS, const float* __restrict__ dust,
                            float* __restrict__ Sc) {
  __shared__ float t[64][65];
  int b = blockIdx.x >> 6, n0 = (blockIdx.x & 63) * 64;
  int tx = threadIdx.x & 63, ty = threadIdx.x >> 6;
  for (int r = ty; r < 64; r += 4)
    t[r][tx] = FS[((size_t)(b * NPB + n0 + r)) * N2 + 128 + tx];
  __syncthreads();
  for (int k = ty; k < 64; k += 4)
    Sc[((size_t)(b * MA) + k) * NPB + n0 + tx] = t[tx][k];
  if (threadIdx.x < 64)
    Sc[((size_t)(b * MA) + 64) * NPB + n0 + threadIdx.x] = dust[0];
}

// ---------------- sinkhorn: u update — one-pass online LSE over n=4096 ----------------
__global__ void k_sink_u(const float* __restrict__ Sc, const float* __restrict__ v,
                         float* __restrict__ u) {
  __shared__ float redm[4], reds[4];
  int b = blockIdx.x / MA, k = blockIdx.x % MA;
  const float* row = Sc + ((size_t)(b * MA) + k) * NPB;
  const float* vb = v + (size_t)b * NPB;
  int tid = threadIdx.x;
  float mx = -1e30f, s = 0.f;
  for (int n = tid; n < NPB; n += 256) {
    float x = row[n] + vb[n];
    float m2 = fmaxf(mx, x);
    s = s * __expf(mx - m2) + __expf(x - m2);
    mx = m2;
  }
  #pragma unroll
  for (int o = 32; o; o >>= 1) {
    float mo = __shfl_down(mx, o), so = __shfl_down(s, o);
    float m2 = fmaxf(mx, mo);
    s = s * __expf(mx - m2) + so * __expf(mo - m2);
    mx = m2;
  }
  if ((tid & 63) == 0) { redm[tid >> 6] = mx; reds[tid >> 6] = s; }
  __syncthreads();
  if (tid == 0) {
    float M = redm[0];
    #pragma unroll
    for (int i = 1; i < 4; ++i) M = fmaxf(M, redm[i]);
    float S = 0.f;
    #pragma unroll
    for (int i = 0; i < 4; ++i) S += reds[i] * __expf(redm[i] - M);
    const float nrm = -logf((float)(NPB + MD));
    float la = (k == MD) ? (nrm + logf((float)(NPB - MD))) : nrm;
    u[b * MA + k] = la - (M + __logf(S));
  }
}

// ---------------- sinkhorn: v update (col LSE over m+1=65) ----------------
__global__ void k_sink_v(const float* __restrict__ Sc, const float* __restrict__ u,
                         float* __restrict__ v) {
  __shared__ float us[MA];
  int b = blockIdx.x >> 4;
  int n = ((blockIdx.x & 15) << 8) + threadIdx.x;
  if (threadIdx.x < MA) us[threadIdx.x] = u[b * MA + threadIdx.x];
  __syncthreads();
  const float* Sb = Sc + (size_t)b * MA * NPB + n;
  float mx = -1e30f;
  for (int k = 0; k < MA; ++k) mx = fmaxf(mx, Sb[(size_t)k * NPB] + us[k]);
  float s = 0.f;
  for (int k = 0; k < MA; ++k) s += __expf(Sb[(size_t)k * NPB] + us[k] - mx);
  const float nrm = -logf((float)(NPB + MD));
  v[(size_t)b * NPB + n] = nrm - (mx + __logf(s));
}

// ---------------- pooled stage 1 (P fused): partial[b][j][c][k] over 64-n chunks ------
__global__ __launch_bounds__(256)
void k_pooled1(const float* __restrict__ FS, const float* __restrict__ Sc,
               const float* __restrict__ u, const float* __restrict__ v,
               float* __restrict__ partial) {
  __shared__ float Fs[64][132];
  __shared__ float Ps[64][68];
  int b = blockIdx.x >> 6, j = blockIdx.x & 63;
  int n0 = j << 6;
  int tid = threadIdx.x;
  {
    int r = tid >> 5;
    int c4 = (tid & 31) << 2;
    #pragma unroll
    for (int i = 0; i < 8; ++i) {
      int n = r + (i << 3);
      float4 vv = *(const float4*)&FS[((size_t)(b * NPB + n0 + n)) * N2 + c4];
      *(float4*)&Fs[n][c4] = vv;
    }
  }
  {
    const float nrm = -logf((float)(NPB + MD));
    int r = tid >> 4;
    int c4 = (tid & 15) << 2;
    #pragma unroll
    for (int i = 0; i < 4; ++i) {
      int k = r + (i << 4);
      float uk = u[b * MA + k];
      float4 sv = *(const float4*)&Sc[((size_t)(b * MA) + k) * NPB + n0 + c4];
      float4 vv = *(const float4*)&v[(size_t)b * NPB + n0 + c4];
      float4 o;
      o.x = __expf(sv.x + uk + vv.x - nrm);
      o.y = __expf(sv.y + uk + vv.y - nrm);
      o.z = __expf(sv.z + uk + vv.z - nrm);
      o.w = __expf(sv.w + uk + vv.w - nrm);
      *(float4*)&Ps[k][c4] = o;
    }
  }
  __syncthreads();
  int tc = tid & 31, tk = tid >> 5;
  int c0 = tc << 2, k0 = tk << 3;
  float acc[4][8];
  #pragma unroll
  for (int i = 0; i < 4; ++i)
    #pragma unroll
    for (int kk = 0; kk < 8; ++kk) acc[i][kk] = 0.f;
  for (int n = 0; n < 64; ++n) {
    float4 f = *(const float4*)&Fs[n][c0];
    float pv[8];
    #pragma unroll
    for (int kk = 0; kk < 8; ++kk) pv[kk] = Ps[k0 + kk][n];
    #pragma unroll
    for (int i = 0; i < 4; ++i) {
      float fv = ((const float*)&f)[i];
      #pragma unroll
      for (int kk = 0; kk < 8; ++kk) acc[i][kk] += fv * pv[kk];
    }
  }
  float* dst = partial + ((size_t)(b * 64 + j) << 13);
  #pragma unroll
  for (int i = 0; i < 4; ++i) {
    float4 lo = {acc[i][0], acc[i][1], acc[i][2], acc[i][3]};
    float4 hi = {acc[i][4], acc[i][5], acc[i][6], acc[i][7]};
    *(float4*)&dst[((c0 + i) << 6) + k0] = lo;
    *(float4*)&dst[((c0 + i) << 6) + k0 + 4] = hi;
  }
}

// ---------------- pooled stage 2: reduce 64 partials, coalesced ----------------
__global__ void k_pooled2(const float* __restrict__ partial, float* __restrict__ pooled) {
  int o = blockIdx.x * 256 + threadIdx.x;
  int b = o >> 13, rem = o & 8191;
  const float* src = partial + ((size_t)b << 19) + rem;
  float s = 0.f;
  #pragma unroll 8
  for (int j = 0; j < 64; ++j) s += src[(size_t)j << 13];
  pooled[o] = s;
}

// ---------------- patch output: l2norm over c (128), write [b][c*64+k] --------------
__global__ void k_patch_out(const float* __restrict__ pooled, float* __restrict__ out) {
  int b = blockIdx.x >> 6, k = blockIdx.x & 63;
  int tid = threadIdx.x;
  float v0 = pooled[((size_t)(b * 128) + tid) * MD + k];
  float v1 = pooled[((size_t)(b * 128) + 64 + tid) * MD + k];
  float ss = v0 * v0 + v1 * v1;
  #pragma unroll
  for (int o = 32; o; o >>= 1) ss += __shfl_down(ss, o);
  ss = __shfl(ss, 0);
  float inv = 1.f / fmaxf(sqrtf(ss), 1e-12f);
  out[(size_t)b * 8704 + tid * 64 + k] = v0 * inv;
  out[(size_t)b * 8704 + (64 + tid) * 64 + k] = v1 * inv;
}

// ---------------- workspace layout (bytes) ----------------
// lifetime rule: below 67,108,864 overlaps Abf (live until GEMM1 done);
// 67,108,864..100,663,296 overlaps H (live GEMM1->GEMM2). cr path runs AFTER GEMM2.
// GSB/O1B reuse CP1 region (cp1 last read by k_cr_fin1; cr3a runs after k_cr_fin2).
#define OFF_ABF 0u
#define OFF_SC 0u
#define OFF_U 4259840u
#define OFF_V 4263936u
#define OFF_POOL 8523776u
#define OFF_HP 8982528u                   // written post-GEMM2 only!
#define OFF_H 67108864u
#define OFF_PART OFF_H                    // 8,388,608 (disjoint from CP1)
#define OFF_CP1 75497472u
#define OFF_GSB OFF_CP1                   // 8*512*4 = 16,384
#define OFF_O1B 75513856u                 // 8*512*4 = 16,384
#define OFF_CP2 83886080u
#define OFF_BT1CR 88080384u
#define OFF_BT2CR 96468992u
#define OFF_ACR 98566144u
#define OFF_A2 99090432u
#define OFF_FS 100663296u
#define OFF_W1T 117440512u
#define OFF_W2T 121634816u
#define OFF_B1C 122159104u
#define OFF_B2C 122163200u

extern "C" void kernel_launch(void* const* d_in, const int* in_sizes, int n_in,
                              void* d_out, int out_size, void* d_ws, size_t ws_size,
                              hipStream_t stream) {
  (void)in_sizes; (void)n_in; (void)out_size; (void)ws_size;
  const float* tokens = (const float*)d_in[0];
  const float* cam_w1 = (const float*)d_in[2];
  const float* cam_b1 = (const float*)d_in[3];
  const float* cam_w2 = (const float*)d_in[4];
  const float* cam_b2 = (const float*)d_in[5];
  const float* cam_p  = (const float*)d_in[6];
  const float* cam_w3 = (const float*)d_in[7];
  const float* cam_b3 = (const float*)d_in[8];
  const float* cam_w4 = (const float*)d_in[9];
  const float* cam_b4 = (const float*)d_in[10];
  const float* reg_w1 = (const float*)d_in[11];
  const float* reg_b1 = (const float*)d_in[12];
  const float* reg_w2 = (const float*)d_in[13];
  const float* reg_b2 = (const float*)d_in[14];
  const float* reg_p  = (const float*)d_in[15];
  const float* reg_w3 = (const float*)d_in[16];
  const float* reg_b3 = (const float*)d_in[17];
  const float* reg_w4 = (const float*)d_in[18];
  const float* reg_b4 = (const float*)d_in[19];
  const float* pf_w1  = (const float*)d_in[20];
  const float* pf_b1  = (const float*)d_in[21];
  const float* pf_w2  = (const float*)d_in[22];
  const float* pf_b2  = (const float*)d_in[23];
  const float* ps_w1  = (const float*)d_in[24];
  const float* ps_b1  = (const float*)d_in[25];
  const float* ps_w2  = (const float*)d_in[26];
  const float* ps_b2  = (const float*)d_in[27];
  const float* dust   = (const float*)d_in[28];
  float* out = (float*)d_out;
  char* ws = (char*)d_ws;

  u16* Abf = (u16*)(ws + OFF_ABF);
  float* Sc = (float*)(ws + OFF_SC);
  float* ub = (float*)(ws + OFF_U);
  float* vb = (float*)(ws + OFF_V);
  float* pooled = (float*)(ws + OFF_POOL);
  float* hp = (float*)(ws + OFF_HP);
  u16* H   = (u16*)(ws + OFF_H);
  float* partial = (float*)(ws + OFF_PART);
  float* cp1 = (float*)(ws + OFF_CP1);
  float* gsb = (float*)(ws + OFF_GSB);
  float* o1b = (float*)(ws + OFF_O1B);
  float* cp2 = (float*)(ws + OFF_CP2);
  u16* Bt1cr = (u16*)(ws + OFF_BT1CR);
  u16* Bt2cr = (u16*)(ws + OFF_BT2CR);
  u16* Acr = (u16*)(ws + OFF_ACR);
  u16* A2  = (u16*)(ws + OFF_A2);
  float* FS = (float*)(ws + OFF_FS);
  u16* W1t = (u16*)(ws + OFF_W1T);
  u16* W2t = (u16*)(ws + OFF_W2T);
  float* b1c = (float*)(ws + OFF_B1C);
  float* b2c = (float*)(ws + OFF_B2C);

  hipMemsetAsync(vb, 0, (size_t)B_ * NPB * sizeof(float), stream);

  // ---- patch packs + GEMMs ----
  k_convert_patch<<<16384, 256, 0, stream>>>(tokens, Abf);
  k_pack_patch<<<2308, 256, 0, stream>>>(pf_w1, ps_w1, pf_w2, ps_w2,
                                         pf_b1, ps_b1, pf_b2, ps_b2,
                                         W1t, W2t, b1c, b2c);
  k_gemm<1, 1><<<dim3(128, 8), 256, 0, stream>>>(Abf, W1t, b1c, (void*)H, MROWS, N1, CDIM);
  k_gemm<0, 0><<<dim3(128, 2), 256, 0, stream>>>(H, W2t, b2c, (void*)FS, MROWS, N2, N1);

  // ---- cam/reg path (Abf and H regions now dead) ----
  k_pack_cr<<<5248, 256, 0, stream>>>(cam_w1, reg_w1, cam_w2, reg_w2, tokens,
                                      Bt1cr, Bt2cr, Acr);
  k_gemm_splitk<<<dim3(1, 16, 8), 256, 0, stream>>>(Acr, Bt1cr, cp1, 2048, CDIM, 256);
  k_cr_fin1<<<dim3(128, 4), 256, 0, stream>>>(cp1, cam_b1, reg_b1, A2);
  k_gemm_splitk<<<dim3(1, 8, 8), 256, 0, stream>>>(A2, Bt2cr, cp2, 1024, N1, 128);
  k_cr_fin2<<<80, 512, 0, stream>>>(cp2, cam_b2, reg_b2, cam_p, reg_p, hp);
  k_cr3a<<<8, 512, 0, stream>>>(hp, cam_p, reg_p, gsb);
  k_cr3b<<<dim3(8, 4), 512, 0, stream>>>(gsb, cam_w3, reg_w3, cam_b3, reg_b3, o1b);
  k_cr3c<<<8, 512, 0, stream>>>(o1b, cam_w4, reg_w4, cam_b4, reg_b4, out);

  // ---- sinkhorn + pooled + outputs ----
  k_tr_scores<<<256, 256, 0, stream>>>(FS, dust, Sc);
  for (int it = 0; it < 3; ++it) {
    k_sink_u<<<B_ * MA, 256, 0, stream>>>(Sc, vb, ub);
    k_sink_v<<<B_ * 16, 256, 0, stream>>>(Sc, ub, vb);
  }
  k_pooled1<<<B_ * 64, 256, 0, stream>>>(FS, Sc, ub, vb, partial);
  k_pooled2<<<128, 256, 0, stream>>>(partial, pooled);
  k_patch_out<<<B_ * MD, 64, 0, stream>>>(pooled, out);
}

// Round 9
// 242.597 us; speedup vs baseline: 3.0031x; 1.0124x over previous
//
#include <hip/hip_runtime.h>

typedef unsigned short u16;
typedef unsigned int u32;

#define B_ 4
#define S_ 4
#define NTOK 1029
#define CDIM 2048
#define PSI 5
#define NPB 4096
#define MROWS 16384
#define N1 1024
#define N2 256
#define MD 64
#define MA 65

using bf16x8 = __attribute__((ext_vector_type(8))) short;
using f32x4  = __attribute__((ext_vector_type(4))) float;
using u16x8  = __attribute__((ext_vector_type(8))) unsigned short;

typedef __attribute__((address_space(1))) const void global_cvoid;
typedef __attribute__((address_space(3))) void lds_void;

__device__ __forceinline__ u16 f2b(float f) {
  u32 u = __builtin_bit_cast(u32, f);
  u32 r = (u + 0x7fffu + ((u >> 16) & 1u)) >> 16;
  return (u16)r;
}

// ---------------- prep: gather patch tokens, convert fp32 -> bf16 ----------------
__global__ void k_convert_patch(const float* __restrict__ tokens, u16* __restrict__ Abf) {
  size_t idx = (size_t)blockIdx.x * 256 + threadIdx.x;
  size_t r = idx >> 8;
  int cv = (int)(idx & 255) << 3;
  int b = (int)(r >> 12), s = (int)((r >> 10) & 3), j = (int)(r & 1023);
  const float* src = tokens + ((size_t)((b * S_ + s) * NTOK + PSI + j)) * CDIM + cv;
  float4 v0 = *(const float4*)src;
  float4 v1 = *(const float4*)(src + 4);
  u16x8 o;
  o[0] = f2b(v0.x); o[1] = f2b(v0.y); o[2] = f2b(v0.z); o[3] = f2b(v0.w);
  o[4] = f2b(v1.x); o[5] = f2b(v1.y); o[6] = f2b(v1.z); o[7] = f2b(v1.w);
  *(u16x8*)(Abf + r * CDIM + cv) = o;
}

// ---------------- merged patch-side packs: W1t, W2t, biases ----------------
__global__ void k_pack_patch(const float* __restrict__ pfw1, const float* __restrict__ psw1,
                             const float* __restrict__ pfw2, const float* __restrict__ psw2,
                             const float* __restrict__ pfb1, const float* __restrict__ psb1,
                             const float* __restrict__ pfb2, const float* __restrict__ psb2,
                             u16* __restrict__ W1t, u16* __restrict__ W2t,
                             float* __restrict__ b1c, float* __restrict__ b2c) {
  __shared__ float tile[32][33];
  int id = blockIdx.x, tid = threadIdx.x;
  int tx = tid & 31, ty = tid >> 5;
  if (id < 2048) {
    int kb = (id & 63) * 32, nb = (id >> 6) * 32;
    #pragma unroll
    for (int i = 0; i < 4; ++i) {
      int k = kb + ty + i * 8, n = nb + tx;
      tile[ty + i * 8][tx] = (n < 512) ? pfw1[(size_t)k * 512 + n] : psw1[(size_t)k * 512 + (n - 512)];
    }
    __syncthreads();
    #pragma unroll
    for (int i = 0; i < 4; ++i) {
      int n = nb + ty + i * 8, k = kb + tx;
      W1t[(size_t)n * CDIM + k] = f2b(tile[tx][ty + i * 8]);
    }
  } else if (id < 2304) {
    int i2 = id - 2048;
    int kb = (i2 & 31) * 32, jb = (i2 >> 5) * 32;
    #pragma unroll
    for (int i = 0; i < 4; ++i) {
      int k = kb + ty + i * 8, j = jb + tx;
      float v = 0.f;
      if (j < 128) { if (k < 512) v = pfw2[(size_t)k * 128 + j]; }
      else if (j < 192) { if (k >= 512) v = psw2[(size_t)(k - 512) * 64 + (j - 128)]; }
      tile[ty + i * 8][tx] = v;
    }
    __syncthreads();
    #pragma unroll
    for (int i = 0; i < 4; ++i) {
      int j = jb + ty + i * 8, k = kb + tx;
      W2t[(size_t)j * N1 + k] = f2b(tile[tx][ty + i * 8]);
    }
  } else {
    int t = (id - 2304) * 256 + tid;
    if (t < 1024) b1c[t] = (t < 512) ? pfb1[t] : psb1[t - 512];
    if (t < 256)  b2c[t] = (t < 128) ? pfb2[t] : ((t < 192) ? psb2[t - 128] : 0.f);
  }
}

// ---------------- merged cr-side packs: Bt1cr, Bt2cr, Acr ----------------
__global__ void k_pack_cr(const float* __restrict__ camw1, const float* __restrict__ regw1,
                          const float* __restrict__ camw2, const float* __restrict__ regw2,
                          const float* __restrict__ tokens,
                          u16* __restrict__ Bt1cr, u16* __restrict__ Bt2cr,
                          u16* __restrict__ Acr) {
  __shared__ float tile[32][33];
  int id = blockIdx.x, tid = threadIdx.x;
  int tx = tid & 31, ty = tid >> 5;
  if (id < 4096) {
    const float* src = (id < 2048) ? camw1 : regw1;
    u16* dst = Bt1cr + ((id < 2048) ? 0 : (size_t)1024 * CDIM);
    int i2 = id & 2047;
    int kb = (i2 & 63) * 32, nb = (i2 >> 6) * 32;
    #pragma unroll
    for (int i = 0; i < 4; ++i)
      tile[ty + i * 8][tx] = src[(size_t)(kb + ty + i * 8) * 1024 + nb + tx];
    __syncthreads();
    #pragma unroll
    for (int i = 0; i < 4; ++i)
      dst[(size_t)(nb + ty + i * 8) * CDIM + kb + tx] = f2b(tile[tx][ty + i * 8]);
  } else if (id < 5120) {
    int i3 = id - 4096;
    const float* src = (i3 < 512) ? camw2 : regw2;
    u16* dst = Bt2cr + ((i3 < 512) ? 0 : (size_t)512 * N1);
    int i2 = i3 & 511;
    int kb = (i2 & 31) * 32, nb = (i2 >> 5) * 32;
    #pragma unroll
    for (int i = 0; i < 4; ++i)
      tile[ty + i * 8][tx] = src[(size_t)(kb + ty + i * 8) * 512 + nb + tx];
    __syncthreads();
    #pragma unroll
    for (int i = 0; i < 4; ++i)
      dst[(size_t)(nb + ty + i * 8) * N1 + kb + tx] = f2b(tile[tx][ty + i * 8]);
  } else {
    int r = id - 5120;
    int c0 = tid << 3;
    u16x8 o;
    if (r >= 80) {
      #pragma unroll
      for (int i = 0; i < 8; ++i) o[i] = 0;
    } else {
      const float* src;
      if (r < 16) { int b = r >> 2, s = r & 3; src = tokens + ((size_t)(b * S_ + s) * NTOK) * CDIM; }
      else { int r2 = r - 16; int b = r2 >> 4, q = r2 & 15, s = q >> 2, t = (q & 3) + 1;
             src = tokens + ((size_t)(b * S_ + s) * NTOK + t) * CDIM; }
      float4 v0 = *(const float4*)(src + c0);
      float4 v1 = *(const float4*)(src + c0 + 4);
      o[0] = f2b(v0.x); o[1] = f2b(v0.y); o[2] = f2b(v0.z); o[3] = f2b(v0.w);
      o[4] = f2b(v1.x); o[5] = f2b(v1.y); o[6] = f2b(v1.z); o[7] = f2b(v1.w);
    }
    *(u16x8*)(Acr + (size_t)r * CDIM + c0) = o;
  }
}

// ================= 256x256 bf16 MFMA GEMM: 8 waves, 2-buf, counted vmcnt, swizzle ====
// Per-wave output 128x64 (wr in {0,1}, wc in {0..3}); acc[8][4] f32x4.
// LDS 128 KB: As[2][256*64] + Bs[2][256*64] bf16. Same schedule as the proven 128^2
// kernel (vmcnt(8) ledger: 8 global_load_lds per tile), same XOR col-swizzle
// (row&7 == lane&7 on both staging and read side).
#define STAGE_TILE256(buf, k0)                                                 \
  {                                                                            \
    _Pragma("unroll")                                                          \
    for (int r = 0; r < 4; ++r) {                                              \
      __builtin_amdgcn_global_load_lds(                                        \
          (global_cvoid*)(A + abase + (size_t)(r * 64) * K + (k0)),            \
          (lds_void*)(&As[buf][(r << 12) + lofs]), 16, 0, 0);                  \
      __builtin_amdgcn_global_load_lds(                                        \
          (global_cvoid*)(Bt + bbase + (size_t)(r * 64) * K + (k0)),           \
          (lds_void*)(&Bs[buf][(r << 12) + lofs]), 16, 0, 0);                  \
    }                                                                          \
  }

#define COMPUTE_TILE256(buf)                                                   \
  {                                                                            \
    _Pragma("unroll")                                                          \
    for (int kk = 0; kk < 64; kk += 32) {                                      \
      const int csw = (kk + hi8) ^ ((lane & 7) << 3);                          \
      bf16x8 bfr[4], af[8];                                                    \
      _Pragma("unroll")                                                        \
      for (int i = 0; i < 4; ++i)                                              \
        bfr[i] = *(const bf16x8*)&Bs[buf][((wc << 6) + (i << 4) + (lane & 15)) * 64 + csw]; \
      _Pragma("unroll")                                                        \
      for (int i = 0; i < 8; ++i)                                              \
        af[i]  = *(const bf16x8*)&As[buf][((wr << 7) + (i << 4) + (lane & 15)) * 64 + csw]; \
      __builtin_amdgcn_s_setprio(1);                                           \
      _Pragma("unroll")                                                        \
      for (int mi = 0; mi < 8; ++mi)                                           \
        _Pragma("unroll")                                                      \
        for (int ni = 0; ni < 4; ++ni)                                         \
          acc[mi][ni] = __builtin_amdgcn_mfma_f32_16x16x32_bf16(af[mi], bfr[ni], acc[mi][ni], 0, 0, 0); \
      __builtin_amdgcn_s_setprio(0);                                           \
    }                                                                          \
  }

template <int RELU, int OUTBF>
__global__ __launch_bounds__(512, 1)
void k_gemm256(const u16* __restrict__ A, const u16* __restrict__ Bt,
               const float* __restrict__ bias, void* __restrict__ Cout,
               int M, int N, int K) {
  __shared__ u16 As[2][256 * 64];
  __shared__ u16 Bs[2][256 * 64];
  const int tid = threadIdx.x;
  const int lane = tid & 63;
  const int wave = tid >> 6;
  const int tM = blockIdx.x << 8;
  const int tN = blockIdx.y << 8;
  const int wr = wave >> 2, wc = wave & 3;
  const int hi8 = (lane >> 4) << 3;

  const int srow = tid >> 3;                       // 0..63
  const int scolsw = ((tid & 7) ^ (srow & 7)) << 3;  // swizzled source col
  const size_t abase = (size_t)(tM + srow) * K + scolsw;
  const size_t bbase = (size_t)(tN + srow) * K + scolsw;
  const int lofs = tid << 3;                       // linear LDS dest (elements)

  f32x4 acc[8][4];
  #pragma unroll
  for (int i = 0; i < 8; ++i)
    #pragma unroll
    for (int j = 0; j < 4; ++j)
      acc[i][j] = (f32x4){0.f, 0.f, 0.f, 0.f};

  const int nt = K >> 6;            // 32 for K=2048 (even, >= 4)
  STAGE_TILE256(0, 0)
  STAGE_TILE256(1, 64)
  for (int t = 0; t < nt; t += 2) {
    asm volatile("s_waitcnt vmcnt(8)" ::: "memory");
    __builtin_amdgcn_s_barrier();
    COMPUTE_TILE256(0)
    __builtin_amdgcn_s_barrier();
    if (t + 2 < nt) STAGE_TILE256(0, (t + 2) << 6)
    if (t + 1 == nt - 1) {
      asm volatile("s_waitcnt vmcnt(0)" ::: "memory");
    } else {
      asm volatile("s_waitcnt vmcnt(8)" ::: "memory");
    }
    __builtin_amdgcn_s_barrier();
    COMPUTE_TILE256(1)
    __builtin_amdgcn_s_barrier();
    if (t + 3 < nt) STAGE_TILE256(1, (t + 3) << 6)
  }

  #pragma unroll
  for (int ni = 0; ni < 4; ++ni) {
    const int col = tN + (wc << 6) + (ni << 4) + (lane & 15);
    const float bv = bias[col];
    #pragma unroll
    for (int mi = 0; mi < 8; ++mi) {
      #pragma unroll
      for (int j = 0; j < 4; ++j) {
        const int row = tM + (wr << 7) + (mi << 4) + ((lane >> 4) << 2) + j;
        float vv = acc[mi][ni][j] + bv;
        if (RELU) vv = fmaxf(vv, 0.f);
        if (OUTBF) ((u16*)Cout)[(size_t)row * N + col] = f2b(vv);
        else       ((float*)Cout)[(size_t)row * N + col] = vv;
      }
    }
  }
}

// ---------------- 128^2 bf16 MFMA GEMM (R8-proven): used for GEMM2 ----------------
#define STAGE_TILE(buf, k0)                                                    \
  {                                                                            \
    _Pragma("unroll")                                                          \
    for (int r = 0; r < 4; ++r) {                                              \
      __builtin_amdgcn_global_load_lds(                                        \
          (global_cvoid*)(A + abase + (size_t)(r * 32) * K + (k0)),            \
          (lds_void*)(&As[buf][lofs + r * 2048]), 16, 0, 0);                   \
      __builtin_amdgcn_global_load_lds(                                        \
          (global_cvoid*)(Bt + bbase + (size_t)(r * 32) * K + (k0)),           \
          (lds_void*)(&Bs[buf][lofs + r * 2048]), 16, 0, 0);                   \
    }                                                                          \
  }

#define COMPUTE_TILE(buf)                                                      \
  {                                                                            \
    _Pragma("unroll")                                                          \
    for (int kk = 0; kk < 64; kk += 32) {                                      \
      const int csw = (kk + hi8) ^ ((lane & 7) << 3);                          \
      bf16x8 af[4], bfr[4];                                                    \
      _Pragma("unroll")                                                        \
      for (int i = 0; i < 4; ++i) {                                            \
        af[i]  = *(const bf16x8*)&As[buf][((wr << 6) + (i << 4) + (lane & 15)) * 64 + csw]; \
        bfr[i] = *(const bf16x8*)&Bs[buf][((wc << 6) + (i << 4) + (lane & 15)) * 64 + csw]; \
      }                                                                        \
      _Pragma("unroll")                                                        \
      for (int mi = 0; mi < 4; ++mi)                                           \
        _Pragma("unroll")                                                      \
        for (int ni = 0; ni < 4; ++ni)                                         \
          acc[mi][ni] = __builtin_amdgcn_mfma_f32_16x16x32_bf16(af[mi], bfr[ni], acc[mi][ni], 0, 0, 0); \
    }                                                                          \
  }

template <int RELU, int OUTBF>
__global__ __launch_bounds__(256, 2)
void k_gemm(const u16* __restrict__ A, const u16* __restrict__ Bt,
            const float* __restrict__ bias, void* __restrict__ Cout,
            int M, int N, int K) {
  __shared__ u16 As[2][128 * 64];
  __shared__ u16 Bs[2][128 * 64];
  const int tid = threadIdx.x;
  const int lane = tid & 63;
  const int wave = tid >> 6;
  const int tM = blockIdx.x << 7;
  const int tN = blockIdx.y << 7;
  const int wr = wave >> 1, wc = wave & 1;
  const int hi8 = (lane >> 4) << 3;

  const int srow = (wave << 3) + (lane >> 3);
  const int scolsw = ((lane & 7) ^ (lane >> 3)) << 3;
  const size_t abase = (size_t)(tM + srow) * K + scolsw;
  const size_t bbase = (size_t)(tN + srow) * K + scolsw;
  const int lofs = (wave << 9) + (lane << 3);

  f32x4 acc[4][4];
  #pragma unroll
  for (int i = 0; i < 4; ++i)
    #pragma unroll
    for (int j = 0; j < 4; ++j)
      acc[i][j] = (f32x4){0.f, 0.f, 0.f, 0.f};

  const int nt = K >> 6;
  STAGE_TILE(0, 0)
  STAGE_TILE(1, 64)
  for (int t = 0; t < nt; t += 2) {
    asm volatile("s_waitcnt vmcnt(8)" ::: "memory");
    __builtin_amdgcn_s_barrier();
    COMPUTE_TILE(0)
    __builtin_amdgcn_s_barrier();
    if (t + 2 < nt) STAGE_TILE(0, (t + 2) << 6)
    if (t + 1 == nt - 1) {
      asm volatile("s_waitcnt vmcnt(0)" ::: "memory");
    } else {
      asm volatile("s_waitcnt vmcnt(8)" ::: "memory");
    }
    __builtin_amdgcn_s_barrier();
    COMPUTE_TILE(1)
    __builtin_amdgcn_s_barrier();
    if (t + 3 < nt) STAGE_TILE(1, (t + 3) << 6)
  }

  #pragma unroll
  for (int ni = 0; ni < 4; ++ni) {
    const int col = tN + (wc << 6) + (ni << 4) + (lane & 15);
    const float bv = bias[col];
    #pragma unroll
    for (int mi = 0; mi < 4; ++mi) {
      #pragma unroll
      for (int j = 0; j < 4; ++j) {
        const int row = tM + (wr << 6) + (mi << 4) + ((lane >> 4) << 2) + j;
        float vv = acc[mi][ni][j] + bv;
        if (RELU) vv = fmaxf(vv, 0.f);
        if (OUTBF) ((u16*)Cout)[(size_t)row * N + col] = f2b(vv);
        else       ((float*)Cout)[(size_t)row * N + col] = vv;
      }
    }
  }
}

// ---------------- split-K MFMA GEMM, M=128 fixed (single-buffer, known-good) ----
__global__ __launch_bounds__(256, 2)
void k_gemm_splitk(const u16* __restrict__ A, const u16* __restrict__ Bt,
                   float* __restrict__ part, int N, int K, int KC) {
  __shared__ u16 As1[128 * 64];
  __shared__ u16 Bs1[128 * 64];
  const int tid = threadIdx.x;
  const int lane = tid & 63;
  const int wave = tid >> 6;
  const int tN = blockIdx.y << 7;
  const int kb = blockIdx.z * KC;
  const int wr = wave >> 1, wc = wave & 1;
  const int srow = (wave << 3) + (lane >> 3);
  const int scol = (lane & 7) << 3;
  const size_t abase = (size_t)srow * K + scol;
  const size_t bbase = (size_t)(tN + srow) * K + scol;
  u16* asw = &As1[(wave << 9) + (lane << 3)];
  u16* bsw = &Bs1[(wave << 9) + (lane << 3)];

  f32x4 acc[4][4];
  #pragma unroll
  for (int i = 0; i < 4; ++i)
    #pragma unroll
    for (int j = 0; j < 4; ++j)
      acc[i][j] = (f32x4){0.f, 0.f, 0.f, 0.f};

  for (int k0 = kb; k0 < kb + KC; k0 += 64) {
    #pragma unroll
    for (int r = 0; r < 4; ++r) {
      __builtin_amdgcn_global_load_lds(
          (global_cvoid*)(A + abase + (size_t)(r * 32) * K + k0),
          (lds_void*)(asw + r * 2048), 16, 0, 0);
      __builtin_amdgcn_global_load_lds(
          (global_cvoid*)(Bt + bbase + (size_t)(r * 32) * K + k0),
          (lds_void*)(bsw + r * 2048), 16, 0, 0);
    }
    __syncthreads();
    #pragma unroll
    for (int kk = 0; kk < 64; kk += 32) {
      bf16x8 af[4], bfr[4];
      #pragma unroll
      for (int i = 0; i < 4; ++i) {
        af[i]  = *(const bf16x8*)&As1[((wr << 6) + (i << 4) + (lane & 15)) * 64 + kk + ((lane >> 4) << 3)];
        bfr[i] = *(const bf16x8*)&Bs1[((wc << 6) + (i << 4) + (lane & 15)) * 64 + kk + ((lane >> 4) << 3)];
      }
      #pragma unroll
      for (int mi = 0; mi < 4; ++mi)
        #pragma unroll
        for (int ni = 0; ni < 4; ++ni)
          acc[mi][ni] = __builtin_amdgcn_mfma_f32_16x16x32_bf16(af[mi], bfr[ni], acc[mi][ni], 0, 0, 0);
    }
    __syncthreads();
  }

  float* dst = part + (size_t)blockIdx.z * 128 * N;
  #pragma unroll
  for (int ni = 0; ni < 4; ++ni) {
    const int col = tN + (wc << 6) + (ni << 4) + (lane & 15);
    #pragma unroll
    for (int mi = 0; mi < 4; ++mi) {
      #pragma unroll
      for (int j = 0; j < 4; ++j) {
        const int row = (wr << 6) + (mi << 4) + ((lane >> 4) << 2) + j;
        dst[(size_t)row * N + col] = acc[mi][ni][j];
      }
    }
  }
}

// ---------------- cr fin1: reduce part1(kc=8) + bias + relu -> A2 bf16 [128][1024] ----
__global__ void k_cr_fin1(const float* __restrict__ part1,
                          const float* __restrict__ camb1, const float* __restrict__ regb1,
                          u16* __restrict__ A2) {
  int r = blockIdx.x;
  int j = blockIdx.y * 256 + threadIdx.x;
  if (r >= 80) { A2[(size_t)r * N1 + j] = 0; return; }
  bool cam = (r < 16);
  int cm = j + (cam ? 0 : 1024);
  float s = 0.f;
  #pragma unroll
  for (int kc = 0; kc < 8; ++kc) s += part1[((size_t)kc * 128 + r) * 2048 + cm];
  s += cam ? camb1[j] : regb1[j];
  A2[(size_t)r * N1 + j] = f2b(fmaxf(s, 0.f));
}

// ---------------- cr fin2: reduce part2(kc=8) + bias + l2norm + clip^p -> hp[80][512] -
__global__ __launch_bounds__(512)
void k_cr_fin2(const float* __restrict__ part2,
               const float* __restrict__ camb2, const float* __restrict__ regb2,
               const float* __restrict__ camp, const float* __restrict__ regp,
               float* __restrict__ hp) {
  __shared__ float red[8];
  int r = blockIdx.x;
  int j = threadIdx.x;
  bool cam = (r < 16);
  int cm = j + (cam ? 0 : 512);
  float s = 0.f;
  #pragma unroll
  for (int kc = 0; kc < 8; ++kc) s += part2[((size_t)kc * 128 + r) * 1024 + cm];
  s += cam ? camb2[j] : regb2[j];
  float ss = s * s;
  #pragma unroll
  for (int o = 32; o; o >>= 1) ss += __shfl_down(ss, o);
  if ((j & 63) == 0) red[j >> 6] = ss;
  __syncthreads();
  float tot = 0.f;
  #pragma unroll
  for (int i = 0; i < 8; ++i) tot += red[i];
  float inv = 1.f / fmaxf(sqrtf(tot), 1e-12f);
  float t = fmaxf(s * inv, 1e-6f);
  hp[(size_t)r * 512 + j] = powf(t, cam ? camp[0] : regp[0]);
}

// ---------------- cr3a: GeM finalize -> gsb[8][512] ----------------
__global__ __launch_bounds__(512)
void k_cr3a(const float* __restrict__ hp, const float* __restrict__ camp,
            const float* __restrict__ regp, float* __restrict__ gsb) {
  int pb = blockIdx.x;
  bool cam = (pb < 4);
  int b = pb & 3;
  float p = cam ? camp[0] : regp[0];
  int L = cam ? 4 : 16;
  int row0 = cam ? b * 4 : 16 + b * 16;
  int o = threadIdx.x;
  float s = 0.f;
  for (int r = 0; r < L; ++r) s += hp[(size_t)(row0 + r) * 512 + o];
  gsb[pb * 512 + o] = powf(s / (float)L, 1.f / p);
}

// ---------------- cr3b: o1[8][512] = ReLU(gs @ W3 + b3), k-split x4 ----------------
__global__ __launch_bounds__(512)
void k_cr3b(const float* __restrict__ gsb,
            const float* __restrict__ camw3, const float* __restrict__ regw3,
            const float* __restrict__ camb3, const float* __restrict__ regb3,
            float* __restrict__ o1b) {
  __shared__ float gls[512];
  __shared__ float part[4][128];
  int pb = blockIdx.x, och = blockIdx.y;
  bool cam = (pb < 4);
  const float* W3 = cam ? camw3 : regw3;
  const float* B3 = cam ? camb3 : regb3;
  int tid = threadIdx.x;
  gls[tid] = gsb[pb * 512 + tid];
  __syncthreads();
  int col = tid & 127, kq = tid >> 7;
  int o = (och << 7) + col;
  float acc = 0.f;
  const float* w = W3 + (size_t)(kq << 7) * 512 + o;
  #pragma unroll 8
  for (int kk = 0; kk < 128; ++kk) acc += gls[(kq << 7) + kk] * w[(size_t)kk * 512];
  part[kq][col] = acc;
  __syncthreads();
  if (kq == 0) {
    float s = part[0][col] + part[1][col] + part[2][col] + part[3][col] + B3[o];
    o1b[pb * 512 + o] = fmaxf(s, 0.f);
  }
}

// ---------------- cr3c: out = l2norm(o1 @ W4 + b4), k-split x2 + block l2norm -------
__global__ __launch_bounds__(512)
void k_cr3c(const float* __restrict__ o1b,
            const float* __restrict__ camw4, const float* __restrict__ regw4,
            const float* __restrict__ camb4, const float* __restrict__ regb4,
            float* __restrict__ out) {
  __shared__ float o1s[512];
  __shared__ float part[2][256];
  __shared__ float vsq[256];
  __shared__ float red[4];
  int pb = blockIdx.x;
  bool cam = (pb < 4);
  int path = pb >> 2, b = pb & 3;
  const float* W4 = cam ? camw4 : regw4;
  const float* B4 = cam ? camb4 : regb4;
  int tid = threadIdx.x;
  o1s[tid] = o1b[pb * 512 + tid];
  __syncthreads();
  int col = tid & 255, kh = tid >> 8;
  float acc = 0.f;
  const float* w = W4 + (size_t)(kh << 8) * 256 + col;
  #pragma unroll 8
  for (int kk = 0; kk < 256; ++kk) acc += o1s[(kh << 8) + kk] * w[(size_t)kk * 256];
  part[kh][col] = acc;
  __syncthreads();
  float val = 0.f;
  if (kh == 0) {
    val = part[0][col] + part[1][col] + B4[col];
    vsq[col] = val * val;
  }
  __syncthreads();
  float ss = (tid < 256) ? vsq[tid] : 0.f;
  #pragma unroll
  for (int o = 32; o; o >>= 1) ss += __shfl_down(ss, o);
  if (tid < 256 && (tid & 63) == 0) red[tid >> 6] = ss;
  __syncthreads();
  if (kh == 0) {
    float tot = red[0] + red[1] + red[2] + red[3];
    float inv = 1.f / fmaxf(sqrtf(tot), 1e-12f);
    out[(size_t)b * 8704 + 8192 + path * 256 + col] = val * inv;
  }
}

// ---------------- scores transpose: FS[:,128:192] -> Sc[B][65][4096] (+dust row) ----
__global__ void k_tr_scores(const float* __restrict__ FS, const float* __restrict__ dust,
                            float* __restrict__ Sc) {
  __shared__ float t[64][65];
  int b = blockIdx.x >> 6, n0 = (blockIdx.x & 63) * 64;
  int tx = threadIdx.x & 63, ty = threadIdx.x >> 6;
  for (int r = ty; r < 64; r += 4)
    t[r][tx] = FS[((size_t)(b * NPB + n0 + r)) * N2 + 128 + tx];
  __syncthreads();
  for (int k = ty; k < 64; k += 4)
    Sc[((size_t)(b * MA) + k) * NPB + n0 + tx] = t[tx][k];
  if (threadIdx.x < 64)
    Sc[((size_t)(b * MA) + 64) * NPB + n0 + threadIdx.x] = dust[0];
}

// ---------------- sinkhorn: u update — one-pass online LSE over n=4096 ----------------
__global__ void k_sink_u(const float* __restrict__ Sc, const float* __restrict__ v,
                         float* __restrict__ u) {
  __shared__ float redm[4], reds[4];
  int b = blockIdx.x / MA, k = blockIdx.x % MA;
  const float* row = Sc + ((size_t)(b * MA) + k) * NPB;
  const float* vb = v + (size_t)b * NPB;
  int tid = threadIdx.x;
  float mx = -1e30f, s = 0.f;
  for (int n = tid; n < NPB; n += 256) {
    float x = row[n] + vb[n];
    float m2 = fmaxf(mx, x);
    s = s * __expf(mx - m2) + __expf(x - m2);
    mx = m2;
  }
  #pragma unroll
  for (int o = 32; o; o >>= 1) {
    float mo = __shfl_down(mx, o), so = __shfl_down(s, o);
    float m2 = fmaxf(mx, mo);
    s = s * __expf(mx - m2) + so * __expf(mo - m2);
    mx = m2;
  }
  if ((tid & 63) == 0) { redm[tid >> 6] = mx; reds[tid >> 6] = s; }
  __syncthreads();
  if (tid == 0) {
    float M = redm[0];
    #pragma unroll
    for (int i = 1; i < 4; ++i) M = fmaxf(M, redm[i]);
    float S = 0.f;
    #pragma unroll
    for (int i = 0; i < 4; ++i) S += reds[i] * __expf(redm[i] - M);
    const float nrm = -logf((float)(NPB + MD));
    float la = (k == MD) ? (nrm + logf((float)(NPB - MD))) : nrm;
    u[b * MA + k] = la - (M + __logf(S));
  }
}

// ---------------- sinkhorn: v update (col LSE over m+1=65) ----------------
__global__ void k_sink_v(const float* __restrict__ Sc, const float* __restrict__ u,
                         float* __restrict__ v) {
  __shared__ float us[MA];
  int b = blockIdx.x >> 4;
  int n = ((blockIdx.x & 15) << 8) + threadIdx.x;
  if (threadIdx.x < MA) us[threadIdx.x] = u[b * MA + threadIdx.x];
  __syncthreads();
  const float* Sb = Sc + (size_t)b * MA * NPB + n;
  float mx = -1e30f;
  for (int k = 0; k < MA; ++k) mx = fmaxf(mx, Sb[(size_t)k * NPB] + us[k]);
  float s = 0.f;
  for (int k = 0; k < MA; ++k) s += __expf(Sb[(size_t)k * NPB] + us[k] - mx);
  const float nrm = -logf((float)(NPB + MD));
  v[(size_t)b * NPB + n] = nrm - (mx + __logf(s));
}

// ---------------- pooled stage 1 (P fused): partial[b][j][c][k] over 64-n chunks ------
__global__ __launch_bounds__(256)
void k_pooled1(const float* __restrict__ FS, const float* __restrict__ Sc,
               const float* __restrict__ u, const float* __restrict__ v,
               float* __restrict__ partial) {
  __shared__ float Fs[64][132];
  __shared__ float Ps[64][68];
  int b = blockIdx.x >> 6, j = blockIdx.x & 63;
  int n0 = j << 6;
  int tid = threadIdx.x;
  {
    int r = tid >> 5;
    int c4 = (tid & 31) << 2;
    #pragma unroll
    for (int i = 0; i < 8; ++i) {
      int n = r + (i << 3);
      float4 vv = *(const float4*)&FS[((size_t)(b * NPB + n0 + n)) * N2 + c4];
      *(float4*)&Fs[n][c4] = vv;
    }
  }
  {
    const float nrm = -logf((float)(NPB + MD));
    int r = tid >> 4;
    int c4 = (tid & 15) << 2;
    #pragma unroll
    for (int i = 0; i < 4; ++i) {
      int k = r + (i << 4);
      float uk = u[b * MA + k];
      float4 sv = *(const float4*)&Sc[((size_t)(b * MA) + k) * NPB + n0 + c4];
      float4 vv = *(const float4*)&v[(size_t)b * NPB + n0 + c4];
      float4 o;
      o.x = __expf(sv.x + uk + vv.x - nrm);
      o.y = __expf(sv.y + uk + vv.y - nrm);
      o.z = __expf(sv.z + uk + vv.z - nrm);
      o.w = __expf(sv.w + uk + vv.w - nrm);
      *(float4*)&Ps[k][c4] = o;
    }
  }
  __syncthreads();
  int tc = tid & 31, tk = tid >> 5;
  int c0 = tc << 2, k0 = tk << 3;
  float acc[4][8];
  #pragma unroll
  for (int i = 0; i < 4; ++i)
    #pragma unroll
    for (int kk = 0; kk < 8; ++kk) acc[i][kk] = 0.f;
  for (int n = 0; n < 64; ++n) {
    float4 f = *(const float4*)&Fs[n][c0];
    float pv[8];
    #pragma unroll
    for (int kk = 0; kk < 8; ++kk) pv[kk] = Ps[k0 + kk][n];
    #pragma unroll
    for (int i = 0; i < 4; ++i) {
      float fv = ((const float*)&f)[i];
      #pragma unroll
      for (int kk = 0; kk < 8; ++kk) acc[i][kk] += fv * pv[kk];
    }
  }
  float* dst = partial + ((size_t)(b * 64 + j) << 13);
  #pragma unroll
  for (int i = 0; i < 4; ++i) {
    float4 lo = {acc[i][0], acc[i][1], acc[i][2], acc[i][3]};
    float4 hi = {acc[i][4], acc[i][5], acc[i][6], acc[i][7]};
    *(float4*)&dst[((c0 + i) << 6) + k0] = lo;
    *(float4*)&dst[((c0 + i) << 6) + k0 + 4] = hi;
  }
}

// ---------------- pooled stage 2: reduce 64 partials, coalesced ----------------
__global__ void k_pooled2(const float* __restrict__ partial, float* __restrict__ pooled) {
  int o = blockIdx.x * 256 + threadIdx.x;
  int b = o >> 13, rem = o & 8191;
  const float* src = partial + ((size_t)b << 19) + rem;
  float s = 0.f;
  #pragma unroll 8
  for (int j = 0; j < 64; ++j) s += src[(size_t)j << 13];
  pooled[o] = s;
}

// ---------------- patch output: l2norm over c (128), write [b][c*64+k] --------------
__global__ void k_patch_out(const float* __restrict__ pooled, float* __restrict__ out) {
  int b = blockIdx.x >> 6, k = blockIdx.x & 63;
  int tid = threadIdx.x;
  float v0 = pooled[((size_t)(b * 128) + tid) * MD + k];
  float v1 = pooled[((size_t)(b * 128) + 64 + tid) * MD + k];
  float ss = v0 * v0 + v1 * v1;
  #pragma unroll
  for (int o = 32; o; o >>= 1) ss += __shfl_down(ss, o);
  ss = __shfl(ss, 0);
  float inv = 1.f / fmaxf(sqrtf(ss), 1e-12f);
  out[(size_t)b * 8704 + tid * 64 + k] = v0 * inv;
  out[(size_t)b * 8704 + (64 + tid) * 64 + k] = v1 * inv;
}

// ---------------- workspace layout (bytes) ----------------
// lifetime rule: below 67,108,864 overlaps Abf (live until GEMM1 done);
// 67,108,864..100,663,296 overlaps H (live GEMM1->GEMM2). cr path runs AFTER GEMM2.
// GSB/O1B reuse CP1 region (cp1 last read by k_cr_fin1; cr3a runs after k_cr_fin2).
#define OFF_ABF 0u
#define OFF_SC 0u
#define OFF_U 4259840u
#define OFF_V 4263936u
#define OFF_POOL 8523776u
#define OFF_HP 8982528u                   // written post-GEMM2 only!
#define OFF_H 67108864u
#define OFF_PART OFF_H                    // 8,388,608 (disjoint from CP1)
#define OFF_CP1 75497472u
#define OFF_GSB OFF_CP1                   // 8*512*4 = 16,384
#define OFF_O1B 75513856u                 // 8*512*4 = 16,384
#define OFF_CP2 83886080u
#define OFF_BT1CR 88080384u
#define OFF_BT2CR 96468992u
#define OFF_ACR 98566144u
#define OFF_A2 99090432u
#define OFF_FS 100663296u
#define OFF_W1T 117440512u
#define OFF_W2T 121634816u
#define OFF_B1C 122159104u
#define OFF_B2C 122163200u

extern "C" void kernel_launch(void* const* d_in, const int* in_sizes, int n_in,
                              void* d_out, int out_size, void* d_ws, size_t ws_size,
                              hipStream_t stream) {
  (void)in_sizes; (void)n_in; (void)out_size; (void)ws_size;
  const float* tokens = (const float*)d_in[0];
  const float* cam_w1 = (const float*)d_in[2];
  const float* cam_b1 = (const float*)d_in[3];
  const float* cam_w2 = (const float*)d_in[4];
  const float* cam_b2 = (const float*)d_in[5];
  const float* cam_p  = (const float*)d_in[6];
  const float* cam_w3 = (const float*)d_in[7];
  const float* cam_b3 = (const float*)d_in[8];
  const float* cam_w4 = (const float*)d_in[9];
  const float* cam_b4 = (const float*)d_in[10];
  const float* reg_w1 = (const float*)d_in[11];
  const float* reg_b1 = (const float*)d_in[12];
  const float* reg_w2 = (const float*)d_in[13];
  const float* reg_b2 = (const float*)d_in[14];
  const float* reg_p  = (const float*)d_in[15];
  const float* reg_w3 = (const float*)d_in[16];
  const float* reg_b3 = (const float*)d_in[17];
  const float* reg_w4 = (const float*)d_in[18];
  const float* reg_b4 = (const float*)d_in[19];
  const float* pf_w1  = (const float*)d_in[20];
  const float* pf_b1  = (const float*)d_in[21];
  const float* pf_w2  = (const float*)d_in[22];
  const float* pf_b2  = (const float*)d_in[23];
  const float* ps_w1  = (const float*)d_in[24];
  const float* ps_b1  = (const float*)d_in[25];
  const float* ps_w2  = (const float*)d_in[26];
  const float* ps_b2  = (const float*)d_in[27];
  const float* dust   = (const float*)d_in[28];
  float* out = (float*)d_out;
  char* ws = (char*)d_ws;

  u16* Abf = (u16*)(ws + OFF_ABF);
  float* Sc = (float*)(ws + OFF_SC);
  float* ub = (float*)(ws + OFF_U);
  float* vb = (float*)(ws + OFF_V);
  float* pooled = (float*)(ws + OFF_POOL);
  float* hp = (float*)(ws + OFF_HP);
  u16* H   = (u16*)(ws + OFF_H);
  float* partial = (float*)(ws + OFF_PART);
  float* cp1 = (float*)(ws + OFF_CP1);
  float* gsb = (float*)(ws + OFF_GSB);
  float* o1b = (float*)(ws + OFF_O1B);
  float* cp2 = (float*)(ws + OFF_CP2);
  u16* Bt1cr = (u16*)(ws + OFF_BT1CR);
  u16* Bt2cr = (u16*)(ws + OFF_BT2CR);
  u16* Acr = (u16*)(ws + OFF_ACR);
  u16* A2  = (u16*)(ws + OFF_A2);
  float* FS = (float*)(ws + OFF_FS);
  u16* W1t = (u16*)(ws + OFF_W1T);
  u16* W2t = (u16*)(ws + OFF_W2T);
  float* b1c = (float*)(ws + OFF_B1C);
  float* b2c = (float*)(ws + OFF_B2C);

  hipMemsetAsync(vb, 0, (size_t)B_ * NPB * sizeof(float), stream);

  // ---- patch packs + GEMMs ----
  k_convert_patch<<<16384, 256, 0, stream>>>(tokens, Abf);
  k_pack_patch<<<2308, 256, 0, stream>>>(pf_w1, ps_w1, pf_w2, ps_w2,
                                         pf_b1, ps_b1, pf_b2, ps_b2,
                                         W1t, W2t, b1c, b2c);
  k_gemm256<1, 1><<<dim3(64, 4), 512, 0, stream>>>(Abf, W1t, b1c, (void*)H, MROWS, N1, CDIM);
  k_gemm<0, 0><<<dim3(128, 2), 256, 0, stream>>>(H, W2t, b2c, (void*)FS, MROWS, N2, N1);

  // ---- cam/reg path (Abf and H regions now dead) ----
  k_pack_cr<<<5248, 256, 0, stream>>>(cam_w1, reg_w1, cam_w2, reg_w2, tokens,
                                      Bt1cr, Bt2cr, Acr);
  k_gemm_splitk<<<dim3(1, 16, 8), 256, 0, stream>>>(Acr, Bt1cr, cp1, 2048, CDIM, 256);
  k_cr_fin1<<<dim3(128, 4), 256, 0, stream>>>(cp1, cam_b1, reg_b1, A2);
  k_gemm_splitk<<<dim3(1, 8, 8), 256, 0, stream>>>(A2, Bt2cr, cp2, 1024, N1, 128);
  k_cr_fin2<<<80, 512, 0, stream>>>(cp2, cam_b2, reg_b2, cam_p, reg_p, hp);
  k_cr3a<<<8, 512, 0, stream>>>(hp, cam_p, reg_p, gsb);
  k_cr3b<<<dim3(8, 4), 512, 0, stream>>>(gsb, cam_w3, reg_w3, cam_b3, reg_b3, o1b);
  k_cr3c<<<8, 512, 0, stream>>>(o1b, cam_w4, reg_w4, cam_b4, reg_b4, out);

  // ---- sinkhorn + pooled + outputs ----
  k_tr_scores<<<256, 256, 0, stream>>>(FS, dust, Sc);
  for (int it = 0; it < 3; ++it) {
    k_sink_u<<<B_ * MA, 256, 0, stream>>>(Sc, vb, ub);
    k_sink_v<<<B_ * 16, 256, 0, stream>>>(Sc, ub, vb);
  }
  k_pooled1<<<B_ * 64, 256, 0, stream>>>(FS, Sc, ub, vb, partial);
  k_pooled2<<<128, 256, 0, stream>>>(partial, pooled);
  k_patch_out<<<B_ * MD, 64, 0, stream>>>(pooled, out);
}